// Round 1
// baseline (6553.222 us; speedup 1.0000x reference)
//
#include <hip/hip_runtime.h>
#include <math.h>

#define B 32
#define L 2048
#define DIN 5
#define DOUT 5
#define H 256
#define NST 32
#define NLAYERS 4
#define NRES 3
#define CHUNK 128
#define NCH 16            // L / CHUNK
#define LSEQ (B*H*L)      // 16777216

__device__ __forceinline__ float gelu_exact(float v) {
    return 0.5f * v * (1.0f + erff(v * 0.7071067811865475f));
}

// ---------------- conv K=15 pad=7 (encoder & decoder) ----------------
// grid (L/512, Cout, B), block 128; each thread computes 4 consecutive l.
__global__ __launch_bounds__(128) void k_conv15(const float* __restrict__ in,
        const float* __restrict__ w, const float* __restrict__ bias,
        float* __restrict__ out, int Cin) {
    __shared__ float xs[8*528];
    const int tid = threadIdx.x;
    const int l0 = blockIdx.x * 512;
    const int o  = blockIdx.y;
    const int b  = blockIdx.z;
    const int Cout = gridDim.y;
    float acc[4] = {0.f,0.f,0.f,0.f};
    for (int c0 = 0; c0 < Cin; c0 += 8) {
        const int gn = (Cin - c0) < 8 ? (Cin - c0) : 8;
        __syncthreads();
        for (int j = tid; j < gn*526; j += 128) {
            int cl = j / 526, pos = j % 526;
            int gl = l0 + pos - 7;
            xs[cl*528 + pos] = (gl >= 0 && gl < L) ? in[(b*Cin + c0 + cl)*L + gl] : 0.f;
        }
        __syncthreads();
        for (int cl = 0; cl < gn; ++cl) {
            float xw[20];
            #pragma unroll
            for (int q = 0; q < 5; ++q) {
                float4 v = *(const float4*)&xs[cl*528 + tid*4 + q*4];
                xw[q*4+0]=v.x; xw[q*4+1]=v.y; xw[q*4+2]=v.z; xw[q*4+3]=v.w;
            }
            const float* wr = &w[(o*Cin + c0 + cl)*15];
            #pragma unroll
            for (int k = 0; k < 15; ++k) {
                float wk = wr[k];
                #pragma unroll
                for (int ll = 0; ll < 4; ++ll)
                    acc[ll] = fmaf(wk, xw[ll + k], acc[ll]);
            }
        }
    }
    float bo = bias[o];
    int gbase = (b*Cout + o)*L + l0 + tid*4;
    float4 v = {acc[0]+bo, acc[1]+bo, acc[2]+bo, acc[3]+bo};
    *(float4*)&out[gbase] = v;
}

// ---------------- residual conv weight transpose ----------------
// wT[cv][ci][k][o] = w_src[r][o][ci][k],  cv = r*2 + which
__global__ void k_restrans(const float* __restrict__ w1, const float* __restrict__ w2,
                           float* __restrict__ wT) {
    int idx = blockIdx.x*256 + threadIdx.x;
    if (idx >= NRES*2*H*3*H) return;
    int o  = idx % H;
    int k  = (idx / H) % 3;
    int ci = (idx / (H*3)) % H;
    int cv = idx / (H*3*H);
    int r  = cv >> 1;
    const float* src = (cv & 1) ? w2 : w1;
    wT[idx] = src[((r*H + o)*H + ci)*3 + k];
}

// ---------------- residual conv K=3 pad=1 (+optional residual, relu) ----------------
// grid (L/64, B), block 256 (tid = out channel); 64 l per thread.
__global__ __launch_bounds__(256) void k_resconv(const float* __restrict__ in,
        const float* __restrict__ wT, const float* __restrict__ bias,
        const float* __restrict__ resid, float* __restrict__ out) {
    __shared__ float xs[8*68];
    const int tid = threadIdx.x;
    const int l0 = blockIdx.x * 64;
    const int b  = blockIdx.y;
    float acc[64];
    #pragma unroll
    for (int i = 0; i < 64; ++i) acc[i] = 0.f;
    for (int cg = 0; cg < 32; ++cg) {
        __syncthreads();
        for (int j = tid; j < 8*66; j += 256) {
            int cl = j / 66, pos = j % 66;
            int gl = l0 + pos - 1;
            xs[cl*68 + pos] = (gl >= 0 && gl < L) ? in[(b*H + cg*8 + cl)*L + gl] : 0.f;
        }
        __syncthreads();
        for (int cl = 0; cl < 8; ++cl) {
            int ci = cg*8 + cl;
            float w0 = wT[(ci*3+0)*H + tid];
            float w1 = wT[(ci*3+1)*H + tid];
            float w2 = wT[(ci*3+2)*H + tid];
            #pragma unroll
            for (int g = 0; g < 4; ++g) {
                float xw[20];
                #pragma unroll
                for (int q = 0; q < 5; ++q) {
                    float4 v = *(const float4*)&xs[cl*68 + g*16 + q*4];
                    xw[q*4+0]=v.x; xw[q*4+1]=v.y; xw[q*4+2]=v.z; xw[q*4+3]=v.w;
                }
                #pragma unroll
                for (int ll = 0; ll < 16; ++ll)
                    acc[g*16+ll] = fmaf(w0, xw[ll],
                                   fmaf(w1, xw[ll+1],
                                   fmaf(w2, xw[ll+2], acc[g*16+ll])));
            }
        }
    }
    float bo = bias[tid];
    int gbase = (b*H + tid)*L + l0;
    if (resid) {
        #pragma unroll
        for (int g = 0; g < 16; ++g) {
            float4 rv = *(const float4*)&resid[gbase + g*4];
            float4 v;
            v.x = fmaxf(acc[g*4+0] + bo + rv.x, 0.f);
            v.y = fmaxf(acc[g*4+1] + bo + rv.y, 0.f);
            v.z = fmaxf(acc[g*4+2] + bo + rv.z, 0.f);
            v.w = fmaxf(acc[g*4+3] + bo + rv.w, 0.f);
            *(float4*)&out[gbase + g*4] = v;
        }
    } else {
        #pragma unroll
        for (int g = 0; g < 16; ++g) {
            float4 v;
            v.x = fmaxf(acc[g*4+0] + bo, 0.f);
            v.y = fmaxf(acc[g*4+1] + bo, 0.f);
            v.z = fmaxf(acc[g*4+2] + bo, 0.f);
            v.w = fmaxf(acc[g*4+3] + bo, 0.f);
            *(float4*)&out[gbase + g*4] = v;
        }
    }
}

// ---------------- DSS: per-(h,n) discretized pole z and z^CHUNK ----------------
__global__ void k_zw(const float* __restrict__ log_dt, const float* __restrict__ lam_re,
                     const float* __restrict__ lam_im, float4* __restrict__ zwbuf, int layer) {
    int idx = blockIdx.x*256 + threadIdx.x;
    if (idx >= H*NST) return;
    int hh = idx / NST, n = idx % NST;
    float dt = expf(log_dt[layer*H + hh]);
    float a  = dt * lam_re[layer*NST + n];
    float bi = dt * lam_im[layer*NST + n];
    float er = expf(a);
    float zre = er * cosf(bi), zim = er * sinf(bi);
    float eC = expf(a * (float)CHUNK);
    float bC = bi * (float)CHUNK;
    float zcre = eC * cosf(bC), zcim = eC * sinf(bC);
    zwbuf[idx] = make_float4(zre, zim, zcre, zcim);
}

// ---------------- DSS: glu weight transpose wtg[k][o] = glu_w[layer][o][k] ----------------
__global__ void k_wtg(const float* __restrict__ gw, float* __restrict__ wtg, int layer) {
    int idx = blockIdx.x*256 + threadIdx.x;
    if (idx >= 512*256) return;
    int k = idx / 512, o = idx % 512;
    wtg[idx] = gw[layer*512*256 + o*256 + k];
}

// ---------------- DSS scan phase 1: per-chunk summaries ----------------
// block = (b,h,ch), 64 threads (lane = dir*32 + n).
// fwd: A = sum_j x[j] z^{C-1-j} ; bwd: A = sum_j x[j] z^{j}   (j = local idx)
__global__ __launch_bounds__(64) void k_scan1(const float* __restrict__ in,
        const float4* __restrict__ zw, float2* __restrict__ states) {
    __shared__ float xs[CHUNK];
    int tid = threadIdx.x;
    int ch = blockIdx.x % NCH;
    int hh = (blockIdx.x / NCH) % H;
    int b  = blockIdx.x / (NCH*H);
    const float* src = &in[(b*H + hh)*L + ch*CHUNK];
    for (int j = tid; j < CHUNK; j += 64) xs[j] = src[j];
    __syncthreads();
    int dir = tid >> 5, n = tid & 31;
    float4 z4 = zw[hh*NST + n];
    float zre = z4.x, zim = z4.y;
    float are = 0.f, aim = 0.f;
    for (int t = 0; t < CHUNK; t += 4) {
        float4 vf = *(const float4*)&xs[t];
        float4 vb = *(const float4*)&xs[CHUNK - 4 - t];
        float xv[4];
        if (dir == 0) { xv[0]=vf.x; xv[1]=vf.y; xv[2]=vf.z; xv[3]=vf.w; }
        else          { xv[0]=vb.w; xv[1]=vb.z; xv[2]=vb.y; xv[3]=vb.x; }
        #pragma unroll
        for (int q = 0; q < 4; ++q) {
            float nre = fmaf(zre, are, fmaf(-zim, aim, xv[q]));
            float nim = fmaf(zre, aim, zim * are);
            are = nre; aim = nim;
        }
    }
    states[((b*H + hh)*NCH + ch)*64 + tid] = make_float2(are, aim);
}

// ---------------- DSS scan phase 2: exclusive chunk prefix/suffix ----------------
// thread = (b,h,dir,n); in-place on states.
__global__ void k_scan2(const float4* __restrict__ zw, float2* __restrict__ states) {
    int idx = blockIdx.x*256 + threadIdx.x;   // B*H*64 total
    int dn = idx & 63;
    int bh = idx >> 6;
    int hh = bh % H;
    int n = dn & 31, dir = dn >> 5;
    float4 z4 = zw[hh*NST + n];
    float zcre = z4.z, zcim = z4.w;
    float2* base = &states[bh*NCH*64 + dn];
    float pre = 0.f, pim = 0.f;
    if (dir == 0) {
        for (int ch = 0; ch < NCH; ++ch) {
            float2 cur = base[ch*64];
            base[ch*64] = make_float2(pre, pim);
            float nre = fmaf(zcre, pre, fmaf(-zcim, pim, cur.x));
            float nim = fmaf(zcre, pim, fmaf(zcim, pre, cur.y));
            pre = nre; pim = nim;
        }
    } else {
        for (int ch = NCH-1; ch >= 0; --ch) {
            float2 cur = base[ch*64];
            base[ch*64] = make_float2(pre, pim);
            float nre = fmaf(zcre, pre, fmaf(-zcim, pim, cur.x));
            float nim = fmaf(zcre, pim, fmaf(zcim, pre, cur.y));
            pre = nre; pim = nim;
        }
    }
}

// ---------------- DSS scan phase 3: rescan with projection ----------------
// block = (h-pair, b), 64 threads: lane = hl*32 + nh*16 + ch. Each lane scans
// one chunk with 16 states. DIR=0 writes y_fwd; DIR=1 adds y_bwd + D*x, gelu.
template<int DIR>
__global__ __launch_bounds__(64) void k_scan3(const float* __restrict__ in,
        const float4* __restrict__ zw, const float2* __restrict__ states,
        const float* __restrict__ W_re, const float* __restrict__ W_im,
        const float* __restrict__ Dv, float* __restrict__ y, int layer) {
    __shared__ float xp[2*2064];
    __shared__ float yp[2*2064];
    int tid = threadIdx.x;
    int b = blockIdx.y;
    int h0 = blockIdx.x * 2;
    for (int j = tid; j < 2*2048; j += 64) {
        int hl = j >> 11, pos = j & 2047;
        xp[hl*2064 + (pos>>7)*129 + (pos&127)] = in[(b*H + h0 + hl)*L + pos];
    }
    __syncthreads();
    int hl = tid >> 5, nh = (tid >> 4) & 1, ch = tid & 15;
    int hh = h0 + hl;
    float zr[16], zi[16], wr[16], wi[16], sre[16], sim[16];
    const float2* sbase = &states[((b*H + hh)*NCH + ch)*64 + DIR*32 + nh*16];
    const float* wrb = &W_re[((layer*2 + DIR)*H + hh)*NST + nh*16];
    const float* wib = &W_im[((layer*2 + DIR)*H + hh)*NST + nh*16];
    #pragma unroll
    for (int q = 0; q < 16; ++q) {
        float4 z4 = zw[hh*NST + nh*16 + q];
        zr[q] = z4.x; zi[q] = z4.y;
        wr[q] = wrb[q]; wi[q] = wib[q];
        float2 s = sbase[q];
        sre[q] = s.x; sim[q] = s.y;
    }
    const float* xrow = &xp[hl*2064 + ch*129];
    float* yrow = &yp[hl*2064 + ch*129];
    if (DIR == 0) {
        for (int t = 0; t < CHUNK; ++t) {
            float xv = xrow[t];
            float acc = 0.f;
            #pragma unroll
            for (int q = 0; q < 16; ++q) {
                float nre = fmaf(zr[q], sre[q], fmaf(-zi[q], sim[q], xv));
                float nim = fmaf(zr[q], sim[q], zi[q]*sre[q]);
                sre[q] = nre; sim[q] = nim;
                acc = fmaf(wr[q], nre, fmaf(-wi[q], nim, acc));
            }
            acc += __shfl_xor(acc, 16);
            if (nh == 0) yrow[t] = acc;
        }
    } else {
        for (int t = 0; t < CHUNK; ++t) {
            int tl = CHUNK - 1 - t;
            if (t > 0) {
                float xv = xrow[tl + 1];
                #pragma unroll
                for (int q = 0; q < 16; ++q) {
                    float nre = fmaf(zr[q], sre[q], fmaf(-zi[q], sim[q], xv));
                    float nim = fmaf(zr[q], sim[q], zi[q]*sre[q]);
                    sre[q] = nre; sim[q] = nim;
                }
            }
            float acc = 0.f;
            #pragma unroll
            for (int q = 0; q < 16; ++q)
                acc = fmaf(wr[q], sre[q], fmaf(-wi[q], sim[q], acc));
            acc += __shfl_xor(acc, 16);
            if (nh == 0) yrow[tl] = acc;
        }
    }
    __syncthreads();
    if (DIR == 0) {
        for (int j = tid; j < 2*2048; j += 64) {
            int hl2 = j >> 11, pos = j & 2047;
            y[(b*H + h0 + hl2)*L + pos] = yp[hl2*2064 + (pos>>7)*129 + (pos&127)];
        }
    } else {
        for (int j = tid; j < 2*2048; j += 64) {
            int hl2 = j >> 11, pos = j & 2047;
            int gi = (b*H + h0 + hl2)*L + pos;
            float xv = xp[hl2*2064 + (pos>>7)*129 + (pos&127)];
            float v = y[gi] + yp[hl2*2064 + (pos>>7)*129 + (pos&127)]
                    + Dv[layer*H + h0 + hl2] * xv;
            y[gi] = gelu_exact(v);
        }
    }
}

// ---------------- GLU: z = (W0 y + b0) * sigmoid(W1 y + b1), both halves fused ----------------
// grid (L/64, H/64, B), block 256; thread -> 4o x 4l, both halves.
__global__ __launch_bounds__(256) void k_glu(const float* __restrict__ y,
        const float* __restrict__ wtg, const float* __restrict__ bias,
        float* __restrict__ z) {
    __shared__ float Ws[16*128];
    __shared__ float Ys[16*68];
    int tid = threadIdx.x;
    int lt = blockIdx.x, ot = blockIdx.y, b = blockIdx.z;
    int l0 = lt*64;
    float acc0[4][4] = {{0.f}}, acc1[4][4] = {{0.f}};
    for (int kc = 0; kc < 256; kc += 16) {
        __syncthreads();
        for (int j = tid; j < 2048; j += 256) {
            int kk = j >> 7, oo = j & 127;
            int o = ((oo >> 6) ? 256 : 0) + ot*64 + (oo & 63);
            Ws[kk*128 + oo] = wtg[(kc+kk)*512 + o];
        }
        for (int j = tid; j < 1024; j += 256) {
            int kk = j >> 6, ll = j & 63;
            Ys[kk*68 + ll] = y[(b*H + kc + kk)*L + l0 + ll];
        }
        __syncthreads();
        int to = tid >> 4, tl = tid & 15;
        #pragma unroll
        for (int kk = 0; kk < 16; ++kk) {
            float4 w0 = *(const float4*)&Ws[kk*128 + to*4];
            float4 w1 = *(const float4*)&Ws[kk*128 + 64 + to*4];
            float4 yv = *(const float4*)&Ys[kk*68 + tl*4];
            float wa[4]={w0.x,w0.y,w0.z,w0.w};
            float wb[4]={w1.x,w1.y,w1.z,w1.w};
            float yy[4]={yv.x,yv.y,yv.z,yv.w};
            #pragma unroll
            for (int r = 0; r < 4; ++r)
                #pragma unroll
                for (int c = 0; c < 4; ++c) {
                    acc0[r][c] = fmaf(wa[r], yy[c], acc0[r][c]);
                    acc1[r][c] = fmaf(wb[r], yy[c], acc1[r][c]);
                }
        }
    }
    int to = tid >> 4, tl = tid & 15;
    #pragma unroll
    for (int r = 0; r < 4; ++r) {
        int og = ot*64 + to*4 + r;
        float b0 = bias[og], b1 = bias[256 + og];
        float g0 = acc0[r][0] + b0, g1 = acc0[r][1] + b0;
        float g2 = acc0[r][2] + b0, g3 = acc0[r][3] + b0;
        float s0 = acc1[r][0] + b1, s1 = acc1[r][1] + b1;
        float s2 = acc1[r][2] + b1, s3 = acc1[r][3] + b1;
        float4 v;
        v.x = g0 / (1.f + expf(-s0));
        v.y = g1 / (1.f + expf(-s1));
        v.z = g2 / (1.f + expf(-s2));
        v.w = g3 / (1.f + expf(-s3));
        *(float4*)&z[(b*H + og)*L + l0 + tl*4] = v;
    }
}

// ---------------- LayerNorm over channel dim of (z + h) -> h ----------------
__global__ __launch_bounds__(256) void k_ln(const float* __restrict__ z,
        float* __restrict__ h, const float* __restrict__ g, const float* __restrict__ bb) {
    int tid = threadIdx.x;
    int b = blockIdx.y;
    int l0 = blockIdx.x * 256;
    int gi0 = b*H*L + l0 + tid;
    float sum = 0.f, ss = 0.f;
    for (int c = 0; c < H; ++c) {
        float v = z[gi0 + c*L] + h[gi0 + c*L];
        sum += v; ss = fmaf(v, v, ss);
    }
    float mu = sum * (1.f/H);
    float var = ss * (1.f/H) - mu*mu;
    float rs = rsqrtf(var + 1e-5f);
    for (int c = 0; c < H; ++c) {
        float v = z[gi0 + c*L] + h[gi0 + c*L];
        h[gi0 + c*L] = (v - mu) * rs * g[c] + bb[c];
    }
}

// ---------------- species embedding add; also emit seq_emb output ----------------
__global__ void k_species(float* __restrict__ h, const int* __restrict__ xs,
        const float* __restrict__ emb, float* __restrict__ outseq) {
    int idx = blockIdx.x*256 + threadIdx.x;
    if (idx >= LSEQ) return;
    int c = (idx / L) % H;
    int b = idx / (H*L);
    float v = h[idx] + emb[xs[b]*H + c];
    h[idx] = v;
    outseq[idx] = v;
}

// ---------------- mean over L ----------------
__global__ __launch_bounds__(256) void k_agg(const float* __restrict__ h, float* __restrict__ agg) {
    __shared__ float red[256];
    int bc = blockIdx.x;
    int tid = threadIdx.x;
    float s = 0.f;
    for (int t = tid; t < L; t += 256) s += h[bc*L + t];
    red[tid] = s; __syncthreads();
    for (int k = 128; k > 0; k >>= 1) {
        if (tid < k) red[tid] += red[tid+k];
        __syncthreads();
    }
    if (tid == 0) agg[bc] = red[0] * (1.f/(float)L);
}

// ---------------- tiny regression MLP, one block per batch ----------------
__global__ __launch_bounds__(128) void k_mlp(const float* __restrict__ agg,
        const float* __restrict__ w1, const float* __restrict__ b1,
        const float* __restrict__ w2, const float* __restrict__ b2,
        const float* __restrict__ w3, const float* __restrict__ b3,
        const float* __restrict__ w4, const float* __restrict__ b4,
        float* __restrict__ outreg) {
    __shared__ float a0[256], r1[128], r2[64], r3[32];
    int b = blockIdx.x, tid = threadIdx.x;
    a0[tid] = agg[b*256 + tid];
    a0[tid+128] = agg[b*256 + tid + 128];
    __syncthreads();
    {
        float s = b1[tid];
        for (int k = 0; k < 256; ++k) s = fmaf(w1[tid*256+k], a0[k], s);
        r1[tid] = s > 0.f ? s : expm1f(s);
    }
    __syncthreads();
    if (tid < 64) {
        float s = b2[tid];
        for (int k = 0; k < 128; ++k) s = fmaf(w2[tid*128+k], r1[k], s);
        r2[tid] = s > 0.f ? s : expm1f(s);
    }
    __syncthreads();
    if (tid < 32) {
        float s = b3[tid];
        for (int k = 0; k < 64; ++k) s = fmaf(w3[tid*64+k], r2[k], s);
        r3[tid] = s > 0.f ? s : expm1f(s);
    }
    __syncthreads();
    if (tid == 0) {
        float s = b4[0];
        for (int k = 0; k < 32; ++k) s = fmaf(w4[k], r3[k], s);
        outreg[b] = s;
    }
}

extern "C" void kernel_launch(void* const* d_in, const int* in_sizes, int n_in,
                              void* d_out, int out_size, void* d_ws, size_t ws_size,
                              hipStream_t stream) {
    const float* x      = (const float*)d_in[0];
    const int*   xs     = (const int*)d_in[1];
    const float* enc_w  = (const float*)d_in[2];
    const float* enc_b  = (const float*)d_in[3];
    const float* res_w1 = (const float*)d_in[4];
    const float* res_b1 = (const float*)d_in[5];
    const float* res_w2 = (const float*)d_in[6];
    const float* res_b2 = (const float*)d_in[7];
    const float* log_dt = (const float*)d_in[8];
    const float* lam_re = (const float*)d_in[9];
    const float* lam_im = (const float*)d_in[10];
    const float* W_re   = (const float*)d_in[11];
    const float* W_im   = (const float*)d_in[12];
    const float* Dv     = (const float*)d_in[13];
    const float* glu_w  = (const float*)d_in[14];
    const float* glu_b  = (const float*)d_in[15];
    const float* ln_g   = (const float*)d_in[16];
    const float* ln_b   = (const float*)d_in[17];
    const float* dec_w  = (const float*)d_in[18];
    const float* dec_b  = (const float*)d_in[19];
    const float* sp_emb = (const float*)d_in[20];
    const float* h1_w = (const float*)d_in[21]; const float* h1_b = (const float*)d_in[22];
    const float* h2_w = (const float*)d_in[23]; const float* h2_b = (const float*)d_in[24];
    const float* h3_w = (const float*)d_in[25]; const float* h3_b = (const float*)d_in[26];
    const float* h4_w = (const float*)d_in[27]; const float* h4_b = (const float*)d_in[28];

    float* ws   = (float*)d_ws;
    float* h    = ws;                                  // LSEQ
    float* t1   = ws + (size_t)LSEQ;                   // LSEQ
    float* t2   = ws + (size_t)2*LSEQ;                 // LSEQ (states alias; wT6 alias pre-DSS)
    float2* states = (float2*)t2;
    float* wT6  = t2;                                  // 6*H*3*H, dead before states written
    float* wtg  = ws + (size_t)3*LSEQ;                 // 512*256
    float4* zwb = (float4*)(wtg + 512*256);            // H*NST float4
    float* aggb = wtg + 512*256 + H*NST*4;             // B*H

    float* outdec = (float*)d_out;
    float* outseq = outdec + B*DOUT*L;
    float* outreg = outseq + (size_t)LSEQ;

    // encoder conv
    k_conv15<<<dim3(L/512, H, B), 128, 0, stream>>>(x, enc_w, enc_b, h, DIN);

    // residual stack
    k_restrans<<<(NRES*2*H*3*H + 255)/256, 256, 0, stream>>>(res_w1, res_w2, wT6);
    for (int r = 0; r < NRES; ++r) {
        k_resconv<<<dim3(L/64, B), 256, 0, stream>>>(
            h, wT6 + (size_t)(r*2+0)*H*3*H, res_b1 + r*H, nullptr, t1);
        k_resconv<<<dim3(L/64, B), 256, 0, stream>>>(
            t1, wT6 + (size_t)(r*2+1)*H*3*H, res_b2 + r*H, h, h);
    }

    // DSS blocks
    for (int i = 0; i < NLAYERS; ++i) {
        k_zw<<<(H*NST + 255)/256, 256, 0, stream>>>(log_dt, lam_re, lam_im, zwb, i);
        k_wtg<<<(512*256 + 255)/256, 256, 0, stream>>>(glu_w, wtg, i);
        k_scan1<<<B*H*NCH, 64, 0, stream>>>(h, zwb, states);
        k_scan2<<<(B*H*64)/256, 256, 0, stream>>>(zwb, states);
        k_scan3<0><<<dim3(H/2, B), 64, 0, stream>>>(h, zwb, states, W_re, W_im, Dv, t1, i);
        k_scan3<1><<<dim3(H/2, B), 64, 0, stream>>>(h, zwb, states, W_re, W_im, Dv, t1, i);
        k_glu<<<dim3(L/64, H/64, B), 256, 0, stream>>>(t1, wtg, glu_b + i*512, t2);
        k_ln<<<dim3(L/256, B), 256, 0, stream>>>(t2, h, ln_g + i*H, ln_b + i*H);
    }

    // species embedding + seq_emb output
    k_species<<<(LSEQ + 255)/256, 256, 0, stream>>>(h, xs, sp_emb, outseq);
    // aggregate + regression head
    k_agg<<<B*H, 256, 0, stream>>>(h, aggb);
    k_mlp<<<B, 128, 0, stream>>>(aggb, h1_w, h1_b, h2_w, h2_b, h3_w, h3_b, h4_w, h4_b, outreg);
    // decoder conv
    k_conv15<<<dim3(L/512, DOUT, B), 128, 0, stream>>>(h, dec_w, dec_b, outdec, H);
}

// Round 3
// 4509.701 us; speedup vs baseline: 1.4531x; 1.4531x over previous
//
#include <hip/hip_runtime.h>
#include <math.h>

#define B 32
#define L 2048
#define DIN 5
#define DOUT 5
#define H 256
#define NST 32
#define NLAYERS 4
#define NRES 3
#define CHUNK 128
#define NCH 16            // L / CHUNK
#define LSEQ (B*H*L)      // 16777216

typedef __attribute__((ext_vector_type(8))) _Float16 half8;
typedef __attribute__((ext_vector_type(4))) float f32x4;

__device__ __forceinline__ float gelu_exact(float v) {
    return 0.5f * v * (1.0f + erff(v * 0.7071067811865475f));
}
#define SWZ(r) ((((r) ^ ((r) >> 2)) & 3))

// ---------------- conv K=15 pad=7 (encoder & decoder) ----------------
__global__ __launch_bounds__(128) void k_conv15(const float* __restrict__ in,
        const float* __restrict__ w, const float* __restrict__ bias,
        float* __restrict__ out, int Cin) {
    __shared__ float xs[8*528];
    const int tid = threadIdx.x;
    const int l0 = blockIdx.x * 512;
    const int o  = blockIdx.y;
    const int b  = blockIdx.z;
    const int Cout = gridDim.y;
    float acc[4] = {0.f,0.f,0.f,0.f};
    for (int c0 = 0; c0 < Cin; c0 += 8) {
        const int gn = (Cin - c0) < 8 ? (Cin - c0) : 8;
        __syncthreads();
        for (int j = tid; j < gn*526; j += 128) {
            int cl = j / 526, pos = j % 526;
            int gl = l0 + pos - 7;
            xs[cl*528 + pos] = (gl >= 0 && gl < L) ? in[(b*Cin + c0 + cl)*L + gl] : 0.f;
        }
        __syncthreads();
        for (int cl = 0; cl < gn; ++cl) {
            float xw[20];
            #pragma unroll
            for (int q = 0; q < 5; ++q) {
                float4 v = *(const float4*)&xs[cl*528 + tid*4 + q*4];
                xw[q*4+0]=v.x; xw[q*4+1]=v.y; xw[q*4+2]=v.z; xw[q*4+3]=v.w;
            }
            const float* wr = &w[(o*Cin + c0 + cl)*15];
            #pragma unroll
            for (int k = 0; k < 15; ++k) {
                float wk = wr[k];
                #pragma unroll
                for (int ll = 0; ll < 4; ++ll)
                    acc[ll] = fmaf(wk, xw[ll + k], acc[ll]);
            }
        }
    }
    float bo = bias[o];
    int gbase = (b*Cout + o)*L + l0 + tid*4;
    float4 v = {acc[0]+bo, acc[1]+bo, acc[2]+bo, acc[3]+bo};
    *(float4*)&out[gbase] = v;
}

// ---------------- weight pack: wpk[cv][k][o][ci] fp16 <- w[r][o][ci][k] ----------------
__global__ void k_wpack(const float* __restrict__ w1, const float* __restrict__ w2,
                        _Float16* __restrict__ wpk) {
    int idx = blockIdx.x*256 + threadIdx.x;
    if (idx >= NRES*2*3*65536) return;
    int ci = idx & 255;
    int o  = (idx >> 8) & 255;
    int k  = (idx >> 16) % 3;
    int cv = idx / (3*65536);
    const float* src = (cv & 1) ? w2 : w1;
    wpk[idx] = (_Float16)src[(((cv>>1)*H + o)*H + ci)*3 + k];
}

// ---------------- transpose f32 [b][c][l] -> fp16 channel-last [b*L][c] ----------------
__global__ __launch_bounds__(256) void k_t_cl(const float* __restrict__ in,
                                              _Float16* __restrict__ out) {
    __shared__ float t[64][65];
    int tid = threadIdx.x;
    int l0 = blockIdx.x*64, c0 = blockIdx.y*64, b = blockIdx.z;
    #pragma unroll
    for (int i = 0; i < 16; ++i) {
        int idx = i*256 + tid;
        int c = idx >> 6, l = idx & 63;
        t[c][l] = in[((size_t)(b*H + c0 + c))*L + l0 + l];
    }
    __syncthreads();
    #pragma unroll
    for (int i = 0; i < 16; ++i) {
        int idx = i*256 + tid;
        int l = idx >> 6, c = idx & 63;
        out[((size_t)b*L + l0 + l)*256 + c0 + c] = (_Float16)t[c][l];
    }
}

// ---------------- transpose fp16 channel-last [b*L][c] -> f32 [b][c][l] ----------------
__global__ __launch_bounds__(256) void k_t_cf(const _Float16* __restrict__ in,
                                              float* __restrict__ out) {
    __shared__ float t[64][65];
    int tid = threadIdx.x;
    int l0 = blockIdx.x*64, c0 = blockIdx.y*64, b = blockIdx.z;
    #pragma unroll
    for (int i = 0; i < 16; ++i) {
        int idx = i*256 + tid;
        int l = idx >> 6, c = idx & 63;
        t[c][l] = (float)in[((size_t)b*L + l0 + l)*256 + c0 + c];
    }
    __syncthreads();
    #pragma unroll
    for (int i = 0; i < 16; ++i) {
        int idx = i*256 + tid;
        int c = idx >> 6, l = idx & 63;
        out[((size_t)(b*H + c0 + c))*L + l0 + l] = t[c][l];
    }
}

// ---------------- MFMA residual conv K=3 (fp16): out = relu(conv(xin) + bias [+ resid]) ----------------
// channel-last fp16. Tile 128(m=b*L) x 128(o), BK=32, K-loop = 3 taps x 8 ci-chunks.
template<bool RESID>
__global__ __launch_bounds__(256) void k_cv3(const _Float16* __restrict__ xin,
        const _Float16* __restrict__ wpk, const float* __restrict__ bias,
        const _Float16* __restrict__ resid, _Float16* __restrict__ out) {
    __shared__ _Float16 a_lds[128*32];
    __shared__ _Float16 b_lds[128*32];
    const int tid = threadIdx.x;
    const int mbase = blockIdx.x * 128;
    const int o0 = blockIdx.y * 128;
    const int lane = tid & 63;
    const int w = tid >> 6;
    const int wm = (w >> 1) * 64, wn = (w & 1) * 64;
    const int fr = lane & 15, kg = lane >> 4;

    const int r0s = tid >> 2, q0 = tid & 3;
    const int r1s = 64 + (tid >> 2);
    const int aw0 = r0s*32 + ((q0 ^ SWZ(r0s)) * 8);
    const int aw1 = r1s*32 + ((q0 ^ SWZ(r1s)) * 8);

    f32x4 acc[4][4];
    #pragma unroll
    for (int i = 0; i < 4; ++i)
        #pragma unroll
        for (int j = 0; j < 4; ++j)
            #pragma unroll
            for (int k = 0; k < 4; ++k) acc[i][j][k] = 0.f;

    uint4 pa0, pa1, pb0, pb1;
    auto loadstep = [&](int kk, uint4& a0, uint4& a1, uint4& b0, uint4& b1) {
        const int koff = kk >> 3, cic = kk & 7;
        const int cb = cic*32 + q0*8;
        {
            int m = mbase + r0s;
            int ll = (m & (L-1)) + koff - 1;
            a0 = (ll >= 0 && ll < L) ? *(const uint4*)&xin[((size_t)(m + koff - 1))*256 + cb]
                                     : make_uint4(0,0,0,0);
            int m1 = mbase + r1s;
            int l1 = (m1 & (L-1)) + koff - 1;
            a1 = (l1 >= 0 && l1 < L) ? *(const uint4*)&xin[((size_t)(m1 + koff - 1))*256 + cb]
                                     : make_uint4(0,0,0,0);
        }
        b0 = *(const uint4*)&wpk[((size_t)(koff*256 + o0 + r0s))*256 + cb];
        b1 = *(const uint4*)&wpk[((size_t)(koff*256 + o0 + r1s))*256 + cb];
    };
    loadstep(0, pa0, pa1, pb0, pb1);
    for (int kk = 0; kk < 24; ++kk) {
        __syncthreads();
        *(uint4*)&a_lds[aw0] = pa0;
        *(uint4*)&a_lds[aw1] = pa1;
        *(uint4*)&b_lds[aw0] = pb0;
        *(uint4*)&b_lds[aw1] = pb1;
        uint4 na0 = make_uint4(0,0,0,0), na1 = na0, nb0 = na0, nb1 = na0;
        if (kk < 23) loadstep(kk+1, na0, na1, nb0, nb1);
        __syncthreads();
        half8 af[4], bfr[4];
        #pragma unroll
        for (int mf = 0; mf < 4; ++mf) {
            int ra = wm + mf*16 + fr;
            af[mf] = *(const half8*)&a_lds[ra*32 + ((kg ^ SWZ(ra)) * 8)];
        }
        #pragma unroll
        for (int nf = 0; nf < 4; ++nf) {
            int rb = wn + nf*16 + fr;
            bfr[nf] = *(const half8*)&b_lds[rb*32 + ((kg ^ SWZ(rb)) * 8)];
        }
        #pragma unroll
        for (int mf = 0; mf < 4; ++mf)
            #pragma unroll
            for (int nf = 0; nf < 4; ++nf)
                acc[mf][nf] = __builtin_amdgcn_mfma_f32_16x16x32_f16(af[mf], bfr[nf], acc[mf][nf], 0, 0, 0);
        pa0 = na0; pa1 = na1; pb0 = nb0; pb1 = nb1;
    }
    const int orow = kg * 4;
    #pragma unroll
    for (int nf = 0; nf < 4; ++nf) {
        int o = o0 + wn + nf*16 + fr;
        float bo = bias[o];
        #pragma unroll
        for (int mf = 0; mf < 4; ++mf) {
            #pragma unroll
            for (int rg = 0; rg < 4; ++rg) {
                size_t m = (size_t)mbase + wm + mf*16 + orow + rg;
                float v = acc[mf][nf][rg] + bo;
                if (RESID) v += (float)resid[m*256 + o];
                v = fmaxf(v, 0.f);
                out[m*256 + o] = (_Float16)v;
            }
        }
    }
}

// ---------------- DSS: per-(h,n) discretized pole z and z^CHUNK ----------------
__global__ void k_zw(const float* __restrict__ log_dt, const float* __restrict__ lam_re,
                     const float* __restrict__ lam_im, float4* __restrict__ zwbuf, int layer) {
    int idx = blockIdx.x*256 + threadIdx.x;
    if (idx >= H*NST) return;
    int hh = idx / NST, n = idx % NST;
    float dt = expf(log_dt[layer*H + hh]);
    float a  = dt * lam_re[layer*NST + n];
    float bi = dt * lam_im[layer*NST + n];
    float er = expf(a);
    float zre = er * cosf(bi), zim = er * sinf(bi);
    float eC = expf(a * (float)CHUNK);
    float bC = bi * (float)CHUNK;
    float zcre = eC * cosf(bC), zcim = eC * sinf(bC);
    zwbuf[idx] = make_float4(zre, zim, zcre, zcim);
}

// ---------------- DSS: glu weight transpose ----------------
__global__ void k_wtg(const float* __restrict__ gw, float* __restrict__ wtg, int layer) {
    int idx = blockIdx.x*256 + threadIdx.x;
    if (idx >= 512*256) return;
    int k = idx / 512, o = idx % 512;
    wtg[idx] = gw[layer*512*256 + o*256 + k];
}

// ---------------- DSS scan phase 1 ----------------
__global__ __launch_bounds__(64) void k_scan1(const float* __restrict__ in,
        const float4* __restrict__ zw, float2* __restrict__ states) {
    __shared__ float xs[CHUNK];
    int tid = threadIdx.x;
    int ch = blockIdx.x % NCH;
    int hh = (blockIdx.x / NCH) % H;
    int b  = blockIdx.x / (NCH*H);
    const float* src = &in[(b*H + hh)*L + ch*CHUNK];
    for (int j = tid; j < CHUNK; j += 64) xs[j] = src[j];
    __syncthreads();
    int dir = tid >> 5, n = tid & 31;
    float4 z4 = zw[hh*NST + n];
    float zre = z4.x, zim = z4.y;
    float are = 0.f, aim = 0.f;
    for (int t = 0; t < CHUNK; t += 4) {
        float4 vf = *(const float4*)&xs[t];
        float4 vb = *(const float4*)&xs[CHUNK - 4 - t];
        float xv[4];
        if (dir == 0) { xv[0]=vf.x; xv[1]=vf.y; xv[2]=vf.z; xv[3]=vf.w; }
        else          { xv[0]=vb.w; xv[1]=vb.z; xv[2]=vb.y; xv[3]=vb.x; }
        #pragma unroll
        for (int q = 0; q < 4; ++q) {
            float nre = fmaf(zre, are, fmaf(-zim, aim, xv[q]));
            float nim = fmaf(zre, aim, zim * are);
            are = nre; aim = nim;
        }
    }
    states[((b*H + hh)*NCH + ch)*64 + tid] = make_float2(are, aim);
}

// ---------------- DSS scan phase 2 ----------------
__global__ void k_scan2(const float4* __restrict__ zw, float2* __restrict__ states) {
    int idx = blockIdx.x*256 + threadIdx.x;
    int dn = idx & 63;
    int bh = idx >> 6;
    int hh = bh % H;
    int n = dn & 31, dir = dn >> 5;
    float4 z4 = zw[hh*NST + n];
    float zcre = z4.z, zcim = z4.w;
    float2* base = &states[bh*NCH*64 + dn];
    float pre = 0.f, pim = 0.f;
    if (dir == 0) {
        for (int ch = 0; ch < NCH; ++ch) {
            float2 cur = base[ch*64];
            base[ch*64] = make_float2(pre, pim);
            float nre = fmaf(zcre, pre, fmaf(-zcim, pim, cur.x));
            float nim = fmaf(zcre, pim, fmaf(zcim, pre, cur.y));
            pre = nre; pim = nim;
        }
    } else {
        for (int ch = NCH-1; ch >= 0; --ch) {
            float2 cur = base[ch*64];
            base[ch*64] = make_float2(pre, pim);
            float nre = fmaf(zcre, pre, fmaf(-zcim, pim, cur.x));
            float nim = fmaf(zcre, pim, fmaf(zcim, pre, cur.y));
            pre = nre; pim = nim;
        }
    }
}

// ---------------- DSS scan phase 3 ----------------
template<int DIR>
__global__ __launch_bounds__(64) void k_scan3(const float* __restrict__ in,
        const float4* __restrict__ zw, const float2* __restrict__ states,
        const float* __restrict__ W_re, const float* __restrict__ W_im,
        const float* __restrict__ Dv, float* __restrict__ y, int layer) {
    __shared__ float xp[2*2064];
    __shared__ float yp[2*2064];
    int tid = threadIdx.x;
    int b = blockIdx.y;
    int h0 = blockIdx.x * 2;
    for (int j = tid; j < 2*2048; j += 64) {
        int hl = j >> 11, pos = j & 2047;
        xp[hl*2064 + (pos>>7)*129 + (pos&127)] = in[(b*H + h0 + hl)*L + pos];
    }
    __syncthreads();
    int hl = tid >> 5, nh = (tid >> 4) & 1, ch = tid & 15;
    int hh = h0 + hl;
    float zr[16], zi[16], wr[16], wi[16], sre[16], sim[16];
    const float2* sbase = &states[((b*H + hh)*NCH + ch)*64 + DIR*32 + nh*16];
    const float* wrb = &W_re[((layer*2 + DIR)*H + hh)*NST + nh*16];
    const float* wib = &W_im[((layer*2 + DIR)*H + hh)*NST + nh*16];
    #pragma unroll
    for (int q = 0; q < 16; ++q) {
        float4 z4 = zw[hh*NST + nh*16 + q];
        zr[q] = z4.x; zi[q] = z4.y;
        wr[q] = wrb[q]; wi[q] = wib[q];
        float2 s = sbase[q];
        sre[q] = s.x; sim[q] = s.y;
    }
    const float* xrow = &xp[hl*2064 + ch*129];
    float* yrow = &yp[hl*2064 + ch*129];
    if (DIR == 0) {
        for (int t = 0; t < CHUNK; ++t) {
            float xv = xrow[t];
            float acc = 0.f;
            #pragma unroll
            for (int q = 0; q < 16; ++q) {
                float nre = fmaf(zr[q], sre[q], fmaf(-zi[q], sim[q], xv));
                float nim = fmaf(zr[q], sim[q], zi[q]*sre[q]);
                sre[q] = nre; sim[q] = nim;
                acc = fmaf(wr[q], nre, fmaf(-wi[q], nim, acc));
            }
            acc += __shfl_xor(acc, 16);
            if (nh == 0) yrow[t] = acc;
        }
    } else {
        for (int t = 0; t < CHUNK; ++t) {
            int tl = CHUNK - 1 - t;
            if (t > 0) {
                float xv = xrow[tl + 1];
                #pragma unroll
                for (int q = 0; q < 16; ++q) {
                    float nre = fmaf(zr[q], sre[q], fmaf(-zi[q], sim[q], xv));
                    float nim = fmaf(zr[q], sim[q], zi[q]*sre[q]);
                    sre[q] = nre; sim[q] = nim;
                }
            }
            float acc = 0.f;
            #pragma unroll
            for (int q = 0; q < 16; ++q)
                acc = fmaf(wr[q], sre[q], fmaf(-wi[q], sim[q], acc));
            acc += __shfl_xor(acc, 16);
            if (nh == 0) yrow[tl] = acc;
        }
    }
    __syncthreads();
    if (DIR == 0) {
        for (int j = tid; j < 2*2048; j += 64) {
            int hl2 = j >> 11, pos = j & 2047;
            y[(b*H + h0 + hl2)*L + pos] = yp[hl2*2064 + (pos>>7)*129 + (pos&127)];
        }
    } else {
        for (int j = tid; j < 2*2048; j += 64) {
            int hl2 = j >> 11, pos = j & 2047;
            int gi = (b*H + h0 + hl2)*L + pos;
            float xv = xp[hl2*2064 + (pos>>7)*129 + (pos&127)];
            float v = y[gi] + yp[hl2*2064 + (pos>>7)*129 + (pos&127)]
                    + Dv[layer*H + h0 + hl2] * xv;
            y[gi] = gelu_exact(v);
        }
    }
}

// ---------------- GLU ----------------
__global__ __launch_bounds__(256) void k_glu(const float* __restrict__ y,
        const float* __restrict__ wtg, const float* __restrict__ bias,
        float* __restrict__ z) {
    __shared__ float Ws[16*128];
    __shared__ float Ys[16*68];
    int tid = threadIdx.x;
    int lt = blockIdx.x, ot = blockIdx.y, b = blockIdx.z;
    int l0 = lt*64;
    float acc0[4][4] = {{0.f}}, acc1[4][4] = {{0.f}};
    for (int kc = 0; kc < 256; kc += 16) {
        __syncthreads();
        for (int j = tid; j < 2048; j += 256) {
            int kk = j >> 7, oo = j & 127;
            int o = ((oo >> 6) ? 256 : 0) + ot*64 + (oo & 63);
            Ws[kk*128 + oo] = wtg[(kc+kk)*512 + o];
        }
        for (int j = tid; j < 1024; j += 256) {
            int kk = j >> 6, ll = j & 63;
            Ys[kk*68 + ll] = y[(b*H + kc + kk)*L + l0 + ll];
        }
        __syncthreads();
        int to = tid >> 4, tl = tid & 15;
        #pragma unroll
        for (int kk = 0; kk < 16; ++kk) {
            float4 w0 = *(const float4*)&Ws[kk*128 + to*4];
            float4 w1 = *(const float4*)&Ws[kk*128 + 64 + to*4];
            float4 yv = *(const float4*)&Ys[kk*68 + tl*4];
            float wa[4]={w0.x,w0.y,w0.z,w0.w};
            float wb[4]={w1.x,w1.y,w1.z,w1.w};
            float yy[4]={yv.x,yv.y,yv.z,yv.w};
            #pragma unroll
            for (int r = 0; r < 4; ++r)
                #pragma unroll
                for (int c = 0; c < 4; ++c) {
                    acc0[r][c] = fmaf(wa[r], yy[c], acc0[r][c]);
                    acc1[r][c] = fmaf(wb[r], yy[c], acc1[r][c]);
                }
        }
    }
    int to = tid >> 4, tl = tid & 15;
    #pragma unroll
    for (int r = 0; r < 4; ++r) {
        int og = ot*64 + to*4 + r;
        float b0 = bias[og], b1 = bias[256 + og];
        float g0 = acc0[r][0] + b0, g1 = acc0[r][1] + b0;
        float g2 = acc0[r][2] + b0, g3 = acc0[r][3] + b0;
        float s0 = acc1[r][0] + b1, s1 = acc1[r][1] + b1;
        float s2 = acc1[r][2] + b1, s3 = acc1[r][3] + b1;
        float4 v;
        v.x = g0 / (1.f + expf(-s0));
        v.y = g1 / (1.f + expf(-s1));
        v.z = g2 / (1.f + expf(-s2));
        v.w = g3 / (1.f + expf(-s3));
        *(float4*)&z[(b*H + og)*L + l0 + tl*4] = v;
    }
}

// ---------------- LayerNorm ----------------
__global__ __launch_bounds__(256) void k_ln(const float* __restrict__ z,
        float* __restrict__ h, const float* __restrict__ g, const float* __restrict__ bb) {
    int tid = threadIdx.x;
    int b = blockIdx.y;
    int l0 = blockIdx.x * 256;
    int gi0 = b*H*L + l0 + tid;
    float sum = 0.f, ss = 0.f;
    for (int c = 0; c < H; ++c) {
        float v = z[gi0 + c*L] + h[gi0 + c*L];
        sum += v; ss = fmaf(v, v, ss);
    }
    float mu = sum * (1.f/H);
    float var = ss * (1.f/H) - mu*mu;
    float rs = rsqrtf(var + 1e-5f);
    for (int c = 0; c < H; ++c) {
        float v = z[gi0 + c*L] + h[gi0 + c*L];
        h[gi0 + c*L] = (v - mu) * rs * g[c] + bb[c];
    }
}

// ---------------- species embedding ----------------
__global__ void k_species(float* __restrict__ h, const int* __restrict__ xs,
        const float* __restrict__ emb, float* __restrict__ outseq) {
    int idx = blockIdx.x*256 + threadIdx.x;
    if (idx >= LSEQ) return;
    int c = (idx / L) % H;
    int b = idx / (H*L);
    float v = h[idx] + emb[xs[b]*H + c];
    h[idx] = v;
    outseq[idx] = v;
}

// ---------------- mean over L ----------------
__global__ __launch_bounds__(256) void k_agg(const float* __restrict__ h, float* __restrict__ agg) {
    __shared__ float red[256];
    int bc = blockIdx.x;
    int tid = threadIdx.x;
    float s = 0.f;
    for (int t = tid; t < L; t += 256) s += h[bc*L + t];
    red[tid] = s; __syncthreads();
    for (int k = 128; k > 0; k >>= 1) {
        if (tid < k) red[tid] += red[tid+k];
        __syncthreads();
    }
    if (tid == 0) agg[bc] = red[0] * (1.f/(float)L);
}

// ---------------- regression MLP ----------------
__global__ __launch_bounds__(128) void k_mlp(const float* __restrict__ agg,
        const float* __restrict__ w1, const float* __restrict__ b1,
        const float* __restrict__ w2, const float* __restrict__ b2,
        const float* __restrict__ w3, const float* __restrict__ b3,
        const float* __restrict__ w4, const float* __restrict__ b4,
        float* __restrict__ outreg) {
    __shared__ float a0[256], r1[128], r2[64], r3[32];
    int b = blockIdx.x, tid = threadIdx.x;
    a0[tid] = agg[b*256 + tid];
    a0[tid+128] = agg[b*256 + tid + 128];
    __syncthreads();
    {
        float s = b1[tid];
        for (int k = 0; k < 256; ++k) s = fmaf(w1[tid*256+k], a0[k], s);
        r1[tid] = s > 0.f ? s : expm1f(s);
    }
    __syncthreads();
    if (tid < 64) {
        float s = b2[tid];
        for (int k = 0; k < 128; ++k) s = fmaf(w2[tid*128+k], r1[k], s);
        r2[tid] = s > 0.f ? s : expm1f(s);
    }
    __syncthreads();
    if (tid < 32) {
        float s = b3[tid];
        for (int k = 0; k < 64; ++k) s = fmaf(w3[tid*64+k], r2[k], s);
        r3[tid] = s > 0.f ? s : expm1f(s);
    }
    __syncthreads();
    if (tid == 0) {
        float s = b4[0];
        for (int k = 0; k < 32; ++k) s = fmaf(w4[k], r3[k], s);
        outreg[b] = s;
    }
}

extern "C" void kernel_launch(void* const* d_in, const int* in_sizes, int n_in,
                              void* d_out, int out_size, void* d_ws, size_t ws_size,
                              hipStream_t stream) {
    const float* x      = (const float*)d_in[0];
    const int*   xs     = (const int*)d_in[1];
    const float* enc_w  = (const float*)d_in[2];
    const float* enc_b  = (const float*)d_in[3];
    const float* res_w1 = (const float*)d_in[4];
    const float* res_b1 = (const float*)d_in[5];
    const float* res_w2 = (const float*)d_in[6];
    const float* res_b2 = (const float*)d_in[7];
    const float* log_dt = (const float*)d_in[8];
    const float* lam_re = (const float*)d_in[9];
    const float* lam_im = (const float*)d_in[10];
    const float* W_re   = (const float*)d_in[11];
    const float* W_im   = (const float*)d_in[12];
    const float* Dv     = (const float*)d_in[13];
    const float* glu_w  = (const float*)d_in[14];
    const float* glu_b  = (const float*)d_in[15];
    const float* ln_g   = (const float*)d_in[16];
    const float* ln_b   = (const float*)d_in[17];
    const float* dec_w  = (const float*)d_in[18];
    const float* dec_b  = (const float*)d_in[19];
    const float* sp_emb = (const float*)d_in[20];
    const float* h1_w = (const float*)d_in[21]; const float* h1_b = (const float*)d_in[22];
    const float* h2_w = (const float*)d_in[23]; const float* h2_b = (const float*)d_in[24];
    const float* h3_w = (const float*)d_in[25]; const float* h3_b = (const float*)d_in[26];
    const float* h4_w = (const float*)d_in[27]; const float* h4_b = (const float*)d_in[28];

    float* ws   = (float*)d_ws;
    float* h    = ws;                                  // LSEQ f32 [b][c][l]
    float* t1   = ws + (size_t)LSEQ;                   // LSEQ f32
    float* t2   = ws + (size_t)2*LSEQ;                 // LSEQ f32 (states in DSS phase)
    float2* states = (float2*)t2;
    // res-phase aliases (dead once DSS starts):
    _Float16* xa  = (_Float16*)t1;                     // LSEQ fp16 (32MiB)
    _Float16* xb  = xa + (size_t)LSEQ;                 // LSEQ fp16 (32MiB)
    _Float16* wpk = (_Float16*)t2;                     // 6*3*65536 fp16
    float* wtg  = ws + (size_t)3*LSEQ;                 // 512*256
    float4* zwb = (float4*)(wtg + 512*256);            // H*NST float4
    float* aggb = wtg + 512*256 + H*NST*4;             // B*H

    float* outdec = (float*)d_out;
    float* outseq = outdec + B*DOUT*L;
    float* outreg = outseq + (size_t)LSEQ;

    // encoder conv
    k_conv15<<<dim3(L/512, H, B), 128, 0, stream>>>(x, enc_w, enc_b, h, DIN);

    // residual stack (fp16 MFMA, channel-last)
    k_wpack<<<(NRES*2*3*65536 + 255)/256, 256, 0, stream>>>(res_w1, res_w2, wpk);
    k_t_cl<<<dim3(L/64, H/64, B), 256, 0, stream>>>(h, xa);
    for (int r = 0; r < NRES; ++r) {
        k_cv3<false><<<dim3(B*L/128, 2), 256, 0, stream>>>(
            xa, wpk + (size_t)(r*2+0)*3*65536, res_b1 + r*H, nullptr, xb);
        k_cv3<true><<<dim3(B*L/128, 2), 256, 0, stream>>>(
            xb, wpk + (size_t)(r*2+1)*3*65536, res_b2 + r*H, xa, xa);
    }
    k_t_cf<<<dim3(L/64, H/64, B), 256, 0, stream>>>(xa, h);

    // DSS blocks
    for (int i = 0; i < NLAYERS; ++i) {
        k_zw<<<(H*NST + 255)/256, 256, 0, stream>>>(log_dt, lam_re, lam_im, zwb, i);
        k_wtg<<<(512*256 + 255)/256, 256, 0, stream>>>(glu_w, wtg, i);
        k_scan1<<<B*H*NCH, 64, 0, stream>>>(h, zwb, states);
        k_scan2<<<(B*H*64)/256, 256, 0, stream>>>(zwb, states);
        k_scan3<0><<<dim3(H/2, B), 64, 0, stream>>>(h, zwb, states, W_re, W_im, Dv, t1, i);
        k_scan3<1><<<dim3(H/2, B), 64, 0, stream>>>(h, zwb, states, W_re, W_im, Dv, t1, i);
        k_glu<<<dim3(L/64, H/64, B), 256, 0, stream>>>(t1, wtg, glu_b + i*512, t2);
        k_ln<<<dim3(L/256, B), 256, 0, stream>>>(t2, h, ln_g + i*H, ln_b + i*H);
    }

    // species embedding + outputs
    k_species<<<(LSEQ + 255)/256, 256, 0, stream>>>(h, xs, sp_emb, outseq);
    k_agg<<<B*H, 256, 0, stream>>>(h, aggb);
    k_mlp<<<B, 128, 0, stream>>>(aggb, h1_w, h1_b, h2_w, h2_b, h3_w, h3_b, h4_w, h4_b, outreg);
    k_conv15<<<dim3(L/512, DOUT, B), 128, 0, stream>>>(h, dec_w, dec_b, outdec, H);
}

// Round 4
// 2681.251 us; speedup vs baseline: 2.4441x; 1.6819x over previous
//
#include <hip/hip_runtime.h>
#include <math.h>

#define B 32
#define L 2048
#define DIN 5
#define DOUT 5
#define H 256
#define NST 32
#define NLAYERS 4
#define NRES 3
#define CHUNK 128
#define NCH 16            // L / CHUNK
#define LSEQ (B*H*L)      // 16777216

typedef __attribute__((ext_vector_type(8))) _Float16 half8;
typedef __attribute__((ext_vector_type(4))) float f32x4;

__device__ __forceinline__ float gelu_exact(float v) {
    return 0.5f * v * (1.0f + erff(v * 0.7071067811865475f));
}
#define SWZ(r) ((((r) ^ ((r) >> 2)) & 3))
#define LDIDX(l, c) ((l)*281 + ((c)>>5)*35 + ((c)&31))

// ---------------- conv K=15 pad=7 (encoder only now) ----------------
__global__ __launch_bounds__(128) void k_conv15(const float* __restrict__ in,
        const float* __restrict__ w, const float* __restrict__ bias,
        float* __restrict__ out, int Cin) {
    __shared__ float xs[8*528];
    const int tid = threadIdx.x;
    const int l0 = blockIdx.x * 512;
    const int o  = blockIdx.y;
    const int b  = blockIdx.z;
    const int Cout = gridDim.y;
    float acc[4] = {0.f,0.f,0.f,0.f};
    for (int c0 = 0; c0 < Cin; c0 += 8) {
        const int gn = (Cin - c0) < 8 ? (Cin - c0) : 8;
        __syncthreads();
        for (int j = tid; j < gn*526; j += 128) {
            int cl = j / 526, pos = j % 526;
            int gl = l0 + pos - 7;
            xs[cl*528 + pos] = (gl >= 0 && gl < L) ? in[(b*Cin + c0 + cl)*L + gl] : 0.f;
        }
        __syncthreads();
        for (int cl = 0; cl < gn; ++cl) {
            float xw[20];
            #pragma unroll
            for (int q = 0; q < 5; ++q) {
                float4 v = *(const float4*)&xs[cl*528 + tid*4 + q*4];
                xw[q*4+0]=v.x; xw[q*4+1]=v.y; xw[q*4+2]=v.z; xw[q*4+3]=v.w;
            }
            const float* wr = &w[(o*Cin + c0 + cl)*15];
            #pragma unroll
            for (int k = 0; k < 15; ++k) {
                float wk = wr[k];
                #pragma unroll
                for (int ll = 0; ll < 4; ++ll)
                    acc[ll] = fmaf(wk, xw[ll + k], acc[ll]);
            }
        }
    }
    float bo = bias[o];
    int gbase = (b*Cout + o)*L + l0 + tid*4;
    float4 v = {acc[0]+bo, acc[1]+bo, acc[2]+bo, acc[3]+bo};
    *(float4*)&out[gbase] = v;
}

// ---------------- weight pack: wpk[cv][k][o][ci] fp16 <- w[r][o][ci][k] ----------------
__global__ void k_wpack(const float* __restrict__ w1, const float* __restrict__ w2,
                        _Float16* __restrict__ wpk) {
    int idx = blockIdx.x*256 + threadIdx.x;
    if (idx >= NRES*2*3*65536) return;
    int ci = idx & 255;
    int o  = (idx >> 8) & 255;
    int k  = (idx >> 16) % 3;
    int cv = idx / (3*65536);
    const float* src = (cv & 1) ? w2 : w1;
    wpk[idx] = (_Float16)src[(((cv>>1)*H + o)*H + ci)*3 + k];
}

// ---------------- transpose f32 [b][c][l] -> fp16 channel-last [b*L][c] ----------------
__global__ __launch_bounds__(256) void k_t_cl(const float* __restrict__ in,
                                              _Float16* __restrict__ out) {
    __shared__ float t[64][65];
    int tid = threadIdx.x;
    int l0 = blockIdx.x*64, c0 = blockIdx.y*64, b = blockIdx.z;
    #pragma unroll
    for (int i = 0; i < 16; ++i) {
        int idx = i*256 + tid;
        int c = idx >> 6, l = idx & 63;
        t[c][l] = in[((size_t)(b*H + c0 + c))*L + l0 + l];
    }
    __syncthreads();
    #pragma unroll
    for (int i = 0; i < 16; ++i) {
        int idx = i*256 + tid;
        int l = idx >> 6, c = idx & 63;
        out[((size_t)b*L + l0 + l)*256 + c0 + c] = (_Float16)t[c][l];
    }
}

// ---------------- transpose fp16 channel-last [b*L][c] -> f32 [b][c][l] ----------------
__global__ __launch_bounds__(256) void k_t_cf(const _Float16* __restrict__ in,
                                              float* __restrict__ out) {
    __shared__ float t[64][65];
    int tid = threadIdx.x;
    int l0 = blockIdx.x*64, c0 = blockIdx.y*64, b = blockIdx.z;
    #pragma unroll
    for (int i = 0; i < 16; ++i) {
        int idx = i*256 + tid;
        int l = idx >> 6, c = idx & 63;
        t[c][l] = (float)in[((size_t)b*L + l0 + l)*256 + c0 + c];
    }
    __syncthreads();
    #pragma unroll
    for (int i = 0; i < 16; ++i) {
        int idx = i*256 + tid;
        int c = idx >> 6, l = idx & 63;
        out[((size_t)(b*H + c0 + c))*L + l0 + l] = t[c][l];
    }
}

// ---------------- MFMA residual conv K=3 (fp16) ----------------
template<bool RESID>
__global__ __launch_bounds__(256) void k_cv3(const _Float16* __restrict__ xin,
        const _Float16* __restrict__ wpk, const float* __restrict__ bias,
        const _Float16* __restrict__ resid, _Float16* __restrict__ out) {
    __shared__ _Float16 a_lds[128*32];
    __shared__ _Float16 b_lds[128*32];
    const int tid = threadIdx.x;
    const int mbase = blockIdx.x * 128;
    const int o0 = blockIdx.y * 128;
    const int lane = tid & 63;
    const int w = tid >> 6;
    const int wm = (w >> 1) * 64, wn = (w & 1) * 64;
    const int fr = lane & 15, kg = lane >> 4;

    const int r0s = tid >> 2, q0 = tid & 3;
    const int r1s = 64 + (tid >> 2);
    const int aw0 = r0s*32 + ((q0 ^ SWZ(r0s)) * 8);
    const int aw1 = r1s*32 + ((q0 ^ SWZ(r1s)) * 8);

    f32x4 acc[4][4];
    #pragma unroll
    for (int i = 0; i < 4; ++i)
        #pragma unroll
        for (int j = 0; j < 4; ++j)
            #pragma unroll
            for (int k = 0; k < 4; ++k) acc[i][j][k] = 0.f;

    uint4 pa0, pa1, pb0, pb1;
    auto loadstep = [&](int kk, uint4& a0, uint4& a1, uint4& b0, uint4& b1) {
        const int koff = kk >> 3, cic = kk & 7;
        const int cb = cic*32 + q0*8;
        {
            int m = mbase + r0s;
            int ll = (m & (L-1)) + koff - 1;
            a0 = (ll >= 0 && ll < L) ? *(const uint4*)&xin[((size_t)(m + koff - 1))*256 + cb]
                                     : make_uint4(0,0,0,0);
            int m1 = mbase + r1s;
            int l1 = (m1 & (L-1)) + koff - 1;
            a1 = (l1 >= 0 && l1 < L) ? *(const uint4*)&xin[((size_t)(m1 + koff - 1))*256 + cb]
                                     : make_uint4(0,0,0,0);
        }
        b0 = *(const uint4*)&wpk[((size_t)(koff*256 + o0 + r0s))*256 + cb];
        b1 = *(const uint4*)&wpk[((size_t)(koff*256 + o0 + r1s))*256 + cb];
    };
    loadstep(0, pa0, pa1, pb0, pb1);
    for (int kk = 0; kk < 24; ++kk) {
        __syncthreads();
        *(uint4*)&a_lds[aw0] = pa0;
        *(uint4*)&a_lds[aw1] = pa1;
        *(uint4*)&b_lds[aw0] = pb0;
        *(uint4*)&b_lds[aw1] = pb1;
        uint4 na0 = make_uint4(0,0,0,0), na1 = na0, nb0 = na0, nb1 = na0;
        if (kk < 23) loadstep(kk+1, na0, na1, nb0, nb1);
        __syncthreads();
        half8 af[4], bfr[4];
        #pragma unroll
        for (int mf = 0; mf < 4; ++mf) {
            int ra = wm + mf*16 + fr;
            af[mf] = *(const half8*)&a_lds[ra*32 + ((kg ^ SWZ(ra)) * 8)];
        }
        #pragma unroll
        for (int nf = 0; nf < 4; ++nf) {
            int rb = wn + nf*16 + fr;
            bfr[nf] = *(const half8*)&b_lds[rb*32 + ((kg ^ SWZ(rb)) * 8)];
        }
        #pragma unroll
        for (int mf = 0; mf < 4; ++mf)
            #pragma unroll
            for (int nf = 0; nf < 4; ++nf)
                acc[mf][nf] = __builtin_amdgcn_mfma_f32_16x16x32_f16(af[mf], bfr[nf], acc[mf][nf], 0, 0, 0);
        pa0 = na0; pa1 = na1; pb0 = nb0; pb1 = nb1;
    }
    const int orow = kg * 4;
    #pragma unroll
    for (int nf = 0; nf < 4; ++nf) {
        int o = o0 + wn + nf*16 + fr;
        float bo = bias[o];
        #pragma unroll
        for (int mf = 0; mf < 4; ++mf) {
            #pragma unroll
            for (int rg = 0; rg < 4; ++rg) {
                size_t m = (size_t)mbase + wm + mf*16 + orow + rg;
                float v = acc[mf][nf][rg] + bo;
                if (RESID) v += (float)resid[m*256 + o];
                v = fmaxf(v, 0.f);
                out[m*256 + o] = (_Float16)v;
            }
        }
    }
}

// ---------------- DSS: per-(h,n) discretized pole z and z^CHUNK ----------------
__global__ void k_zw(const float* __restrict__ log_dt, const float* __restrict__ lam_re,
                     const float* __restrict__ lam_im, float4* __restrict__ zwbuf, int layer) {
    int idx = blockIdx.x*256 + threadIdx.x;
    if (idx >= H*NST) return;
    int hh = idx / NST, n = idx % NST;
    float dt = expf(log_dt[layer*H + hh]);
    float a  = dt * lam_re[layer*NST + n];
    float bi = dt * lam_im[layer*NST + n];
    float er = expf(a);
    float zre = er * cosf(bi), zim = er * sinf(bi);
    float eC = expf(a * (float)CHUNK);
    float bC = bi * (float)CHUNK;
    float zcre = eC * cosf(bC), zcim = eC * sinf(bC);
    zwbuf[idx] = make_float4(zre, zim, zcre, zcim);
}

// ---------------- GLU weight pack fp16 (native o-major) ----------------
__global__ void k_wtg16(const float* __restrict__ gw, _Float16* __restrict__ wg, int layer) {
    int idx = blockIdx.x*256 + threadIdx.x;
    if (idx >= 512*256) return;
    wg[idx] = (_Float16)gw[layer*512*256 + idx];
}

// ---------------- decoder weight pack: pre-swizzled [cc][k][o16][32] fp16 ----------------
__global__ void k_wdec(const float* __restrict__ dw, _Float16* __restrict__ wdk) {
    int idx = blockIdx.x*256 + threadIdx.x;
    if (idx >= 15*16*256) return;
    int cfull = idx & 255;
    int o = (idx >> 8) & 15;
    int k = idx >> 12;
    float v = (o < DOUT) ? dw[(o*H + cfull)*15 + k] : 0.f;
    int cc = cfull >> 5, cl = cfull & 31;
    int cq = cl >> 3, cb = cl & 7;
    wdk[cc*7680 + (k*16 + o)*32 + ((cq ^ SWZ(o))*8) + cb] = (_Float16)v;
}

// ---------------- DSS scan phase 1 ----------------
__global__ __launch_bounds__(64) void k_scan1(const float* __restrict__ in,
        const float4* __restrict__ zw, float2* __restrict__ states) {
    __shared__ float xs[CHUNK];
    int tid = threadIdx.x;
    int ch = blockIdx.x % NCH;
    int hh = (blockIdx.x / NCH) % H;
    int b  = blockIdx.x / (NCH*H);
    const float* src = &in[(b*H + hh)*L + ch*CHUNK];
    for (int j = tid; j < CHUNK; j += 64) xs[j] = src[j];
    __syncthreads();
    int dir = tid >> 5, n = tid & 31;
    float4 z4 = zw[hh*NST + n];
    float zre = z4.x, zim = z4.y;
    float are = 0.f, aim = 0.f;
    for (int t = 0; t < CHUNK; t += 4) {
        float4 vf = *(const float4*)&xs[t];
        float4 vb = *(const float4*)&xs[CHUNK - 4 - t];
        float xv[4];
        if (dir == 0) { xv[0]=vf.x; xv[1]=vf.y; xv[2]=vf.z; xv[3]=vf.w; }
        else          { xv[0]=vb.w; xv[1]=vb.z; xv[2]=vb.y; xv[3]=vb.x; }
        #pragma unroll
        for (int q = 0; q < 4; ++q) {
            float nre = fmaf(zre, are, fmaf(-zim, aim, xv[q]));
            float nim = fmaf(zre, aim, zim * are);
            are = nre; aim = nim;
        }
    }
    states[((b*H + hh)*NCH + ch)*64 + tid] = make_float2(are, aim);
}

// ---------------- DSS scan phase 2 ----------------
__global__ void k_scan2(const float4* __restrict__ zw, float2* __restrict__ states) {
    int idx = blockIdx.x*256 + threadIdx.x;
    int dn = idx & 63;
    int bh = idx >> 6;
    int hh = bh % H;
    int n = dn & 31, dir = dn >> 5;
    float4 z4 = zw[hh*NST + n];
    float zcre = z4.z, zcim = z4.w;
    float2* base = &states[bh*NCH*64 + dn];
    float pre = 0.f, pim = 0.f;
    if (dir == 0) {
        for (int ch = 0; ch < NCH; ++ch) {
            float2 cur = base[ch*64];
            base[ch*64] = make_float2(pre, pim);
            float nre = fmaf(zcre, pre, fmaf(-zcim, pim, cur.x));
            float nim = fmaf(zcre, pim, fmaf(zcim, pre, cur.y));
            pre = nre; pim = nim;
        }
    } else {
        for (int ch = NCH-1; ch >= 0; --ch) {
            float2 cur = base[ch*64];
            base[ch*64] = make_float2(pre, pim);
            float nre = fmaf(zcre, pre, fmaf(-zcim, pim, cur.x));
            float nim = fmaf(zcre, pim, fmaf(zcim, pre, cur.y));
            pre = nre; pim = nim;
        }
    }
}

// ---------------- DSS scan phase 3: fwd+bwd merged (dir = wave), fused D*x + gelu ----------------
__global__ __launch_bounds__(128) void k_scan3m(const float* __restrict__ in,
        const float4* __restrict__ zw, const float2* __restrict__ states,
        const float* __restrict__ W_re, const float* __restrict__ W_im,
        const float* __restrict__ Dv, float* __restrict__ y, int layer) {
    __shared__ float xp[2*2064];
    __shared__ float ypf[2*2064];
    __shared__ float ypb[2*2064];
    int tid = threadIdx.x;
    int b = blockIdx.y;
    int h0 = blockIdx.x * 2;
    for (int j = tid; j < 2*2048; j += 128) {
        int hl = j >> 11, pos = j & 2047;
        xp[hl*2064 + (pos>>7)*129 + (pos&127)] = in[(b*H + h0 + hl)*L + pos];
    }
    __syncthreads();
    int dir = tid >> 6;          // wave-uniform
    int lane = tid & 63;
    int hl = lane >> 5, nh = (lane >> 4) & 1, ch = lane & 15;
    int hh = h0 + hl;
    float zr[16], zi[16], wr[16], wi[16], sre[16], sim[16];
    const float2* sbase = &states[((b*H + hh)*NCH + ch)*64 + dir*32 + nh*16];
    const float* wrb = &W_re[((layer*2 + dir)*H + hh)*NST + nh*16];
    const float* wib = &W_im[((layer*2 + dir)*H + hh)*NST + nh*16];
    #pragma unroll
    for (int q = 0; q < 16; ++q) {
        float4 z4 = zw[hh*NST + nh*16 + q];
        zr[q] = z4.x; zi[q] = z4.y;
        wr[q] = wrb[q]; wi[q] = wib[q];
        float2 s = sbase[q];
        sre[q] = s.x; sim[q] = s.y;
    }
    const float* xrow = &xp[hl*2064 + ch*129];
    float* yrow = dir ? &ypb[hl*2064 + ch*129] : &ypf[hl*2064 + ch*129];
    if (dir == 0) {
        for (int t = 0; t < CHUNK; ++t) {
            float xv = xrow[t];
            float acc = 0.f;
            #pragma unroll
            for (int q = 0; q < 16; ++q) {
                float nre = fmaf(zr[q], sre[q], fmaf(-zi[q], sim[q], xv));
                float nim = fmaf(zr[q], sim[q], zi[q]*sre[q]);
                sre[q] = nre; sim[q] = nim;
                acc = fmaf(wr[q], nre, fmaf(-wi[q], nim, acc));
            }
            acc += __shfl_xor(acc, 16);
            if (nh == 0) yrow[t] = acc;
        }
    } else {
        for (int t = 0; t < CHUNK; ++t) {
            int tl = CHUNK - 1 - t;
            if (t > 0) {
                float xv = xrow[tl + 1];
                #pragma unroll
                for (int q = 0; q < 16; ++q) {
                    float nre = fmaf(zr[q], sre[q], fmaf(-zi[q], sim[q], xv));
                    float nim = fmaf(zr[q], sim[q], zi[q]*sre[q]);
                    sre[q] = nre; sim[q] = nim;
                }
            }
            float acc = 0.f;
            #pragma unroll
            for (int q = 0; q < 16; ++q)
                acc = fmaf(wr[q], sre[q], fmaf(-wi[q], sim[q], acc));
            acc += __shfl_xor(acc, 16);
            if (nh == 0) yrow[tl] = acc;
        }
    }
    __syncthreads();
    float dv0 = Dv[layer*H + h0], dv1 = Dv[layer*H + h0 + 1];
    for (int j = tid; j < 2*2048; j += 128) {
        int hl2 = j >> 11, pos = j & 2047;
        int ip = hl2*2064 + (pos>>7)*129 + (pos&127);
        float v = ypf[ip] + ypb[ip] + (hl2 ? dv1 : dv0) * xp[ip];
        y[(b*H + h0 + hl2)*L + pos] = gelu_exact(v);
    }
}

// ---------------- GLU MFMA fp16: both halves per block, fused sigmoid ----------------
// A = yt (chl fp16, M=B*L x 256), B rows 0-63 gate / 64-127 sig. Tile 128m x 64o(x2).
__global__ __launch_bounds__(256) void k_glu16(const _Float16* __restrict__ yt,
        const _Float16* __restrict__ wg, const float* __restrict__ bias,
        float* __restrict__ zc) {
    __shared__ _Float16 a_lds[128*32];
    __shared__ _Float16 b_lds[128*32];
    const int tid = threadIdx.x;
    const int mbase = blockIdx.x * 128;
    const int o0 = blockIdx.y * 64;
    const int lane = tid & 63;
    const int w = tid >> 6;
    const int wm = (w >> 1) * 64, wn = (w & 1) * 32;
    const int fr = lane & 15, kg = lane >> 4;
    const int r0s = tid >> 2, q0 = tid & 3;
    const int r1s = 64 + r0s;
    const int aw0 = r0s*32 + ((q0 ^ SWZ(r0s)) * 8);
    const int aw1 = r1s*32 + ((q0 ^ SWZ(r1s)) * 8);
    const int og0 = o0 + r0s;
    const int og1 = 256 + o0 + r0s;

    f32x4 accg[4][2], accs[4][2];
    #pragma unroll
    for (int i = 0; i < 4; ++i)
        #pragma unroll
        for (int j = 0; j < 2; ++j)
            #pragma unroll
            for (int k = 0; k < 4; ++k) { accg[i][j][k] = 0.f; accs[i][j][k] = 0.f; }

    uint4 pa0, pa1, pb0, pb1;
    auto loadstep = [&](int kc, uint4& a0, uint4& a1, uint4& b0, uint4& b1) {
        const int cb = kc*32 + q0*8;
        a0 = *(const uint4*)&yt[((size_t)(mbase + r0s))*256 + cb];
        a1 = *(const uint4*)&yt[((size_t)(mbase + r1s))*256 + cb];
        b0 = *(const uint4*)&wg[((size_t)og0)*256 + cb];
        b1 = *(const uint4*)&wg[((size_t)og1)*256 + cb];
    };
    loadstep(0, pa0, pa1, pb0, pb1);
    for (int kc = 0; kc < 8; ++kc) {
        __syncthreads();
        *(uint4*)&a_lds[aw0] = pa0;
        *(uint4*)&a_lds[aw1] = pa1;
        *(uint4*)&b_lds[aw0] = pb0;
        *(uint4*)&b_lds[aw1] = pb1;
        uint4 na0 = make_uint4(0,0,0,0), na1 = na0, nb0 = na0, nb1 = na0;
        if (kc < 7) loadstep(kc+1, na0, na1, nb0, nb1);
        __syncthreads();
        half8 af[4], bg[2], bs[2];
        #pragma unroll
        for (int mf = 0; mf < 4; ++mf) {
            int ra = wm + mf*16 + fr;
            af[mf] = *(const half8*)&a_lds[ra*32 + ((kg ^ SWZ(ra)) * 8)];
        }
        #pragma unroll
        for (int nf = 0; nf < 2; ++nf) {
            int rb = wn + nf*16 + fr;
            bg[nf] = *(const half8*)&b_lds[rb*32 + ((kg ^ SWZ(rb)) * 8)];
            int rb2 = 64 + rb;
            bs[nf] = *(const half8*)&b_lds[rb2*32 + ((kg ^ SWZ(rb2)) * 8)];
        }
        #pragma unroll
        for (int mf = 0; mf < 4; ++mf)
            #pragma unroll
            for (int nf = 0; nf < 2; ++nf) {
                accg[mf][nf] = __builtin_amdgcn_mfma_f32_16x16x32_f16(af[mf], bg[nf], accg[mf][nf], 0, 0, 0);
                accs[mf][nf] = __builtin_amdgcn_mfma_f32_16x16x32_f16(af[mf], bs[nf], accs[mf][nf], 0, 0, 0);
            }
        pa0 = na0; pa1 = na1; pb0 = nb0; pb1 = nb1;
    }
    #pragma unroll
    for (int nf = 0; nf < 2; ++nf) {
        int o = o0 + wn + nf*16 + fr;
        float b0v = bias[o], b1v = bias[256 + o];
        #pragma unroll
        for (int mf = 0; mf < 4; ++mf) {
            #pragma unroll
            for (int rg = 0; rg < 4; ++rg) {
                size_t m = (size_t)mbase + wm + mf*16 + kg*4 + rg;
                float g = accg[mf][nf][rg] + b0v;
                float s = accs[mf][nf][rg] + b1v;
                zc[m*256 + o] = g / (1.f + expf(-s));
            }
        }
    }
}

// ---------------- LayerNorm channel-last z + staged chm residual -> chm h ----------------
__global__ __launch_bounds__(256) void k_ln2(const float* __restrict__ zc,
        float* __restrict__ h, const float* __restrict__ g, const float* __restrict__ bb) {
    __shared__ float tl[8992];
    int tid = threadIdx.x;
    int b = blockIdx.y;
    int l0 = blockIdx.x * 32;
    for (int j = tid; j < 32*256; j += 256) {
        int c = j >> 5, l = j & 31;
        tl[LDIDX(l, c)] = h[((size_t)(b*H + c))*L + l0 + l];
    }
    __syncthreads();
    int r = tid >> 3, p = tid & 7;
    float v[32];
    float sum = 0.f, ss = 0.f;
    const float* zrow = &zc[((size_t)(b*L + l0 + r))*256 + p*32];
    #pragma unroll
    for (int q = 0; q < 8; ++q) {
        float4 z4 = *(const float4*)&zrow[q*4];
        float zz[4] = {z4.x, z4.y, z4.z, z4.w};
        #pragma unroll
        for (int i = 0; i < 4; ++i) {
            float hv = tl[LDIDX(r, p*32 + q*4 + i)];
            float vv = zz[i] + hv;
            v[q*4+i] = vv;
            sum += vv; ss = fmaf(vv, vv, ss);
        }
    }
    sum += __shfl_xor(sum, 1); ss += __shfl_xor(ss, 1);
    sum += __shfl_xor(sum, 2); ss += __shfl_xor(ss, 2);
    sum += __shfl_xor(sum, 4); ss += __shfl_xor(ss, 4);
    float mu = sum * (1.f/256.f);
    float var = ss * (1.f/256.f) - mu*mu;
    float rs = rsqrtf(var + 1e-5f);
    #pragma unroll
    for (int q = 0; q < 32; ++q) {
        int c = p*32 + q;
        tl[LDIDX(r, c)] = (v[q] - mu) * rs * g[c] + bb[c];
    }
    __syncthreads();
    for (int j = tid; j < 32*256; j += 256) {
        int c = j >> 5, l = j & 31;
        h[((size_t)(b*H + c))*L + l0 + l] = tl[LDIDX(l, c)];
    }
}

// ---------------- MFMA decoder conv K=15: ht (chl fp16) -> outdec ----------------
__global__ __launch_bounds__(128) void k_dec(const _Float16* __restrict__ ht,
        const _Float16* __restrict__ wdk, const float* __restrict__ bias,
        float* __restrict__ outdec) {
    __shared__ _Float16 a_lds[160*32];
    __shared__ _Float16 b_lds[15*16*32];
    const int tid = threadIdx.x;
    const int mbase = blockIdx.x * 128;
    const int b = mbase >> 11;
    const int lbase = mbase & 2047;
    const int lane = tid & 63;
    const int w = tid >> 6;
    const int fr = lane & 15, kg = lane >> 4;
    const int rs = tid >> 2, q0 = tid & 3;
    f32x4 acc[4];
    #pragma unroll
    for (int i = 0; i < 4; ++i)
        #pragma unroll
        for (int k = 0; k < 4; ++k) acc[i][k] = 0.f;
    for (int cc = 0; cc < 8; ++cc) {
        __syncthreads();
        #pragma unroll
        for (int ps = 0; ps < 5; ++ps) {
            int r = ps*32 + rs;
            if (r < 142) {
                int l = lbase - 7 + r;
                uint4 v = (l >= 0 && l < L) ? *(const uint4*)&ht[((size_t)(b*L + l))*256 + cc*32 + q0*8]
                                            : make_uint4(0,0,0,0);
                *(uint4*)&a_lds[r*32 + ((q0 ^ SWZ(r))*8)] = v;
            }
        }
        for (int jj = tid; jj < 960; jj += 128)
            *(uint4*)&b_lds[jj*8] = *(const uint4*)&wdk[cc*7680 + jj*8];
        __syncthreads();
        #pragma unroll
        for (int k = 0; k < 15; ++k) {
            half8 bfr = *(const half8*)&b_lds[(k*16 + fr)*32 + ((kg ^ SWZ(fr))*8)];
            #pragma unroll
            for (int mf = 0; mf < 4; ++mf) {
                int ra = w*64 + mf*16 + fr + k;
                half8 af = *(const half8*)&a_lds[ra*32 + ((kg ^ SWZ(ra))*8)];
                acc[mf] = __builtin_amdgcn_mfma_f32_16x16x32_f16(af, bfr, acc[mf], 0, 0, 0);
            }
        }
    }
    if (fr < DOUT) {
        float bo = bias[fr];
        #pragma unroll
        for (int mf = 0; mf < 4; ++mf)
            #pragma unroll
            for (int rg = 0; rg < 4; ++rg) {
                int m = mbase + w*64 + mf*16 + kg*4 + rg;
                outdec[((size_t)(b*DOUT + fr))*L + (m & 2047)] = acc[mf][rg] + bo;
            }
    }
}

// ---------------- species embedding ----------------
__global__ void k_species(float* __restrict__ h, const int* __restrict__ xs,
        const float* __restrict__ emb, float* __restrict__ outseq) {
    int idx = blockIdx.x*256 + threadIdx.x;
    if (idx >= LSEQ) return;
    int c = (idx / L) % H;
    int b = idx / (H*L);
    float v = h[idx] + emb[xs[b]*H + c];
    h[idx] = v;
    outseq[idx] = v;
}

// ---------------- mean over L ----------------
__global__ __launch_bounds__(256) void k_agg(const float* __restrict__ h, float* __restrict__ agg) {
    __shared__ float red[256];
    int bc = blockIdx.x;
    int tid = threadIdx.x;
    float s = 0.f;
    for (int t = tid; t < L; t += 256) s += h[bc*L + t];
    red[tid] = s; __syncthreads();
    for (int k = 128; k > 0; k >>= 1) {
        if (tid < k) red[tid] += red[tid+k];
        __syncthreads();
    }
    if (tid == 0) agg[bc] = red[0] * (1.f/(float)L);
}

// ---------------- regression MLP ----------------
__global__ __launch_bounds__(128) void k_mlp(const float* __restrict__ agg,
        const float* __restrict__ w1, const float* __restrict__ b1,
        const float* __restrict__ w2, const float* __restrict__ b2,
        const float* __restrict__ w3, const float* __restrict__ b3,
        const float* __restrict__ w4, const float* __restrict__ b4,
        float* __restrict__ outreg) {
    __shared__ float a0[256], r1[128], r2[64], r3[32];
    int b = blockIdx.x, tid = threadIdx.x;
    a0[tid] = agg[b*256 + tid];
    a0[tid+128] = agg[b*256 + tid + 128];
    __syncthreads();
    {
        float s = b1[tid];
        for (int k = 0; k < 256; ++k) s = fmaf(w1[tid*256+k], a0[k], s);
        r1[tid] = s > 0.f ? s : expm1f(s);
    }
    __syncthreads();
    if (tid < 64) {
        float s = b2[tid];
        for (int k = 0; k < 128; ++k) s = fmaf(w2[tid*128+k], r1[k], s);
        r2[tid] = s > 0.f ? s : expm1f(s);
    }
    __syncthreads();
    if (tid < 32) {
        float s = b3[tid];
        for (int k = 0; k < 64; ++k) s = fmaf(w3[tid*64+k], r2[k], s);
        r3[tid] = s > 0.f ? s : expm1f(s);
    }
    __syncthreads();
    if (tid == 0) {
        float s = b4[0];
        for (int k = 0; k < 32; ++k) s = fmaf(w4[k], r3[k], s);
        outreg[b] = s;
    }
}

extern "C" void kernel_launch(void* const* d_in, const int* in_sizes, int n_in,
                              void* d_out, int out_size, void* d_ws, size_t ws_size,
                              hipStream_t stream) {
    const float* x      = (const float*)d_in[0];
    const int*   xs     = (const int*)d_in[1];
    const float* enc_w  = (const float*)d_in[2];
    const float* enc_b  = (const float*)d_in[3];
    const float* res_w1 = (const float*)d_in[4];
    const float* res_b1 = (const float*)d_in[5];
    const float* res_w2 = (const float*)d_in[6];
    const float* res_b2 = (const float*)d_in[7];
    const float* log_dt = (const float*)d_in[8];
    const float* lam_re = (const float*)d_in[9];
    const float* lam_im = (const float*)d_in[10];
    const float* W_re   = (const float*)d_in[11];
    const float* W_im   = (const float*)d_in[12];
    const float* Dv     = (const float*)d_in[13];
    const float* glu_w  = (const float*)d_in[14];
    const float* glu_b  = (const float*)d_in[15];
    const float* ln_g   = (const float*)d_in[16];
    const float* ln_b   = (const float*)d_in[17];
    const float* dec_w  = (const float*)d_in[18];
    const float* dec_b  = (const float*)d_in[19];
    const float* sp_emb = (const float*)d_in[20];
    const float* h1_w = (const float*)d_in[21]; const float* h1_b = (const float*)d_in[22];
    const float* h2_w = (const float*)d_in[23]; const float* h2_b = (const float*)d_in[24];
    const float* h3_w = (const float*)d_in[25]; const float* h3_b = (const float*)d_in[26];
    const float* h4_w = (const float*)d_in[27]; const float* h4_b = (const float*)d_in[28];

    float* ws   = (float*)d_ws;
    float* h    = ws;                                  // LSEQ f32 [b][c][l]
    float* t1   = ws + (size_t)LSEQ;                   // LSEQ f32: y, then zc
    float* t2   = ws + (size_t)2*LSEQ;                 // LSEQ f32: states, then yt (upper half)
    float2* states = (float2*)t2;                      // exactly LSEQ f32
    // res-phase aliases (dead once DSS starts):
    _Float16* xa  = (_Float16*)t1;
    _Float16* xb  = xa + (size_t)LSEQ;
    _Float16* wpk = (_Float16*)t2;
    // DSS-phase aliases:
    _Float16* yt  = (_Float16*)t2 + (size_t)LSEQ;      // upper half of t2, fp16 chl y
    float* zcb    = t1;                                // glu output, chl f32
    // tail region:
    float* tail = ws + (size_t)3*LSEQ;
    _Float16* wg  = (_Float16*)tail;                   // 512*256 fp16 (65536 f32 slots)
    float4* zwb = (float4*)(tail + 65536);             // H*NST float4 (32768 f32)
    float* aggb = tail + 65536 + 32768;                // B*H
    _Float16* wdk = (_Float16*)(aggb + 8192);          // 61440 fp16 (30720 f32 slots)

    float* outdec = (float*)d_out;
    float* outseq = outdec + B*DOUT*L;
    float* outreg = outseq + (size_t)LSEQ;

    // encoder conv
    k_conv15<<<dim3(L/512, H, B), 128, 0, stream>>>(x, enc_w, enc_b, h, DIN);

    // residual stack (fp16 MFMA, channel-last)
    k_wpack<<<(NRES*2*3*65536 + 255)/256, 256, 0, stream>>>(res_w1, res_w2, wpk);
    k_t_cl<<<dim3(L/64, H/64, B), 256, 0, stream>>>(h, xa);
    for (int r = 0; r < NRES; ++r) {
        k_cv3<false><<<dim3(B*L/128, 2), 256, 0, stream>>>(
            xa, wpk + (size_t)(r*2+0)*3*65536, res_b1 + r*H, nullptr, xb);
        k_cv3<true><<<dim3(B*L/128, 2), 256, 0, stream>>>(
            xb, wpk + (size_t)(r*2+1)*3*65536, res_b2 + r*H, xa, xa);
    }
    k_t_cf<<<dim3(L/64, H/64, B), 256, 0, stream>>>(xa, h);

    // DSS blocks
    for (int i = 0; i < NLAYERS; ++i) {
        k_zw<<<(H*NST + 255)/256, 256, 0, stream>>>(log_dt, lam_re, lam_im, zwb, i);
        k_wtg16<<<(512*256 + 255)/256, 256, 0, stream>>>(glu_w, wg, i);
        k_scan1<<<B*H*NCH, 64, 0, stream>>>(h, zwb, states);
        k_scan2<<<(B*H*64)/256, 256, 0, stream>>>(zwb, states);
        k_scan3m<<<dim3(H/2, B), 128, 0, stream>>>(h, zwb, states, W_re, W_im, Dv, t1, i);
        k_t_cl<<<dim3(L/64, H/64, B), 256, 0, stream>>>(t1, yt);
        k_glu16<<<dim3(B*L/128, 4), 256, 0, stream>>>(yt, wg, glu_b + i*512, zcb);
        k_ln2<<<dim3(L/32, B), 256, 0, stream>>>(zcb, h, ln_g + i*H, ln_b + i*H);
    }

    // species embedding + outputs
    k_species<<<(LSEQ + 255)/256, 256, 0, stream>>>(h, xs, sp_emb, outseq);
    k_agg<<<B*H, 256, 0, stream>>>(h, aggb);
    k_mlp<<<B, 128, 0, stream>>>(aggb, h1_w, h1_b, h2_w, h2_b, h3_w, h3_b, h4_w, h4_b, outreg);
    // decoder: transpose final h -> fp16 chl, then MFMA conv
    k_t_cl<<<dim3(L/64, H/64, B), 256, 0, stream>>>(h, (_Float16*)t1);
    k_wdec<<<(15*16*256 + 255)/256, 256, 0, stream>>>(dec_w, wdk);
    k_dec<<<B*L/128, 128, 0, stream>>>((_Float16*)t1, wdk, dec_b, outdec);
}

// Round 5
// 1982.552 us; speedup vs baseline: 3.3054x; 1.3524x over previous
//
#include <hip/hip_runtime.h>
#include <math.h>

#define B 32
#define L 2048
#define DIN 5
#define DOUT 5
#define H 256
#define NST 32
#define NLAYERS 4
#define NRES 3
#define CHUNK 128
#define NCH 16            // L / CHUNK
#define LSEQ (B*H*L)      // 16777216

typedef __attribute__((ext_vector_type(8))) _Float16 half8;
typedef __attribute__((ext_vector_type(4))) float f32x4;

__device__ __forceinline__ float gelu_exact(float v) {
    return 0.5f * v * (1.0f + erff(v * 0.7071067811865475f));
}
#define SWZ(r) ((((r) ^ ((r) >> 2)) & 3))
#define LDIDX(l, c) ((l)*281 + ((c)>>5)*35 + ((c)&31))

// ---------------- conv K=15 pad=7 (encoder only) ----------------
__global__ __launch_bounds__(128) void k_conv15(const float* __restrict__ in,
        const float* __restrict__ w, const float* __restrict__ bias,
        float* __restrict__ out, int Cin) {
    __shared__ float xs[8*528];
    const int tid = threadIdx.x;
    const int l0 = blockIdx.x * 512;
    const int o  = blockIdx.y;
    const int b  = blockIdx.z;
    const int Cout = gridDim.y;
    float acc[4] = {0.f,0.f,0.f,0.f};
    for (int c0 = 0; c0 < Cin; c0 += 8) {
        const int gn = (Cin - c0) < 8 ? (Cin - c0) : 8;
        __syncthreads();
        for (int j = tid; j < gn*526; j += 128) {
            int cl = j / 526, pos = j % 526;
            int gl = l0 + pos - 7;
            xs[cl*528 + pos] = (gl >= 0 && gl < L) ? in[(b*Cin + c0 + cl)*L + gl] : 0.f;
        }
        __syncthreads();
        for (int cl = 0; cl < gn; ++cl) {
            float xw[20];
            #pragma unroll
            for (int q = 0; q < 5; ++q) {
                float4 v = *(const float4*)&xs[cl*528 + tid*4 + q*4];
                xw[q*4+0]=v.x; xw[q*4+1]=v.y; xw[q*4+2]=v.z; xw[q*4+3]=v.w;
            }
            const float* wr = &w[(o*Cin + c0 + cl)*15];
            #pragma unroll
            for (int k = 0; k < 15; ++k) {
                float wk = wr[k];
                #pragma unroll
                for (int ll = 0; ll < 4; ++ll)
                    acc[ll] = fmaf(wk, xw[ll + k], acc[ll]);
            }
        }
    }
    float bo = bias[o];
    int gbase = (b*Cout + o)*L + l0 + tid*4;
    float4 v = {acc[0]+bo, acc[1]+bo, acc[2]+bo, acc[3]+bo};
    *(float4*)&out[gbase] = v;
}

// ---------------- weight pack: wpk[cv][k][o][ci] fp16 <- w[r][o][ci][k] ----------------
__global__ void k_wpack(const float* __restrict__ w1, const float* __restrict__ w2,
                        _Float16* __restrict__ wpk) {
    int idx = blockIdx.x*256 + threadIdx.x;
    if (idx >= NRES*2*3*65536) return;
    int ci = idx & 255;
    int o  = (idx >> 8) & 255;
    int k  = (idx >> 16) % 3;
    int cv = idx / (3*65536);
    const float* src = (cv & 1) ? w2 : w1;
    wpk[idx] = (_Float16)src[(((cv>>1)*H + o)*H + ci)*3 + k];
}

// ---------------- transpose f32 [b][c][l] -> fp16 channel-last [b*L][c] ----------------
__global__ __launch_bounds__(256) void k_t_cl(const float* __restrict__ in,
                                              _Float16* __restrict__ out) {
    __shared__ float t[64][65];
    int tid = threadIdx.x;
    int l0 = blockIdx.x*64, c0 = blockIdx.y*64, b = blockIdx.z;
    #pragma unroll
    for (int i = 0; i < 16; ++i) {
        int idx = i*256 + tid;
        int c = idx >> 6, l = idx & 63;
        t[c][l] = in[((size_t)(b*H + c0 + c))*L + l0 + l];
    }
    __syncthreads();
    #pragma unroll
    for (int i = 0; i < 16; ++i) {
        int idx = i*256 + tid;
        int l = idx >> 6, c = idx & 63;
        out[((size_t)b*L + l0 + l)*256 + c0 + c] = (_Float16)t[c][l];
    }
}

// ---------------- transpose fp16 channel-last [b*L][c] -> f32 [b][c][l] ----------------
__global__ __launch_bounds__(256) void k_t_cf(const _Float16* __restrict__ in,
                                              float* __restrict__ out) {
    __shared__ float t[64][65];
    int tid = threadIdx.x;
    int l0 = blockIdx.x*64, c0 = blockIdx.y*64, b = blockIdx.z;
    #pragma unroll
    for (int i = 0; i < 16; ++i) {
        int idx = i*256 + tid;
        int l = idx >> 6, c = idx & 63;
        t[c][l] = (float)in[((size_t)b*L + l0 + l)*256 + c0 + c];
    }
    __syncthreads();
    #pragma unroll
    for (int i = 0; i < 16; ++i) {
        int idx = i*256 + tid;
        int c = idx >> 6, l = idx & 63;
        out[((size_t)(b*H + c0 + c))*L + l0 + l] = t[c][l];
    }
}

// ---------------- MFMA residual conv K=3 (fp16) ----------------
template<bool RESID>
__global__ __launch_bounds__(256) void k_cv3(const _Float16* __restrict__ xin,
        const _Float16* __restrict__ wpk, const float* __restrict__ bias,
        const _Float16* __restrict__ resid, _Float16* __restrict__ out) {
    __shared__ _Float16 a_lds[128*32];
    __shared__ _Float16 b_lds[128*32];
    const int tid = threadIdx.x;
    const int mbase = blockIdx.x * 128;
    const int o0 = blockIdx.y * 128;
    const int lane = tid & 63;
    const int w = tid >> 6;
    const int wm = (w >> 1) * 64, wn = (w & 1) * 64;
    const int fr = lane & 15, kg = lane >> 4;

    const int r0s = tid >> 2, q0 = tid & 3;
    const int r1s = 64 + (tid >> 2);
    const int aw0 = r0s*32 + ((q0 ^ SWZ(r0s)) * 8);
    const int aw1 = r1s*32 + ((q0 ^ SWZ(r1s)) * 8);

    f32x4 acc[4][4];
    #pragma unroll
    for (int i = 0; i < 4; ++i)
        #pragma unroll
        for (int j = 0; j < 4; ++j)
            #pragma unroll
            for (int k = 0; k < 4; ++k) acc[i][j][k] = 0.f;

    uint4 pa0, pa1, pb0, pb1;
    auto loadstep = [&](int kk, uint4& a0, uint4& a1, uint4& b0, uint4& b1) {
        const int koff = kk >> 3, cic = kk & 7;
        const int cb = cic*32 + q0*8;
        {
            int m = mbase + r0s;
            int ll = (m & (L-1)) + koff - 1;
            a0 = (ll >= 0 && ll < L) ? *(const uint4*)&xin[((size_t)(m + koff - 1))*256 + cb]
                                     : make_uint4(0,0,0,0);
            int m1 = mbase + r1s;
            int l1 = (m1 & (L-1)) + koff - 1;
            a1 = (l1 >= 0 && l1 < L) ? *(const uint4*)&xin[((size_t)(m1 + koff - 1))*256 + cb]
                                     : make_uint4(0,0,0,0);
        }
        b0 = *(const uint4*)&wpk[((size_t)(koff*256 + o0 + r0s))*256 + cb];
        b1 = *(const uint4*)&wpk[((size_t)(koff*256 + o0 + r1s))*256 + cb];
    };
    loadstep(0, pa0, pa1, pb0, pb1);
    for (int kk = 0; kk < 24; ++kk) {
        __syncthreads();
        *(uint4*)&a_lds[aw0] = pa0;
        *(uint4*)&a_lds[aw1] = pa1;
        *(uint4*)&b_lds[aw0] = pb0;
        *(uint4*)&b_lds[aw1] = pb1;
        uint4 na0 = make_uint4(0,0,0,0), na1 = na0, nb0 = na0, nb1 = na0;
        if (kk < 23) loadstep(kk+1, na0, na1, nb0, nb1);
        __syncthreads();
        half8 af[4], bfr[4];
        #pragma unroll
        for (int mf = 0; mf < 4; ++mf) {
            int ra = wm + mf*16 + fr;
            af[mf] = *(const half8*)&a_lds[ra*32 + ((kg ^ SWZ(ra)) * 8)];
        }
        #pragma unroll
        for (int nf = 0; nf < 4; ++nf) {
            int rb = wn + nf*16 + fr;
            bfr[nf] = *(const half8*)&b_lds[rb*32 + ((kg ^ SWZ(rb)) * 8)];
        }
        #pragma unroll
        for (int mf = 0; mf < 4; ++mf)
            #pragma unroll
            for (int nf = 0; nf < 4; ++nf)
                acc[mf][nf] = __builtin_amdgcn_mfma_f32_16x16x32_f16(af[mf], bfr[nf], acc[mf][nf], 0, 0, 0);
        pa0 = na0; pa1 = na1; pb0 = nb0; pb1 = nb1;
    }
    const int orow = kg * 4;
    #pragma unroll
    for (int nf = 0; nf < 4; ++nf) {
        int o = o0 + wn + nf*16 + fr;
        float bo = bias[o];
        #pragma unroll
        for (int mf = 0; mf < 4; ++mf) {
            #pragma unroll
            for (int rg = 0; rg < 4; ++rg) {
                size_t m = (size_t)mbase + wm + mf*16 + orow + rg;
                float v = acc[mf][nf][rg] + bo;
                if (RESID) v += (float)resid[m*256 + o];
                v = fmaxf(v, 0.f);
                out[m*256 + o] = (_Float16)v;
            }
        }
    }
}

// ---------------- DSS: per-(h,n) discretized pole z and z^CHUNK ----------------
__global__ void k_zw(const float* __restrict__ log_dt, const float* __restrict__ lam_re,
                     const float* __restrict__ lam_im, float4* __restrict__ zwbuf, int layer) {
    int idx = blockIdx.x*256 + threadIdx.x;
    if (idx >= H*NST) return;
    int hh = idx / NST, n = idx % NST;
    float dt = expf(log_dt[layer*H + hh]);
    float a  = dt * lam_re[layer*NST + n];
    float bi = dt * lam_im[layer*NST + n];
    float er = expf(a);
    float zre = er * cosf(bi), zim = er * sinf(bi);
    float eC = expf(a * (float)CHUNK);
    float bC = bi * (float)CHUNK;
    float zcre = eC * cosf(bC), zcim = eC * sinf(bC);
    zwbuf[idx] = make_float4(zre, zim, zcre, zcim);
}

// ---------------- DSS: combined local-conv + boundary matrix W_big[h][t][256] fp16 ----------------
// k<128: T[t][j] = kf[t-j] (j<=t) else kb[j-t-1];  k>=128: E[t][*] boundary coeffs.
__global__ __launch_bounds__(128) void k_wkern(const float* __restrict__ log_dt,
        const float* __restrict__ lam_re, const float* __restrict__ lam_im,
        const float* __restrict__ W_re, const float* __restrict__ W_im,
        _Float16* __restrict__ wbig, int layer) {
    __shared__ float kf[128], kb[128];
    __shared__ float E[128*129];
    const int hh = blockIdx.x;
    const int t = threadIdx.x;
    float dt = expf(log_dt[layer*H + hh]);
    float skf = 0.f, skb = 0.f;
    for (int n = 0; n < 32; ++n) {
        float a  = dt * lam_re[layer*NST + n];
        float bi = dt * lam_im[layer*NST + n];
        float wfr = W_re[((layer*2+0)*H + hh)*NST + n];
        float wfi = W_im[((layer*2+0)*H + hh)*NST + n];
        float wbr = W_re[((layer*2+1)*H + hh)*NST + n];
        float wbi = W_im[((layer*2+1)*H + hh)*NST + n];
        float e0 = expf(a*t), s0, c0; sincosf(bi*t, &s0, &c0);
        float zr0 = e0*c0, zi0 = e0*s0;
        skf = fmaf(wfr, zr0, skf) - wfi*zi0;
        skb = fmaf(wbr, zr0, skb) - wbi*zi0;
        float e1 = expf(a*(t+1)), s1, c1; sincosf(bi*(t+1), &s1, &c1);
        float zr1 = e1*c1, zi1 = e1*s1;
        E[t*129 + n]      = wfr*zr1 - wfi*zi1;          // Re(Wf z^{t+1})
        E[t*129 + 32 + n] = -(wfr*zi1 + wfi*zr1);       // -Im(Wf z^{t+1})
        float e2 = expf(a*(127-t)), s2, c2; sincosf(bi*(127-t), &s2, &c2);
        float zr2 = e2*c2, zi2 = e2*s2;
        E[t*129 + 64 + n] = wbr*zr2 - wbi*zi2;          // Re(Wb z^{127-t})
        E[t*129 + 96 + n] = -(wbr*zi2 + wbi*zr2);       // -Im(Wb z^{127-t})
    }
    kf[t] = skf; kb[t] = skb;
    __syncthreads();
    _Float16* dst = &wbig[(size_t)hh*32768];
    for (int idx = t; idx < 128*256; idx += 128) {
        int tt = idx >> 8, k = idx & 255;
        float v;
        if (k < 128) v = (k <= tt) ? kf[tt - k] : kb[k - tt - 1];
        else         v = E[tt*129 + (k - 128)];
        dst[idx] = (_Float16)v;
    }
}

// ---------------- GLU weight pack fp16 ----------------
__global__ void k_wtg16(const float* __restrict__ gw, _Float16* __restrict__ wg, int layer) {
    int idx = blockIdx.x*256 + threadIdx.x;
    if (idx >= 512*256) return;
    wg[idx] = (_Float16)gw[layer*512*256 + idx];
}

// ---------------- decoder weight pack ----------------
__global__ void k_wdec(const float* __restrict__ dw, _Float16* __restrict__ wdk) {
    int idx = blockIdx.x*256 + threadIdx.x;
    if (idx >= 15*16*256) return;
    int cfull = idx & 255;
    int o = (idx >> 8) & 15;
    int k = idx >> 12;
    float v = (o < DOUT) ? dw[(o*H + cfull)*15 + k] : 0.f;
    int cc = cfull >> 5, cl = cfull & 31;
    int cq = cl >> 3, cb = cl & 7;
    wdk[cc*7680 + (k*16 + o)*32 + ((cq ^ SWZ(o))*8) + cb] = (_Float16)v;
}

// ---------------- DSS scan phase 1: per-chunk summaries (f32, exact) ----------------
__global__ __launch_bounds__(64) void k_scan1(const float* __restrict__ in,
        const float4* __restrict__ zw, float2* __restrict__ states) {
    __shared__ float xs[CHUNK];
    int tid = threadIdx.x;
    int ch = blockIdx.x % NCH;
    int hh = (blockIdx.x / NCH) % H;
    int b  = blockIdx.x / (NCH*H);
    const float* src = &in[(b*H + hh)*L + ch*CHUNK];
    for (int j = tid; j < CHUNK; j += 64) xs[j] = src[j];
    __syncthreads();
    int dir = tid >> 5, n = tid & 31;
    float4 z4 = zw[hh*NST + n];
    float zre = z4.x, zim = z4.y;
    float are = 0.f, aim = 0.f;
    for (int t = 0; t < CHUNK; t += 4) {
        float4 vf = *(const float4*)&xs[t];
        float4 vb = *(const float4*)&xs[CHUNK - 4 - t];
        float xv[4];
        if (dir == 0) { xv[0]=vf.x; xv[1]=vf.y; xv[2]=vf.z; xv[3]=vf.w; }
        else          { xv[0]=vb.w; xv[1]=vb.z; xv[2]=vb.y; xv[3]=vb.x; }
        #pragma unroll
        for (int q = 0; q < 4; ++q) {
            float nre = fmaf(zre, are, fmaf(-zim, aim, xv[q]));
            float nim = fmaf(zre, aim, zim * are);
            are = nre; aim = nim;
        }
    }
    states[((b*H + hh)*NCH + ch)*64 + tid] = make_float2(are, aim);
}

// ---------------- DSS scan phase 2: exclusive prefix/suffix -> packed fp16 states ----------------
// stp[(bh*NCH+ch)*128 + dir*64 + im*32 + n]
__global__ void k_scan2(const float4* __restrict__ zw, const float2* __restrict__ states,
                        _Float16* __restrict__ stp) {
    int idx = blockIdx.x*256 + threadIdx.x;   // B*H*64 total
    int dn = idx & 63;
    int bh = idx >> 6;
    int hh = bh % H;
    int n = dn & 31, dir = dn >> 5;
    float4 z4 = zw[hh*NST + n];
    float zcre = z4.z, zcim = z4.w;
    const float2* base = &states[bh*NCH*64 + dn];
    _Float16* sb = &stp[(size_t)bh*NCH*128 + dir*64 + n];
    float pre = 0.f, pim = 0.f;
    if (dir == 0) {
        for (int ch = 0; ch < NCH; ++ch) {
            sb[ch*128] = (_Float16)pre; sb[ch*128 + 32] = (_Float16)pim;
            float2 cur = base[ch*64];
            float nre = fmaf(zcre, pre, fmaf(-zcim, pim, cur.x));
            float nim = fmaf(zcre, pim, fmaf(zcim, pre, cur.y));
            pre = nre; pim = nim;
        }
    } else {
        for (int ch = NCH-1; ch >= 0; --ch) {
            sb[ch*128] = (_Float16)pre; sb[ch*128 + 32] = (_Float16)pim;
            float2 cur = base[ch*64];
            float nre = fmaf(zcre, pre, fmaf(-zcim, pim, cur.x));
            float nim = fmaf(zcre, pim, fmaf(zcim, pre, cur.y));
            pre = nre; pim = nim;
        }
    }
}

// ---------------- DSS phase 3 as MFMA GEMM: y = gelu([x|state] @ W_big^T + D*x) ----------------
// grid (mtile=4, h=256), 256 thr. M=128 rows (b,ch), N=128 (t), K=256.
__global__ __launch_bounds__(256) void k_dssg(const float* __restrict__ hx,
        const _Float16* __restrict__ stp, const _Float16* __restrict__ wbig,
        const float* __restrict__ Dv, float* __restrict__ y, int layer) {
    __shared__ _Float16 a_lds[128*32];
    __shared__ _Float16 b_lds[128*32];
    const int tid = threadIdx.x;
    const int mbase = blockIdx.x * 128;
    const int hh = blockIdx.y;
    const int lane = tid & 63;
    const int w = tid >> 6;
    const int wm = (w >> 1) * 64, wn = (w & 1) * 64;
    const int fr = lane & 15, kg = lane >> 4;
    const int r0s = tid >> 2, q0 = tid & 3;
    const int r1s = 64 + r0s;
    const int aw0 = r0s*32 + ((q0 ^ SWZ(r0s)) * 8);
    const int aw1 = r1s*32 + ((q0 ^ SWZ(r1s)) * 8);
    const _Float16* wb = &wbig[(size_t)hh*32768];

    f32x4 acc[4][4];
    #pragma unroll
    for (int i = 0; i < 4; ++i)
        #pragma unroll
        for (int j = 0; j < 4; ++j)
            #pragma unroll
            for (int k = 0; k < 4; ++k) acc[i][j][k] = 0.f;

    auto loadA = [&](int kc, int rs) -> uint4 {
        int g = mbase + rs;
        int b = g >> 4, ch = g & 15;
        if (kc < 4) {
            const float* p = &hx[((size_t)(b*H + hh))*L + ch*CHUNK + kc*32 + q0*8];
            float4 u0 = *(const float4*)p;
            float4 u1 = *(const float4*)(p + 4);
            union { half8 h; uint4 u; } cv;
            cv.h[0] = (_Float16)u0.x; cv.h[1] = (_Float16)u0.y;
            cv.h[2] = (_Float16)u0.z; cv.h[3] = (_Float16)u0.w;
            cv.h[4] = (_Float16)u1.x; cv.h[5] = (_Float16)u1.y;
            cv.h[6] = (_Float16)u1.z; cv.h[7] = (_Float16)u1.w;
            return cv.u;
        } else {
            return *(const uint4*)&stp[((size_t)(b*H + hh)*NCH + ch)*128 + (kc-4)*32 + q0*8];
        }
    };
    uint4 pa0 = loadA(0, r0s), pa1 = loadA(0, r1s);
    uint4 pb0 = *(const uint4*)&wb[r0s*256 + q0*8];
    uint4 pb1 = *(const uint4*)&wb[r1s*256 + q0*8];
    for (int kc = 0; kc < 8; ++kc) {
        __syncthreads();
        *(uint4*)&a_lds[aw0] = pa0;
        *(uint4*)&a_lds[aw1] = pa1;
        *(uint4*)&b_lds[aw0] = pb0;
        *(uint4*)&b_lds[aw1] = pb1;
        uint4 na0 = make_uint4(0,0,0,0), na1 = na0, nb0 = na0, nb1 = na0;
        if (kc < 7) {
            na0 = loadA(kc+1, r0s); na1 = loadA(kc+1, r1s);
            nb0 = *(const uint4*)&wb[r0s*256 + (kc+1)*32 + q0*8];
            nb1 = *(const uint4*)&wb[r1s*256 + (kc+1)*32 + q0*8];
        }
        __syncthreads();
        half8 af[4], bfr[4];
        #pragma unroll
        for (int mf = 0; mf < 4; ++mf) {
            int ra = wm + mf*16 + fr;
            af[mf] = *(const half8*)&a_lds[ra*32 + ((kg ^ SWZ(ra)) * 8)];
        }
        #pragma unroll
        for (int nf = 0; nf < 4; ++nf) {
            int rb = wn + nf*16 + fr;
            bfr[nf] = *(const half8*)&b_lds[rb*32 + ((kg ^ SWZ(rb)) * 8)];
        }
        #pragma unroll
        for (int mf = 0; mf < 4; ++mf)
            #pragma unroll
            for (int nf = 0; nf < 4; ++nf)
                acc[mf][nf] = __builtin_amdgcn_mfma_f32_16x16x32_f16(af[mf], bfr[nf], acc[mf][nf], 0, 0, 0);
        pa0 = na0; pa1 = na1; pb0 = nb0; pb1 = nb1;
    }
    float dv = Dv[layer*H + hh];
    #pragma unroll
    for (int mf = 0; mf < 4; ++mf) {
        #pragma unroll
        for (int rg = 0; rg < 4; ++rg) {
            int g = mbase + wm + mf*16 + kg*4 + rg;
            int b = g >> 4, ch = g & 15;
            size_t gbase = ((size_t)(b*H + hh))*L + ch*CHUNK;
            #pragma unroll
            for (int nf = 0; nf < 4; ++nf) {
                int t = wn + nf*16 + fr;
                float v = acc[mf][nf][rg] + dv * hx[gbase + t];
                y[gbase + t] = gelu_exact(v);
            }
        }
    }
}

// ---------------- GLU MFMA fp16 ----------------
__global__ __launch_bounds__(256) void k_glu16(const _Float16* __restrict__ yt,
        const _Float16* __restrict__ wg, const float* __restrict__ bias,
        float* __restrict__ zc) {
    __shared__ _Float16 a_lds[128*32];
    __shared__ _Float16 b_lds[128*32];
    const int tid = threadIdx.x;
    const int mbase = blockIdx.x * 128;
    const int o0 = blockIdx.y * 64;
    const int lane = tid & 63;
    const int w = tid >> 6;
    const int wm = (w >> 1) * 64, wn = (w & 1) * 32;
    const int fr = lane & 15, kg = lane >> 4;
    const int r0s = tid >> 2, q0 = tid & 3;
    const int r1s = 64 + r0s;
    const int aw0 = r0s*32 + ((q0 ^ SWZ(r0s)) * 8);
    const int aw1 = r1s*32 + ((q0 ^ SWZ(r1s)) * 8);
    const int og0 = o0 + r0s;
    const int og1 = 256 + o0 + r0s;

    f32x4 accg[4][2], accs[4][2];
    #pragma unroll
    for (int i = 0; i < 4; ++i)
        #pragma unroll
        for (int j = 0; j < 2; ++j)
            #pragma unroll
            for (int k = 0; k < 4; ++k) { accg[i][j][k] = 0.f; accs[i][j][k] = 0.f; }

    uint4 pa0, pa1, pb0, pb1;
    auto loadstep = [&](int kc, uint4& a0, uint4& a1, uint4& b0, uint4& b1) {
        const int cb = kc*32 + q0*8;
        a0 = *(const uint4*)&yt[((size_t)(mbase + r0s))*256 + cb];
        a1 = *(const uint4*)&yt[((size_t)(mbase + r1s))*256 + cb];
        b0 = *(const uint4*)&wg[((size_t)og0)*256 + cb];
        b1 = *(const uint4*)&wg[((size_t)og1)*256 + cb];
    };
    loadstep(0, pa0, pa1, pb0, pb1);
    for (int kc = 0; kc < 8; ++kc) {
        __syncthreads();
        *(uint4*)&a_lds[aw0] = pa0;
        *(uint4*)&a_lds[aw1] = pa1;
        *(uint4*)&b_lds[aw0] = pb0;
        *(uint4*)&b_lds[aw1] = pb1;
        uint4 na0 = make_uint4(0,0,0,0), na1 = na0, nb0 = na0, nb1 = na0;
        if (kc < 7) loadstep(kc+1, na0, na1, nb0, nb1);
        __syncthreads();
        half8 af[4], bg[2], bs[2];
        #pragma unroll
        for (int mf = 0; mf < 4; ++mf) {
            int ra = wm + mf*16 + fr;
            af[mf] = *(const half8*)&a_lds[ra*32 + ((kg ^ SWZ(ra)) * 8)];
        }
        #pragma unroll
        for (int nf = 0; nf < 2; ++nf) {
            int rb = wn + nf*16 + fr;
            bg[nf] = *(const half8*)&b_lds[rb*32 + ((kg ^ SWZ(rb)) * 8)];
            int rb2 = 64 + rb;
            bs[nf] = *(const half8*)&b_lds[rb2*32 + ((kg ^ SWZ(rb2)) * 8)];
        }
        #pragma unroll
        for (int mf = 0; mf < 4; ++mf)
            #pragma unroll
            for (int nf = 0; nf < 2; ++nf) {
                accg[mf][nf] = __builtin_amdgcn_mfma_f32_16x16x32_f16(af[mf], bg[nf], accg[mf][nf], 0, 0, 0);
                accs[mf][nf] = __builtin_amdgcn_mfma_f32_16x16x32_f16(af[mf], bs[nf], accs[mf][nf], 0, 0, 0);
            }
        pa0 = na0; pa1 = na1; pb0 = nb0; pb1 = nb1;
    }
    #pragma unroll
    for (int nf = 0; nf < 2; ++nf) {
        int o = o0 + wn + nf*16 + fr;
        float b0v = bias[o], b1v = bias[256 + o];
        #pragma unroll
        for (int mf = 0; mf < 4; ++mf) {
            #pragma unroll
            for (int rg = 0; rg < 4; ++rg) {
                size_t m = (size_t)mbase + wm + mf*16 + kg*4 + rg;
                float g = accg[mf][nf][rg] + b0v;
                float s = accs[mf][nf][rg] + b1v;
                zc[m*256 + o] = g / (1.f + expf(-s));
            }
        }
    }
}

// ---------------- LayerNorm channel-last z + staged chm residual -> chm h ----------------
__global__ __launch_bounds__(256) void k_ln2(const float* __restrict__ zc,
        float* __restrict__ h, const float* __restrict__ g, const float* __restrict__ bb) {
    __shared__ float tl[8992];
    int tid = threadIdx.x;
    int b = blockIdx.y;
    int l0 = blockIdx.x * 32;
    for (int j = tid; j < 32*256; j += 256) {
        int c = j >> 5, l = j & 31;
        tl[LDIDX(l, c)] = h[((size_t)(b*H + c))*L + l0 + l];
    }
    __syncthreads();
    int r = tid >> 3, p = tid & 7;
    float v[32];
    float sum = 0.f, ss = 0.f;
    const float* zrow = &zc[((size_t)(b*L + l0 + r))*256 + p*32];
    #pragma unroll
    for (int q = 0; q < 8; ++q) {
        float4 z4 = *(const float4*)&zrow[q*4];
        float zz[4] = {z4.x, z4.y, z4.z, z4.w};
        #pragma unroll
        for (int i = 0; i < 4; ++i) {
            float hv = tl[LDIDX(r, p*32 + q*4 + i)];
            float vv = zz[i] + hv;
            v[q*4+i] = vv;
            sum += vv; ss = fmaf(vv, vv, ss);
        }
    }
    sum += __shfl_xor(sum, 1); ss += __shfl_xor(ss, 1);
    sum += __shfl_xor(sum, 2); ss += __shfl_xor(ss, 2);
    sum += __shfl_xor(sum, 4); ss += __shfl_xor(ss, 4);
    float mu = sum * (1.f/256.f);
    float var = ss * (1.f/256.f) - mu*mu;
    float rs = rsqrtf(var + 1e-5f);
    #pragma unroll
    for (int q = 0; q < 32; ++q) {
        int c = p*32 + q;
        tl[LDIDX(r, c)] = (v[q] - mu) * rs * g[c] + bb[c];
    }
    __syncthreads();
    for (int j = tid; j < 32*256; j += 256) {
        int c = j >> 5, l = j & 31;
        h[((size_t)(b*H + c))*L + l0 + l] = tl[LDIDX(l, c)];
    }
}

// ---------------- MFMA decoder conv K=15 ----------------
__global__ __launch_bounds__(128) void k_dec(const _Float16* __restrict__ ht,
        const _Float16* __restrict__ wdk, const float* __restrict__ bias,
        float* __restrict__ outdec) {
    __shared__ _Float16 a_lds[160*32];
    __shared__ _Float16 b_lds[15*16*32];
    const int tid = threadIdx.x;
    const int mbase = blockIdx.x * 128;
    const int b = mbase >> 11;
    const int lbase = mbase & 2047;
    const int lane = tid & 63;
    const int w = tid >> 6;
    const int fr = lane & 15, kg = lane >> 4;
    const int rs = tid >> 2, q0 = tid & 3;
    f32x4 acc[4];
    #pragma unroll
    for (int i = 0; i < 4; ++i)
        #pragma unroll
        for (int k = 0; k < 4; ++k) acc[i][k] = 0.f;
    for (int cc = 0; cc < 8; ++cc) {
        __syncthreads();
        #pragma unroll
        for (int ps = 0; ps < 5; ++ps) {
            int r = ps*32 + rs;
            if (r < 142) {
                int l = lbase - 7 + r;
                uint4 v = (l >= 0 && l < L) ? *(const uint4*)&ht[((size_t)(b*L + l))*256 + cc*32 + q0*8]
                                            : make_uint4(0,0,0,0);
                *(uint4*)&a_lds[r*32 + ((q0 ^ SWZ(r))*8)] = v;
            }
        }
        for (int jj = tid; jj < 960; jj += 128)
            *(uint4*)&b_lds[jj*8] = *(const uint4*)&wdk[cc*7680 + jj*8];
        __syncthreads();
        #pragma unroll
        for (int k = 0; k < 15; ++k) {
            half8 bfr = *(const half8*)&b_lds[(k*16 + fr)*32 + ((kg ^ SWZ(fr))*8)];
            #pragma unroll
            for (int mf = 0; mf < 4; ++mf) {
                int ra = w*64 + mf*16 + fr + k;
                half8 af = *(const half8*)&a_lds[ra*32 + ((kg ^ SWZ(ra))*8)];
                acc[mf] = __builtin_amdgcn_mfma_f32_16x16x32_f16(af, bfr, acc[mf], 0, 0, 0);
            }
        }
    }
    if (fr < DOUT) {
        float bo = bias[fr];
        #pragma unroll
        for (int mf = 0; mf < 4; ++mf)
            #pragma unroll
            for (int rg = 0; rg < 4; ++rg) {
                int m = mbase + w*64 + mf*16 + kg*4 + rg;
                outdec[((size_t)(b*DOUT + fr))*L + (m & 2047)] = acc[mf][rg] + bo;
            }
    }
}

// ---------------- species embedding ----------------
__global__ void k_species(float* __restrict__ h, const int* __restrict__ xs,
        const float* __restrict__ emb, float* __restrict__ outseq) {
    int idx = blockIdx.x*256 + threadIdx.x;
    if (idx >= LSEQ) return;
    int c = (idx / L) % H;
    int b = idx / (H*L);
    float v = h[idx] + emb[xs[b]*H + c];
    h[idx] = v;
    outseq[idx] = v;
}

// ---------------- mean over L ----------------
__global__ __launch_bounds__(256) void k_agg(const float* __restrict__ h, float* __restrict__ agg) {
    __shared__ float red[256];
    int bc = blockIdx.x;
    int tid = threadIdx.x;
    float s = 0.f;
    for (int t = tid; t < L; t += 256) s += h[bc*L + t];
    red[tid] = s; __syncthreads();
    for (int k = 128; k > 0; k >>= 1) {
        if (tid < k) red[tid] += red[tid+k];
        __syncthreads();
    }
    if (tid == 0) agg[bc] = red[0] * (1.f/(float)L);
}

// ---------------- regression MLP ----------------
__global__ __launch_bounds__(128) void k_mlp(const float* __restrict__ agg,
        const float* __restrict__ w1, const float* __restrict__ b1,
        const float* __restrict__ w2, const float* __restrict__ b2,
        const float* __restrict__ w3, const float* __restrict__ b3,
        const float* __restrict__ w4, const float* __restrict__ b4,
        float* __restrict__ outreg) {
    __shared__ float a0[256], r1[128], r2[64], r3[32];
    int b = blockIdx.x, tid = threadIdx.x;
    a0[tid] = agg[b*256 + tid];
    a0[tid+128] = agg[b*256 + tid + 128];
    __syncthreads();
    {
        float s = b1[tid];
        for (int k = 0; k < 256; ++k) s = fmaf(w1[tid*256+k], a0[k], s);
        r1[tid] = s > 0.f ? s : expm1f(s);
    }
    __syncthreads();
    if (tid < 64) {
        float s = b2[tid];
        for (int k = 0; k < 128; ++k) s = fmaf(w2[tid*128+k], r1[k], s);
        r2[tid] = s > 0.f ? s : expm1f(s);
    }
    __syncthreads();
    if (tid < 32) {
        float s = b3[tid];
        for (int k = 0; k < 64; ++k) s = fmaf(w3[tid*64+k], r2[k], s);
        r3[tid] = s > 0.f ? s : expm1f(s);
    }
    __syncthreads();
    if (tid == 0) {
        float s = b4[0];
        for (int k = 0; k < 32; ++k) s = fmaf(w4[k], r3[k], s);
        outreg[b] = s;
    }
}

extern "C" void kernel_launch(void* const* d_in, const int* in_sizes, int n_in,
                              void* d_out, int out_size, void* d_ws, size_t ws_size,
                              hipStream_t stream) {
    const float* x      = (const float*)d_in[0];
    const int*   xs     = (const int*)d_in[1];
    const float* enc_w  = (const float*)d_in[2];
    const float* enc_b  = (const float*)d_in[3];
    const float* res_w1 = (const float*)d_in[4];
    const float* res_b1 = (const float*)d_in[5];
    const float* res_w2 = (const float*)d_in[6];
    const float* res_b2 = (const float*)d_in[7];
    const float* log_dt = (const float*)d_in[8];
    const float* lam_re = (const float*)d_in[9];
    const float* lam_im = (const float*)d_in[10];
    const float* W_re   = (const float*)d_in[11];
    const float* W_im   = (const float*)d_in[12];
    const float* Dv     = (const float*)d_in[13];
    const float* glu_w  = (const float*)d_in[14];
    const float* glu_b  = (const float*)d_in[15];
    const float* ln_g   = (const float*)d_in[16];
    const float* ln_b   = (const float*)d_in[17];
    const float* dec_w  = (const float*)d_in[18];
    const float* dec_b  = (const float*)d_in[19];
    const float* sp_emb = (const float*)d_in[20];
    const float* h1_w = (const float*)d_in[21]; const float* h1_b = (const float*)d_in[22];
    const float* h2_w = (const float*)d_in[23]; const float* h2_b = (const float*)d_in[24];
    const float* h3_w = (const float*)d_in[25]; const float* h3_b = (const float*)d_in[26];
    const float* h4_w = (const float*)d_in[27]; const float* h4_b = (const float*)d_in[28];

    float* ws   = (float*)d_ws;
    float* h    = ws;                                  // LSEQ f32 [b][c][l]
    float* t1   = ws + (size_t)LSEQ;                   // LSEQ f32
    float* t2   = ws + (size_t)2*LSEQ;                 // LSEQ f32
    float2* states = (float2*)t2;                      // scan1 output (all of t2)
    // res-phase aliases (dead once DSS starts):
    _Float16* xa  = (_Float16*)t1;
    _Float16* xb  = xa + (size_t)LSEQ;
    _Float16* wpk = (_Float16*)t2;
    // DSS-phase aliases:
    _Float16* stp  = (_Float16*)t1;                    // packed states, t1 lower half
    _Float16* wbig = (_Float16*)t1 + (size_t)LSEQ;     // 8.4M fp16, t1 upper half
    _Float16* yt   = (_Float16*)t1;                    // fp16 chl y (after k_dssg), t1 lower
    float* yb      = t2;                               // dssg output y f32 chm
    float* zcb     = t2;                               // glu output chl f32 (y dead)
    // tail region:
    float* tail = ws + (size_t)3*LSEQ;
    _Float16* wg  = (_Float16*)tail;                   // 512*256 fp16
    float4* zwb = (float4*)(tail + 65536);             // H*NST float4
    float* aggb = tail + 65536 + 32768;                // B*H
    _Float16* wdk = (_Float16*)(aggb + 8192);          // 61440 fp16

    float* outdec = (float*)d_out;
    float* outseq = outdec + B*DOUT*L;
    float* outreg = outseq + (size_t)LSEQ;

    // encoder conv
    k_conv15<<<dim3(L/512, H, B), 128, 0, stream>>>(x, enc_w, enc_b, h, DIN);

    // residual stack (fp16 MFMA, channel-last)
    k_wpack<<<(NRES*2*3*65536 + 255)/256, 256, 0, stream>>>(res_w1, res_w2, wpk);
    k_t_cl<<<dim3(L/64, H/64, B), 256, 0, stream>>>(h, xa);
    for (int r = 0; r < NRES; ++r) {
        k_cv3<false><<<dim3(B*L/128, 2), 256, 0, stream>>>(
            xa, wpk + (size_t)(r*2+0)*3*65536, res_b1 + r*H, nullptr, xb);
        k_cv3<true><<<dim3(B*L/128, 2), 256, 0, stream>>>(
            xb, wpk + (size_t)(r*2+1)*3*65536, res_b2 + r*H, xa, xa);
    }
    k_t_cf<<<dim3(L/64, H/64, B), 256, 0, stream>>>(xa, h);

    // DSS blocks
    for (int i = 0; i < NLAYERS; ++i) {
        k_zw<<<(H*NST + 255)/256, 256, 0, stream>>>(log_dt, lam_re, lam_im, zwb, i);
        k_wkern<<<H, 128, 0, stream>>>(log_dt, lam_re, lam_im, W_re, W_im, wbig, i);
        k_wtg16<<<(512*256 + 255)/256, 256, 0, stream>>>(glu_w, wg, i);
        k_scan1<<<B*H*NCH, 64, 0, stream>>>(h, zwb, states);
        k_scan2<<<(B*H*64)/256, 256, 0, stream>>>(zwb, states, stp);
        k_dssg<<<dim3(4, H), 256, 0, stream>>>(h, stp, wbig, Dv, yb, i);
        k_t_cl<<<dim3(L/64, H/64, B), 256, 0, stream>>>(yb, yt);
        k_glu16<<<dim3(B*L/128, 4), 256, 0, stream>>>(yt, wg, glu_b + i*512, zcb);
        k_ln2<<<dim3(L/32, B), 256, 0, stream>>>(zcb, h, ln_g + i*H, ln_b + i*H);
    }

    // species embedding + outputs
    k_species<<<(LSEQ + 255)/256, 256, 0, stream>>>(h, xs, sp_emb, outseq);
    k_agg<<<B*H, 256, 0, stream>>>(h, aggb);
    k_mlp<<<B, 128, 0, stream>>>(aggb, h1_w, h1_b, h2_w, h2_b, h3_w, h3_b, h4_w, h4_b, outreg);
    // decoder
    k_t_cl<<<dim3(L/64, H/64, B), 256, 0, stream>>>(h, (_Float16*)t1);
    k_wdec<<<(15*16*256 + 255)/256, 256, 0, stream>>>(dec_w, wdk);
    k_dec<<<B*L/128, 128, 0, stream>>>((_Float16*)t1, wdk, dec_b, outdec);
}

// Round 6
// 1524.497 us; speedup vs baseline: 4.2986x; 1.3005x over previous
//
#include <hip/hip_runtime.h>
#include <math.h>

#define B 32
#define L 2048
#define DIN 5
#define DOUT 5
#define H 256
#define NST 32
#define NLAYERS 4
#define NRES 3
#define CHUNK 128
#define NCH 16            // L / CHUNK
#define LSEQ (B*H*L)      // 16777216

typedef __attribute__((ext_vector_type(8))) _Float16 half8;
typedef __attribute__((ext_vector_type(4))) float f32x4;

__device__ __forceinline__ float gelu_exact(float v) {
    return 0.5f * v * (1.0f + erff(v * 0.7071067811865475f));
}
#define SWZ(r) ((((r) ^ ((r) >> 2)) & 3))
#define LDIDX(l, c) ((l)*281 + ((c)>>5)*35 + ((c)&31))

// ---------------- encoder weight pack: wenc[o][kk], kk = ci*16+k (pad 96) ----------------
__global__ void k_wenc(const float* __restrict__ ew, _Float16* __restrict__ wenc) {
    int idx = blockIdx.x*256 + threadIdx.x;
    if (idx >= 256*96) return;
    int o = idx / 96, kk = idx % 96;
    int ci = kk >> 4, k = kk & 15;
    float v = (ci < DIN && k < 15) ? ew[(o*DIN + ci)*15 + k] : 0.f;
    wenc[idx] = (_Float16)v;
}

// ---------------- MFMA encoder conv K=15 Cin=5: x f32 chm -> xa fp16 chl ----------------
// single-shot: K=96 (5ci x 16), im2col in LDS. grid (B*L/128, 2), 256 thr.
__global__ __launch_bounds__(256) void k_enc(const float* __restrict__ x,
        const _Float16* __restrict__ wenc, const float* __restrict__ bias,
        _Float16* __restrict__ out) {
    __shared__ _Float16 a_lds[3*128*32];
    __shared__ _Float16 b_lds[3*128*32];
    const int tid = threadIdx.x;
    const int mbase = blockIdx.x * 128;
    const int oh = blockIdx.y;
    const int b = mbase >> 11;
    const int lbase = mbase & 2047;
    const int lane = tid & 63;
    const int w = tid >> 6;
    const int wm = (w >> 1) * 64, wn = (w & 1) * 64;
    const int fr = lane & 15, kg = lane >> 4;

    #pragma unroll
    for (int i = 0; i < 6; ++i) {
        int g = i*256 + tid;              // 1536 granules of 8
        int r = g / 12, rem = g % 12;
        int ks = rem >> 2, q = rem & 3;
        int kk0 = ks*32 + q*8;
        int ci = kk0 >> 4, k0 = kk0 & 15;
        half8 va;
        #pragma unroll
        for (int e = 0; e < 8; ++e) {
            int k = k0 + e;
            int l = lbase + r - 7 + k;
            float v = (ci < DIN && k < 15 && l >= 0 && l < L)
                        ? x[((size_t)(b*DIN + ci))*L + l] : 0.f;
            va[e] = (_Float16)v;
        }
        *(half8*)&a_lds[ks*4096 + r*32 + ((q ^ SWZ(r))*8)] = va;
        uint4 vb = *(const uint4*)&wenc[(size_t)(oh*128 + r)*96 + kk0];
        *(uint4*)&b_lds[ks*4096 + r*32 + ((q ^ SWZ(r))*8)] = vb;
    }
    __syncthreads();
    f32x4 acc[4][4];
    #pragma unroll
    for (int i = 0; i < 4; ++i)
        #pragma unroll
        for (int j = 0; j < 4; ++j)
            #pragma unroll
            for (int k = 0; k < 4; ++k) acc[i][j][k] = 0.f;
    #pragma unroll
    for (int ks = 0; ks < 3; ++ks) {
        half8 af[4], bfr[4];
        #pragma unroll
        for (int mf = 0; mf < 4; ++mf) {
            int ra = wm + mf*16 + fr;
            af[mf] = *(const half8*)&a_lds[ks*4096 + ra*32 + ((kg ^ SWZ(ra))*8)];
        }
        #pragma unroll
        for (int nf = 0; nf < 4; ++nf) {
            int rb = wn + nf*16 + fr;
            bfr[nf] = *(const half8*)&b_lds[ks*4096 + rb*32 + ((kg ^ SWZ(rb))*8)];
        }
        #pragma unroll
        for (int mf = 0; mf < 4; ++mf)
            #pragma unroll
            for (int nf = 0; nf < 4; ++nf)
                acc[mf][nf] = __builtin_amdgcn_mfma_f32_16x16x32_f16(af[mf], bfr[nf], acc[mf][nf], 0, 0, 0);
    }
    #pragma unroll
    for (int nf = 0; nf < 4; ++nf) {
        int o = oh*128 + wn + nf*16 + fr;
        float bo = bias[o];
        #pragma unroll
        for (int mf = 0; mf < 4; ++mf)
            #pragma unroll
            for (int rg = 0; rg < 4; ++rg) {
                size_t m = (size_t)mbase + wm + mf*16 + kg*4 + rg;
                out[m*256 + o] = (_Float16)(acc[mf][nf][rg] + bo);
            }
    }
}

// ---------------- weight pack: wpk[cv][k][o][ci] fp16 <- w[r][o][ci][k] ----------------
__global__ void k_wpack(const float* __restrict__ w1, const float* __restrict__ w2,
                        _Float16* __restrict__ wpk) {
    int idx = blockIdx.x*256 + threadIdx.x;
    if (idx >= NRES*2*3*65536) return;
    int ci = idx & 255;
    int o  = (idx >> 8) & 255;
    int k  = (idx >> 16) % 3;
    int cv = idx / (3*65536);
    const float* src = (cv & 1) ? w2 : w1;
    wpk[idx] = (_Float16)src[(((cv>>1)*H + o)*H + ci)*3 + k];
}

// ---------------- transpose f32 [b][c][l] -> fp16 channel-last [b*L][c] ----------------
__global__ __launch_bounds__(256) void k_t_cl(const float* __restrict__ in,
                                              _Float16* __restrict__ out) {
    __shared__ float t[64][65];
    int tid = threadIdx.x;
    int l0 = blockIdx.x*64, c0 = blockIdx.y*64, b = blockIdx.z;
    #pragma unroll
    for (int i = 0; i < 16; ++i) {
        int idx = i*256 + tid;
        int c = idx >> 6, l = idx & 63;
        t[c][l] = in[((size_t)(b*H + c0 + c))*L + l0 + l];
    }
    __syncthreads();
    #pragma unroll
    for (int i = 0; i < 16; ++i) {
        int idx = i*256 + tid;
        int l = idx >> 6, c = idx & 63;
        out[((size_t)b*L + l0 + l)*256 + c0 + c] = (_Float16)t[c][l];
    }
}

// ---------------- transpose fp16 channel-last [b*L][c] -> f32 [b][c][l] ----------------
__global__ __launch_bounds__(256) void k_t_cf(const _Float16* __restrict__ in,
                                              float* __restrict__ out) {
    __shared__ float t[64][65];
    int tid = threadIdx.x;
    int l0 = blockIdx.x*64, c0 = blockIdx.y*64, b = blockIdx.z;
    #pragma unroll
    for (int i = 0; i < 16; ++i) {
        int idx = i*256 + tid;
        int l = idx >> 6, c = idx & 63;
        t[c][l] = (float)in[((size_t)b*L + l0 + l)*256 + c0 + c];
    }
    __syncthreads();
    #pragma unroll
    for (int i = 0; i < 16; ++i) {
        int idx = i*256 + tid;
        int c = idx >> 6, l = idx & 63;
        out[((size_t)(b*H + c0 + c))*L + l0 + l] = t[c][l];
    }
}

// ---------------- MFMA residual conv K=3 (fp16) ----------------
template<bool RESID>
__global__ __launch_bounds__(256) void k_cv3(const _Float16* __restrict__ xin,
        const _Float16* __restrict__ wpk, const float* __restrict__ bias,
        const _Float16* __restrict__ resid, _Float16* __restrict__ out) {
    __shared__ _Float16 a_lds[128*32];
    __shared__ _Float16 b_lds[128*32];
    const int tid = threadIdx.x;
    const int mbase = blockIdx.x * 128;
    const int o0 = blockIdx.y * 128;
    const int lane = tid & 63;
    const int w = tid >> 6;
    const int wm = (w >> 1) * 64, wn = (w & 1) * 64;
    const int fr = lane & 15, kg = lane >> 4;

    const int r0s = tid >> 2, q0 = tid & 3;
    const int r1s = 64 + (tid >> 2);
    const int aw0 = r0s*32 + ((q0 ^ SWZ(r0s)) * 8);
    const int aw1 = r1s*32 + ((q0 ^ SWZ(r1s)) * 8);

    f32x4 acc[4][4];
    #pragma unroll
    for (int i = 0; i < 4; ++i)
        #pragma unroll
        for (int j = 0; j < 4; ++j)
            #pragma unroll
            for (int k = 0; k < 4; ++k) acc[i][j][k] = 0.f;

    uint4 pa0, pa1, pb0, pb1;
    auto loadstep = [&](int kk, uint4& a0, uint4& a1, uint4& b0, uint4& b1) {
        const int koff = kk >> 3, cic = kk & 7;
        const int cb = cic*32 + q0*8;
        {
            int m = mbase + r0s;
            int ll = (m & (L-1)) + koff - 1;
            a0 = (ll >= 0 && ll < L) ? *(const uint4*)&xin[((size_t)(m + koff - 1))*256 + cb]
                                     : make_uint4(0,0,0,0);
            int m1 = mbase + r1s;
            int l1 = (m1 & (L-1)) + koff - 1;
            a1 = (l1 >= 0 && l1 < L) ? *(const uint4*)&xin[((size_t)(m1 + koff - 1))*256 + cb]
                                     : make_uint4(0,0,0,0);
        }
        b0 = *(const uint4*)&wpk[((size_t)(koff*256 + o0 + r0s))*256 + cb];
        b1 = *(const uint4*)&wpk[((size_t)(koff*256 + o0 + r1s))*256 + cb];
    };
    loadstep(0, pa0, pa1, pb0, pb1);
    for (int kk = 0; kk < 24; ++kk) {
        __syncthreads();
        *(uint4*)&a_lds[aw0] = pa0;
        *(uint4*)&a_lds[aw1] = pa1;
        *(uint4*)&b_lds[aw0] = pb0;
        *(uint4*)&b_lds[aw1] = pb1;
        uint4 na0 = make_uint4(0,0,0,0), na1 = na0, nb0 = na0, nb1 = na0;
        if (kk < 23) loadstep(kk+1, na0, na1, nb0, nb1);
        __syncthreads();
        half8 af[4], bfr[4];
        #pragma unroll
        for (int mf = 0; mf < 4; ++mf) {
            int ra = wm + mf*16 + fr;
            af[mf] = *(const half8*)&a_lds[ra*32 + ((kg ^ SWZ(ra)) * 8)];
        }
        #pragma unroll
        for (int nf = 0; nf < 4; ++nf) {
            int rb = wn + nf*16 + fr;
            bfr[nf] = *(const half8*)&b_lds[rb*32 + ((kg ^ SWZ(rb)) * 8)];
        }
        #pragma unroll
        for (int mf = 0; mf < 4; ++mf)
            #pragma unroll
            for (int nf = 0; nf < 4; ++nf)
                acc[mf][nf] = __builtin_amdgcn_mfma_f32_16x16x32_f16(af[mf], bfr[nf], acc[mf][nf], 0, 0, 0);
        pa0 = na0; pa1 = na1; pb0 = nb0; pb1 = nb1;
    }
    const int orow = kg * 4;
    #pragma unroll
    for (int nf = 0; nf < 4; ++nf) {
        int o = o0 + wn + nf*16 + fr;
        float bo = bias[o];
        #pragma unroll
        for (int mf = 0; mf < 4; ++mf) {
            #pragma unroll
            for (int rg = 0; rg < 4; ++rg) {
                size_t m = (size_t)mbase + wm + mf*16 + orow + rg;
                float v = acc[mf][nf][rg] + bo;
                if (RESID) v += (float)resid[m*256 + o];
                v = fmaxf(v, 0.f);
                out[m*256 + o] = (_Float16)v;
            }
        }
    }
}

// ---------------- DSS: per-(h,n) discretized pole z and z^CHUNK ----------------
__global__ void k_zw(const float* __restrict__ log_dt, const float* __restrict__ lam_re,
                     const float* __restrict__ lam_im, float4* __restrict__ zwbuf, int layer) {
    int idx = blockIdx.x*256 + threadIdx.x;
    if (idx >= H*NST) return;
    int hh = idx / NST, n = idx % NST;
    float dt = expf(log_dt[layer*H + hh]);
    float a  = dt * lam_re[layer*NST + n];
    float bi = dt * lam_im[layer*NST + n];
    float er = expf(a);
    float zre = er * cosf(bi), zim = er * sinf(bi);
    float eC = expf(a * (float)CHUNK);
    float bC = bi * (float)CHUNK;
    float zcre = eC * cosf(bC), zcim = eC * sinf(bC);
    zwbuf[idx] = make_float4(zre, zim, zcre, zcim);
}

// ---------------- Z-power matrix for scan1-as-GEMM: zp[h][t][j] fp16 ----------------
// t = dn*2 + c, dn = dir*32 + n; dir0: z^{127-j}, dir1: z^{j}; c=0 Re, c=1 Im.
__global__ __launch_bounds__(128) void k_wzp(const float4* __restrict__ zw,
        _Float16* __restrict__ zp) {
    int hh = blockIdx.x;
    int t = threadIdx.x;
    int dn = t >> 1, c = t & 1, dir = dn >> 5, n = dn & 31;
    float4 z4 = zw[hh*NST + n];
    float zre = z4.x, zim = z4.y;
    _Float16* dst = &zp[(size_t)hh*16384 + t*128];
    float cr = 1.f, ci = 0.f;
    for (int p = 0; p < 128; ++p) {
        float val = c ? ci : cr;
        dst[dir ? p : (127 - p)] = (_Float16)val;
        float nr = cr*zre - ci*zim;
        float ni = cr*zim + ci*zre;
        cr = nr; ci = ni;
    }
}

// ---------------- DSS: combined local-conv + boundary matrix W_big[h][t][256] fp16 ----------------
__global__ __launch_bounds__(128) void k_wkern(const float* __restrict__ log_dt,
        const float* __restrict__ lam_re, const float* __restrict__ lam_im,
        const float* __restrict__ W_re, const float* __restrict__ W_im,
        _Float16* __restrict__ wbig, int layer) {
    __shared__ float kf[128], kb[128];
    __shared__ float E[128*129];
    const int hh = blockIdx.x;
    const int t = threadIdx.x;
    float dt = expf(log_dt[layer*H + hh]);
    float skf = 0.f, skb = 0.f;
    for (int n = 0; n < 32; ++n) {
        float a  = dt * lam_re[layer*NST + n];
        float bi = dt * lam_im[layer*NST + n];
        float wfr = W_re[((layer*2+0)*H + hh)*NST + n];
        float wfi = W_im[((layer*2+0)*H + hh)*NST + n];
        float wbr = W_re[((layer*2+1)*H + hh)*NST + n];
        float wbi = W_im[((layer*2+1)*H + hh)*NST + n];
        float e0 = expf(a*t), s0, c0; sincosf(bi*t, &s0, &c0);
        float zr0 = e0*c0, zi0 = e0*s0;
        skf = fmaf(wfr, zr0, skf) - wfi*zi0;
        skb = fmaf(wbr, zr0, skb) - wbi*zi0;
        float e1 = expf(a*(t+1)), s1, c1; sincosf(bi*(t+1), &s1, &c1);
        float zr1 = e1*c1, zi1 = e1*s1;
        E[t*129 + n]      = wfr*zr1 - wfi*zi1;
        E[t*129 + 32 + n] = -(wfr*zi1 + wfi*zr1);
        float e2 = expf(a*(127-t)), s2, c2; sincosf(bi*(127-t), &s2, &c2);
        float zr2 = e2*c2, zi2 = e2*s2;
        E[t*129 + 64 + n] = wbr*zr2 - wbi*zi2;
        E[t*129 + 96 + n] = -(wbr*zi2 + wbi*zr2);
    }
    kf[t] = skf; kb[t] = skb;
    __syncthreads();
    _Float16* dst = &wbig[(size_t)hh*32768];
    for (int idx = t; idx < 128*256; idx += 128) {
        int tt = idx >> 8, k = idx & 255;
        float v;
        if (k < 128) v = (k <= tt) ? kf[tt - k] : kb[k - tt - 1];
        else         v = E[tt*129 + (k - 128)];
        dst[idx] = (_Float16)v;
    }
}

// ---------------- GLU weight pack fp16 ----------------
__global__ void k_wtg16(const float* __restrict__ gw, _Float16* __restrict__ wg, int layer) {
    int idx = blockIdx.x*256 + threadIdx.x;
    if (idx >= 512*256) return;
    wg[idx] = (_Float16)gw[layer*512*256 + idx];
}

// ---------------- decoder weight pack ----------------
__global__ void k_wdec(const float* __restrict__ dw, _Float16* __restrict__ wdk) {
    int idx = blockIdx.x*256 + threadIdx.x;
    if (idx >= 15*16*256) return;
    int cfull = idx & 255;
    int o = (idx >> 8) & 15;
    int k = idx >> 12;
    float v = (o < DOUT) ? dw[(o*H + cfull)*15 + k] : 0.f;
    int cc = cfull >> 5, cl = cfull & 31;
    int cq = cl >> 3, cb = cl & 7;
    wdk[cc*7680 + (k*16 + o)*32 + ((cq ^ SWZ(o))*8) + cb] = (_Float16)v;
}

// ---------------- scan1 as MFMA GEMM: states[(b,h,ch)][t] = sum_j x[j] * zp[h][t][j] ----------------
// grid (4, H), 256 thr. M=128 of 512 (b,ch), N=128 t, K=128 j.
__global__ __launch_bounds__(256) void k_sgem(const float* __restrict__ hx,
        const _Float16* __restrict__ zp, float* __restrict__ states) {
    __shared__ _Float16 a_lds[128*32];
    __shared__ _Float16 b_lds[128*32];
    const int tid = threadIdx.x;
    const int mbase = blockIdx.x * 128;
    const int hh = blockIdx.y;
    const int lane = tid & 63;
    const int w = tid >> 6;
    const int wm = (w >> 1) * 64, wn = (w & 1) * 64;
    const int fr = lane & 15, kg = lane >> 4;
    const int r0s = tid >> 2, q0 = tid & 3;
    const int r1s = 64 + r0s;
    const int aw0 = r0s*32 + ((q0 ^ SWZ(r0s)) * 8);
    const int aw1 = r1s*32 + ((q0 ^ SWZ(r1s)) * 8);
    const _Float16* zb = &zp[(size_t)hh*16384];

    f32x4 acc[4][4];
    #pragma unroll
    for (int i = 0; i < 4; ++i)
        #pragma unroll
        for (int j = 0; j < 4; ++j)
            #pragma unroll
            for (int k = 0; k < 4; ++k) acc[i][j][k] = 0.f;

    auto loadA = [&](int kc, int rs) -> uint4 {
        int g = mbase + rs;
        int b = g >> 4, ch = g & 15;
        const float* p = &hx[((size_t)(b*H + hh))*L + ch*CHUNK + kc*32 + q0*8];
        float4 u0 = *(const float4*)p;
        float4 u1 = *(const float4*)(p + 4);
        union { half8 h; uint4 u; } cv;
        cv.h[0] = (_Float16)u0.x; cv.h[1] = (_Float16)u0.y;
        cv.h[2] = (_Float16)u0.z; cv.h[3] = (_Float16)u0.w;
        cv.h[4] = (_Float16)u1.x; cv.h[5] = (_Float16)u1.y;
        cv.h[6] = (_Float16)u1.z; cv.h[7] = (_Float16)u1.w;
        return cv.u;
    };
    uint4 pa0 = loadA(0, r0s), pa1 = loadA(0, r1s);
    uint4 pb0 = *(const uint4*)&zb[r0s*128 + q0*8];
    uint4 pb1 = *(const uint4*)&zb[r1s*128 + q0*8];
    for (int kc = 0; kc < 4; ++kc) {
        __syncthreads();
        *(uint4*)&a_lds[aw0] = pa0;
        *(uint4*)&a_lds[aw1] = pa1;
        *(uint4*)&b_lds[aw0] = pb0;
        *(uint4*)&b_lds[aw1] = pb1;
        uint4 na0 = make_uint4(0,0,0,0), na1 = na0, nb0 = na0, nb1 = na0;
        if (kc < 3) {
            na0 = loadA(kc+1, r0s); na1 = loadA(kc+1, r1s);
            nb0 = *(const uint4*)&zb[r0s*128 + (kc+1)*32 + q0*8];
            nb1 = *(const uint4*)&zb[r1s*128 + (kc+1)*32 + q0*8];
        }
        __syncthreads();
        half8 af[4], bfr[4];
        #pragma unroll
        for (int mf = 0; mf < 4; ++mf) {
            int ra = wm + mf*16 + fr;
            af[mf] = *(const half8*)&a_lds[ra*32 + ((kg ^ SWZ(ra)) * 8)];
        }
        #pragma unroll
        for (int nf = 0; nf < 4; ++nf) {
            int rb = wn + nf*16 + fr;
            bfr[nf] = *(const half8*)&b_lds[rb*32 + ((kg ^ SWZ(rb)) * 8)];
        }
        #pragma unroll
        for (int mf = 0; mf < 4; ++mf)
            #pragma unroll
            for (int nf = 0; nf < 4; ++nf)
                acc[mf][nf] = __builtin_amdgcn_mfma_f32_16x16x32_f16(af[mf], bfr[nf], acc[mf][nf], 0, 0, 0);
        pa0 = na0; pa1 = na1; pb0 = nb0; pb1 = nb1;
    }
    #pragma unroll
    for (int mf = 0; mf < 4; ++mf) {
        #pragma unroll
        for (int rg = 0; rg < 4; ++rg) {
            int m = mbase + wm + mf*16 + kg*4 + rg;
            int b = m >> 4, ch = m & 15;
            float* srow = &states[(((size_t)b*H + hh)*NCH + ch)*128];
            #pragma unroll
            for (int nf = 0; nf < 4; ++nf) {
                int t = wn + nf*16 + fr;
                srow[t] = acc[mf][nf][rg];
            }
        }
    }
}

// ---------------- DSS scan phase 2: exclusive prefix/suffix -> packed fp16 states ----------------
__global__ void k_scan2(const float4* __restrict__ zw, const float2* __restrict__ states,
                        _Float16* __restrict__ stp) {
    int idx = blockIdx.x*256 + threadIdx.x;   // B*H*64 total
    int dn = idx & 63;
    int bh = idx >> 6;
    int hh = bh % H;
    int n = dn & 31, dir = dn >> 5;
    float4 z4 = zw[hh*NST + n];
    float zcre = z4.z, zcim = z4.w;
    const float2* base = &states[bh*NCH*64 + dn];
    _Float16* sb = &stp[(size_t)bh*NCH*128 + dir*64 + n];
    float pre = 0.f, pim = 0.f;
    if (dir == 0) {
        for (int ch = 0; ch < NCH; ++ch) {
            sb[ch*128] = (_Float16)pre; sb[ch*128 + 32] = (_Float16)pim;
            float2 cur = base[ch*64];
            float nre = fmaf(zcre, pre, fmaf(-zcim, pim, cur.x));
            float nim = fmaf(zcre, pim, fmaf(zcim, pre, cur.y));
            pre = nre; pim = nim;
        }
    } else {
        for (int ch = NCH-1; ch >= 0; --ch) {
            sb[ch*128] = (_Float16)pre; sb[ch*128 + 32] = (_Float16)pim;
            float2 cur = base[ch*64];
            float nre = fmaf(zcre, pre, fmaf(-zcim, pim, cur.x));
            float nim = fmaf(zcre, pim, fmaf(zcim, pre, cur.y));
            pre = nre; pim = nim;
        }
    }
}

// ---------------- DSS phase 3 as MFMA GEMM: y = gelu([x|state] @ W_big^T + D*x) ----------------
__global__ __launch_bounds__(256) void k_dssg(const float* __restrict__ hx,
        const _Float16* __restrict__ stp, const _Float16* __restrict__ wbig,
        const float* __restrict__ Dv, float* __restrict__ y, int layer) {
    __shared__ _Float16 a_lds[128*32];
    __shared__ _Float16 b_lds[128*32];
    const int tid = threadIdx.x;
    const int mbase = blockIdx.x * 128;
    const int hh = blockIdx.y;
    const int lane = tid & 63;
    const int w = tid >> 6;
    const int wm = (w >> 1) * 64, wn = (w & 1) * 64;
    const int fr = lane & 15, kg = lane >> 4;
    const int r0s = tid >> 2, q0 = tid & 3;
    const int r1s = 64 + r0s;
    const int aw0 = r0s*32 + ((q0 ^ SWZ(r0s)) * 8);
    const int aw1 = r1s*32 + ((q0 ^ SWZ(r1s)) * 8);
    const _Float16* wb = &wbig[(size_t)hh*32768];

    f32x4 acc[4][4];
    #pragma unroll
    for (int i = 0; i < 4; ++i)
        #pragma unroll
        for (int j = 0; j < 4; ++j)
            #pragma unroll
            for (int k = 0; k < 4; ++k) acc[i][j][k] = 0.f;

    auto loadA = [&](int kc, int rs) -> uint4 {
        int g = mbase + rs;
        int b = g >> 4, ch = g & 15;
        if (kc < 4) {
            const float* p = &hx[((size_t)(b*H + hh))*L + ch*CHUNK + kc*32 + q0*8];
            float4 u0 = *(const float4*)p;
            float4 u1 = *(const float4*)(p + 4);
            union { half8 h; uint4 u; } cv;
            cv.h[0] = (_Float16)u0.x; cv.h[1] = (_Float16)u0.y;
            cv.h[2] = (_Float16)u0.z; cv.h[3] = (_Float16)u0.w;
            cv.h[4] = (_Float16)u1.x; cv.h[5] = (_Float16)u1.y;
            cv.h[6] = (_Float16)u1.z; cv.h[7] = (_Float16)u1.w;
            return cv.u;
        } else {
            return *(const uint4*)&stp[((size_t)(b*H + hh)*NCH + ch)*128 + (kc-4)*32 + q0*8];
        }
    };
    uint4 pa0 = loadA(0, r0s), pa1 = loadA(0, r1s);
    uint4 pb0 = *(const uint4*)&wb[r0s*256 + q0*8];
    uint4 pb1 = *(const uint4*)&wb[r1s*256 + q0*8];
    for (int kc = 0; kc < 8; ++kc) {
        __syncthreads();
        *(uint4*)&a_lds[aw0] = pa0;
        *(uint4*)&a_lds[aw1] = pa1;
        *(uint4*)&b_lds[aw0] = pb0;
        *(uint4*)&b_lds[aw1] = pb1;
        uint4 na0 = make_uint4(0,0,0,0), na1 = na0, nb0 = na0, nb1 = na0;
        if (kc < 7) {
            na0 = loadA(kc+1, r0s); na1 = loadA(kc+1, r1s);
            nb0 = *(const uint4*)&wb[r0s*256 + (kc+1)*32 + q0*8];
            nb1 = *(const uint4*)&wb[r1s*256 + (kc+1)*32 + q0*8];
        }
        __syncthreads();
        half8 af[4], bfr[4];
        #pragma unroll
        for (int mf = 0; mf < 4; ++mf) {
            int ra = wm + mf*16 + fr;
            af[mf] = *(const half8*)&a_lds[ra*32 + ((kg ^ SWZ(ra)) * 8)];
        }
        #pragma unroll
        for (int nf = 0; nf < 4; ++nf) {
            int rb = wn + nf*16 + fr;
            bfr[nf] = *(const half8*)&b_lds[rb*32 + ((kg ^ SWZ(rb)) * 8)];
        }
        #pragma unroll
        for (int mf = 0; mf < 4; ++mf)
            #pragma unroll
            for (int nf = 0; nf < 4; ++nf)
                acc[mf][nf] = __builtin_amdgcn_mfma_f32_16x16x32_f16(af[mf], bfr[nf], acc[mf][nf], 0, 0, 0);
        pa0 = na0; pa1 = na1; pb0 = nb0; pb1 = nb1;
    }
    float dv = Dv[layer*H + hh];
    #pragma unroll
    for (int mf = 0; mf < 4; ++mf) {
        #pragma unroll
        for (int rg = 0; rg < 4; ++rg) {
            int g = mbase + wm + mf*16 + kg*4 + rg;
            int b = g >> 4, ch = g & 15;
            size_t gbase = ((size_t)(b*H + hh))*L + ch*CHUNK;
            #pragma unroll
            for (int nf = 0; nf < 4; ++nf) {
                int t = wn + nf*16 + fr;
                float v = acc[mf][nf][rg] + dv * hx[gbase + t];
                y[gbase + t] = gelu_exact(v);
            }
        }
    }
}

// ---------------- GLU MFMA fp16 ----------------
__global__ __launch_bounds__(256) void k_glu16(const _Float16* __restrict__ yt,
        const _Float16* __restrict__ wg, const float* __restrict__ bias,
        float* __restrict__ zc) {
    __shared__ _Float16 a_lds[128*32];
    __shared__ _Float16 b_lds[128*32];
    const int tid = threadIdx.x;
    const int mbase = blockIdx.x * 128;
    const int o0 = blockIdx.y * 64;
    const int lane = tid & 63;
    const int w = tid >> 6;
    const int wm = (w >> 1) * 64, wn = (w & 1) * 32;
    const int fr = lane & 15, kg = lane >> 4;
    const int r0s = tid >> 2, q0 = tid & 3;
    const int r1s = 64 + r0s;
    const int aw0 = r0s*32 + ((q0 ^ SWZ(r0s)) * 8);
    const int aw1 = r1s*32 + ((q0 ^ SWZ(r1s)) * 8);
    const int og0 = o0 + r0s;
    const int og1 = 256 + o0 + r0s;

    f32x4 accg[4][2], accs[4][2];
    #pragma unroll
    for (int i = 0; i < 4; ++i)
        #pragma unroll
        for (int j = 0; j < 2; ++j)
            #pragma unroll
            for (int k = 0; k < 4; ++k) { accg[i][j][k] = 0.f; accs[i][j][k] = 0.f; }

    uint4 pa0, pa1, pb0, pb1;
    auto loadstep = [&](int kc, uint4& a0, uint4& a1, uint4& b0, uint4& b1) {
        const int cb = kc*32 + q0*8;
        a0 = *(const uint4*)&yt[((size_t)(mbase + r0s))*256 + cb];
        a1 = *(const uint4*)&yt[((size_t)(mbase + r1s))*256 + cb];
        b0 = *(const uint4*)&wg[((size_t)og0)*256 + cb];
        b1 = *(const uint4*)&wg[((size_t)og1)*256 + cb];
    };
    loadstep(0, pa0, pa1, pb0, pb1);
    for (int kc = 0; kc < 8; ++kc) {
        __syncthreads();
        *(uint4*)&a_lds[aw0] = pa0;
        *(uint4*)&a_lds[aw1] = pa1;
        *(uint4*)&b_lds[aw0] = pb0;
        *(uint4*)&b_lds[aw1] = pb1;
        uint4 na0 = make_uint4(0,0,0,0), na1 = na0, nb0 = na0, nb1 = na0;
        if (kc < 7) loadstep(kc+1, na0, na1, nb0, nb1);
        __syncthreads();
        half8 af[4], bg[2], bs[2];
        #pragma unroll
        for (int mf = 0; mf < 4; ++mf) {
            int ra = wm + mf*16 + fr;
            af[mf] = *(const half8*)&a_lds[ra*32 + ((kg ^ SWZ(ra)) * 8)];
        }
        #pragma unroll
        for (int nf = 0; nf < 2; ++nf) {
            int rb = wn + nf*16 + fr;
            bg[nf] = *(const half8*)&b_lds[rb*32 + ((kg ^ SWZ(rb)) * 8)];
            int rb2 = 64 + rb;
            bs[nf] = *(const half8*)&b_lds[rb2*32 + ((kg ^ SWZ(rb2)) * 8)];
        }
        #pragma unroll
        for (int mf = 0; mf < 4; ++mf)
            #pragma unroll
            for (int nf = 0; nf < 2; ++nf) {
                accg[mf][nf] = __builtin_amdgcn_mfma_f32_16x16x32_f16(af[mf], bg[nf], accg[mf][nf], 0, 0, 0);
                accs[mf][nf] = __builtin_amdgcn_mfma_f32_16x16x32_f16(af[mf], bs[nf], accs[mf][nf], 0, 0, 0);
            }
        pa0 = na0; pa1 = na1; pb0 = nb0; pb1 = nb1;
    }
    #pragma unroll
    for (int nf = 0; nf < 2; ++nf) {
        int o = o0 + wn + nf*16 + fr;
        float b0v = bias[o], b1v = bias[256 + o];
        #pragma unroll
        for (int mf = 0; mf < 4; ++mf) {
            #pragma unroll
            for (int rg = 0; rg < 4; ++rg) {
                size_t m = (size_t)mbase + wm + mf*16 + kg*4 + rg;
                float g = accg[mf][nf][rg] + b0v;
                float s = accs[mf][nf][rg] + b1v;
                zc[m*256 + o] = g / (1.f + expf(-s));
            }
        }
    }
}

// ---------------- LayerNorm channel-last z + staged chm residual -> chm h ----------------
// SP: fuse species-embedding add + outseq emission (last layer).
template<bool SP>
__global__ __launch_bounds__(256) void k_ln2(const float* __restrict__ zc,
        float* __restrict__ h, const float* __restrict__ g, const float* __restrict__ bb,
        const int* __restrict__ xs, const float* __restrict__ emb,
        float* __restrict__ outseq) {
    __shared__ float tl[8992];
    int tid = threadIdx.x;
    int b = blockIdx.y;
    int l0 = blockIdx.x * 32;
    for (int j = tid; j < 32*256; j += 256) {
        int c = j >> 5, l = j & 31;
        tl[LDIDX(l, c)] = h[((size_t)(b*H + c))*L + l0 + l];
    }
    __syncthreads();
    int r = tid >> 3, p = tid & 7;
    float v[32];
    float sum = 0.f, ss = 0.f;
    const float* zrow = &zc[((size_t)(b*L + l0 + r))*256 + p*32];
    #pragma unroll
    for (int q = 0; q < 8; ++q) {
        float4 z4 = *(const float4*)&zrow[q*4];
        float zz[4] = {z4.x, z4.y, z4.z, z4.w};
        #pragma unroll
        for (int i = 0; i < 4; ++i) {
            float hv = tl[LDIDX(r, p*32 + q*4 + i)];
            float vv = zz[i] + hv;
            v[q*4+i] = vv;
            sum += vv; ss = fmaf(vv, vv, ss);
        }
    }
    sum += __shfl_xor(sum, 1); ss += __shfl_xor(ss, 1);
    sum += __shfl_xor(sum, 2); ss += __shfl_xor(ss, 2);
    sum += __shfl_xor(sum, 4); ss += __shfl_xor(ss, 4);
    float mu = sum * (1.f/256.f);
    float var = ss * (1.f/256.f) - mu*mu;
    float rs = rsqrtf(var + 1e-5f);
    int sp = SP ? xs[b] : 0;
    #pragma unroll
    for (int q = 0; q < 32; ++q) {
        int c = p*32 + q;
        float val = (v[q] - mu) * rs * g[c] + bb[c];
        if (SP) val += emb[sp*H + c];
        tl[LDIDX(r, c)] = val;
    }
    __syncthreads();
    for (int j = tid; j < 32*256; j += 256) {
        int c = j >> 5, l = j & 31;
        float val = tl[LDIDX(l, c)];
        h[((size_t)(b*H + c))*L + l0 + l] = val;
        if (SP) outseq[((size_t)(b*H + c))*L + l0 + l] = val;
    }
}

// ---------------- MFMA decoder conv K=15 ----------------
__global__ __launch_bounds__(128) void k_dec(const _Float16* __restrict__ ht,
        const _Float16* __restrict__ wdk, const float* __restrict__ bias,
        float* __restrict__ outdec) {
    __shared__ _Float16 a_lds[160*32];
    __shared__ _Float16 b_lds[15*16*32];
    const int tid = threadIdx.x;
    const int mbase = blockIdx.x * 128;
    const int b = mbase >> 11;
    const int lbase = mbase & 2047;
    const int lane = tid & 63;
    const int w = tid >> 6;
    const int fr = lane & 15, kg = lane >> 4;
    const int rs = tid >> 2, q0 = tid & 3;
    f32x4 acc[4];
    #pragma unroll
    for (int i = 0; i < 4; ++i)
        #pragma unroll
        for (int k = 0; k < 4; ++k) acc[i][k] = 0.f;
    for (int cc = 0; cc < 8; ++cc) {
        __syncthreads();
        #pragma unroll
        for (int ps = 0; ps < 5; ++ps) {
            int r = ps*32 + rs;
            if (r < 142) {
                int l = lbase - 7 + r;
                uint4 v = (l >= 0 && l < L) ? *(const uint4*)&ht[((size_t)(b*L + l))*256 + cc*32 + q0*8]
                                            : make_uint4(0,0,0,0);
                *(uint4*)&a_lds[r*32 + ((q0 ^ SWZ(r))*8)] = v;
            }
        }
        for (int jj = tid; jj < 960; jj += 128)
            *(uint4*)&b_lds[jj*8] = *(const uint4*)&wdk[cc*7680 + jj*8];
        __syncthreads();
        #pragma unroll
        for (int k = 0; k < 15; ++k) {
            half8 bfr = *(const half8*)&b_lds[(k*16 + fr)*32 + ((kg ^ SWZ(fr))*8)];
            #pragma unroll
            for (int mf = 0; mf < 4; ++mf) {
                int ra = w*64 + mf*16 + fr + k;
                half8 af = *(const half8*)&a_lds[ra*32 + ((kg ^ SWZ(ra))*8)];
                acc[mf] = __builtin_amdgcn_mfma_f32_16x16x32_f16(af, bfr, acc[mf], 0, 0, 0);
            }
        }
    }
    if (fr < DOUT) {
        float bo = bias[fr];
        #pragma unroll
        for (int mf = 0; mf < 4; ++mf)
            #pragma unroll
            for (int rg = 0; rg < 4; ++rg) {
                int m = mbase + w*64 + mf*16 + kg*4 + rg;
                outdec[((size_t)(b*DOUT + fr))*L + (m & 2047)] = acc[mf][rg] + bo;
            }
    }
}

// ---------------- mean over L ----------------
__global__ __launch_bounds__(256) void k_agg(const float* __restrict__ h, float* __restrict__ agg) {
    __shared__ float red[256];
    int bc = blockIdx.x;
    int tid = threadIdx.x;
    float s = 0.f;
    for (int t = tid; t < L; t += 256) s += h[bc*L + t];
    red[tid] = s; __syncthreads();
    for (int k = 128; k > 0; k >>= 1) {
        if (tid < k) red[tid] += red[tid+k];
        __syncthreads();
    }
    if (tid == 0) agg[bc] = red[0] * (1.f/(float)L);
}

// ---------------- regression MLP ----------------
__global__ __launch_bounds__(128) void k_mlp(const float* __restrict__ agg,
        const float* __restrict__ w1, const float* __restrict__ b1,
        const float* __restrict__ w2, const float* __restrict__ b2,
        const float* __restrict__ w3, const float* __restrict__ b3,
        const float* __restrict__ w4, const float* __restrict__ b4,
        float* __restrict__ outreg) {
    __shared__ float a0[256], r1[128], r2[64], r3[32];
    int b = blockIdx.x, tid = threadIdx.x;
    a0[tid] = agg[b*256 + tid];
    a0[tid+128] = agg[b*256 + tid + 128];
    __syncthreads();
    {
        float s = b1[tid];
        for (int k = 0; k < 256; ++k) s = fmaf(w1[tid*256+k], a0[k], s);
        r1[tid] = s > 0.f ? s : expm1f(s);
    }
    __syncthreads();
    if (tid < 64) {
        float s = b2[tid];
        for (int k = 0; k < 128; ++k) s = fmaf(w2[tid*128+k], r1[k], s);
        r2[tid] = s > 0.f ? s : expm1f(s);
    }
    __syncthreads();
    if (tid < 32) {
        float s = b3[tid];
        for (int k = 0; k < 64; ++k) s = fmaf(w3[tid*64+k], r2[k], s);
        r3[tid] = s > 0.f ? s : expm1f(s);
    }
    __syncthreads();
    if (tid == 0) {
        float s = b4[0];
        for (int k = 0; k < 32; ++k) s = fmaf(w4[k], r3[k], s);
        outreg[b] = s;
    }
}

extern "C" void kernel_launch(void* const* d_in, const int* in_sizes, int n_in,
                              void* d_out, int out_size, void* d_ws, size_t ws_size,
                              hipStream_t stream) {
    const float* x      = (const float*)d_in[0];
    const int*   xs     = (const int*)d_in[1];
    const float* enc_w  = (const float*)d_in[2];
    const float* enc_b  = (const float*)d_in[3];
    const float* res_w1 = (const float*)d_in[4];
    const float* res_b1 = (const float*)d_in[5];
    const float* res_w2 = (const float*)d_in[6];
    const float* res_b2 = (const float*)d_in[7];
    const float* log_dt = (const float*)d_in[8];
    const float* lam_re = (const float*)d_in[9];
    const float* lam_im = (const float*)d_in[10];
    const float* W_re   = (const float*)d_in[11];
    const float* W_im   = (const float*)d_in[12];
    const float* Dv     = (const float*)d_in[13];
    const float* glu_w  = (const float*)d_in[14];
    const float* glu_b  = (const float*)d_in[15];
    const float* ln_g   = (const float*)d_in[16];
    const float* ln_b   = (const float*)d_in[17];
    const float* dec_w  = (const float*)d_in[18];
    const float* dec_b  = (const float*)d_in[19];
    const float* sp_emb = (const float*)d_in[20];
    const float* h1_w = (const float*)d_in[21]; const float* h1_b = (const float*)d_in[22];
    const float* h2_w = (const float*)d_in[23]; const float* h2_b = (const float*)d_in[24];
    const float* h3_w = (const float*)d_in[25]; const float* h3_b = (const float*)d_in[26];
    const float* h4_w = (const float*)d_in[27]; const float* h4_b = (const float*)d_in[28];

    float* ws   = (float*)d_ws;
    float* h    = ws;                                  // LSEQ f32 [b][c][l]
    float* t1   = ws + (size_t)LSEQ;                   // LSEQ f32
    float* t2   = ws + (size_t)2*LSEQ;                 // LSEQ f32
    float2* states = (float2*)t2;                      // sgem output (all of t2)
    // res-phase aliases (dead once DSS starts):
    _Float16* xa  = (_Float16*)t1;
    _Float16* xb  = xa + (size_t)LSEQ;
    _Float16* wpk = (_Float16*)t2;
    // DSS-phase aliases:
    _Float16* stp  = (_Float16*)t1;                    // packed states, t1 lower half
    _Float16* wbig = (_Float16*)t1 + (size_t)LSEQ;     // 16.8MB fp16, t1 upper half
    _Float16* zp   = wbig + (size_t)H*32768;           // 8.4MB fp16, after wbig
    _Float16* yt   = (_Float16*)t1;                    // fp16 chl y (after dssg), t1 lower
    float* yb      = t2;                               // dssg output y f32 chm
    float* zcb     = t2;                               // glu output chl f32 (y dead)
    // tail region:
    float* tail = ws + (size_t)3*LSEQ;
    _Float16* wg  = (_Float16*)tail;                   // 512*256 fp16
    float4* zwb = (float4*)(tail + 65536);             // H*NST float4
    float* aggb = tail + 65536 + 32768;                // B*H
    _Float16* wdk = (_Float16*)(aggb + 8192);          // 61440 fp16
    _Float16* wenc = wdk + 61440;                      // 256*96 fp16

    float* outdec = (float*)d_out;
    float* outseq = outdec + B*DOUT*L;
    float* outreg = outseq + (size_t)LSEQ;

    // encoder (MFMA, writes fp16 channel-last directly)
    k_wenc<<<96, 256, 0, stream>>>(enc_w, wenc);
    k_enc<<<dim3(B*L/128, 2), 256, 0, stream>>>(x, wenc, enc_b, xa);

    // residual stack (fp16 MFMA, channel-last)
    k_wpack<<<(NRES*2*3*65536 + 255)/256, 256, 0, stream>>>(res_w1, res_w2, wpk);
    for (int r = 0; r < NRES; ++r) {
        k_cv3<false><<<dim3(B*L/128, 2), 256, 0, stream>>>(
            xa, wpk + (size_t)(r*2+0)*3*65536, res_b1 + r*H, nullptr, xb);
        k_cv3<true><<<dim3(B*L/128, 2), 256, 0, stream>>>(
            xb, wpk + (size_t)(r*2+1)*3*65536, res_b2 + r*H, xa, xa);
    }
    k_t_cf<<<dim3(L/64, H/64, B), 256, 0, stream>>>(xa, h);

    // DSS blocks
    for (int i = 0; i < NLAYERS; ++i) {
        k_zw<<<(H*NST + 255)/256, 256, 0, stream>>>(log_dt, lam_re, lam_im, zwb, i);
        k_wzp<<<H, 128, 0, stream>>>(zwb, zp);
        k_wkern<<<H, 128, 0, stream>>>(log_dt, lam_re, lam_im, W_re, W_im, wbig, i);
        k_wtg16<<<(512*256 + 255)/256, 256, 0, stream>>>(glu_w, wg, i);
        k_sgem<<<dim3(4, H), 256, 0, stream>>>(h, zp, (float*)states);
        k_scan2<<<(B*H*64)/256, 256, 0, stream>>>(zwb, states, stp);
        k_dssg<<<dim3(4, H), 256, 0, stream>>>(h, stp, wbig, Dv, yb, i);
        k_t_cl<<<dim3(L/64, H/64, B), 256, 0, stream>>>(yb, yt);
        k_glu16<<<dim3(B*L/128, 4), 256, 0, stream>>>(yt, wg, glu_b + i*512, zcb);
        if (i < NLAYERS - 1)
            k_ln2<false><<<dim3(L/32, B), 256, 0, stream>>>(zcb, h, ln_g + i*H, ln_b + i*H,
                                                            nullptr, nullptr, nullptr);
        else
            k_ln2<true><<<dim3(L/32, B), 256, 0, stream>>>(zcb, h, ln_g + i*H, ln_b + i*H,
                                                           xs, sp_emb, outseq);
    }

    // aggregate + regression head
    k_agg<<<B*H, 256, 0, stream>>>(h, aggb);
    k_mlp<<<B, 128, 0, stream>>>(aggb, h1_w, h1_b, h2_w, h2_b, h3_w, h3_b, h4_w, h4_b, outreg);
    // decoder
    k_t_cl<<<dim3(L/64, H/64, B), 256, 0, stream>>>(h, (_Float16*)t1);
    k_wdec<<<(15*16*256 + 255)/256, 256, 0, stream>>>(dec_w, wdk);
    k_dec<<<B*L/128, 128, 0, stream>>>((_Float16*)t1, wdk, dec_b, outdec);
}

// Round 7
// 1319.041 us; speedup vs baseline: 4.9682x; 1.1558x over previous
//
#include <hip/hip_runtime.h>
#include <math.h>

#define B 32
#define L 2048
#define DIN 5
#define DOUT 5
#define H 256
#define NST 32
#define NLAYERS 4
#define NRES 3
#define CHUNK 128
#define NCH 16            // L / CHUNK
#define LSEQ (B*H*L)      // 16777216

typedef __attribute__((ext_vector_type(8))) _Float16 half8;
typedef __attribute__((ext_vector_type(4))) float f32x4;

__device__ __forceinline__ float gelu_exact(float v) {
    return 0.5f * v * (1.0f + erff(v * 0.7071067811865475f));
}
#define SWZ(r) ((((r) ^ ((r) >> 2)) & 3))
#define LDIDX(l, c) ((l)*281 + ((c)>>5)*35 + ((c)&31))

// ---------------- encoder weight pack ----------------
__global__ void k_wenc(const float* __restrict__ ew, _Float16* __restrict__ wenc) {
    int idx = blockIdx.x*256 + threadIdx.x;
    if (idx >= 256*96) return;
    int o = idx / 96, kk = idx % 96;
    int ci = kk >> 4, k = kk & 15;
    float v = (ci < DIN && k < 15) ? ew[(o*DIN + ci)*15 + k] : 0.f;
    wenc[idx] = (_Float16)v;
}

// ---------------- MFMA encoder conv K=15 Cin=5 ----------------
__global__ __launch_bounds__(256) void k_enc(const float* __restrict__ x,
        const _Float16* __restrict__ wenc, const float* __restrict__ bias,
        _Float16* __restrict__ out) {
    __shared__ _Float16 a_lds[3*128*32];
    __shared__ _Float16 b_lds[3*128*32];
    const int tid = threadIdx.x;
    const int mbase = blockIdx.x * 128;
    const int oh = blockIdx.y;
    const int b = mbase >> 11;
    const int lbase = mbase & 2047;
    const int lane = tid & 63;
    const int w = tid >> 6;
    const int wm = (w >> 1) * 64, wn = (w & 1) * 64;
    const int fr = lane & 15, kg = lane >> 4;

    #pragma unroll
    for (int i = 0; i < 6; ++i) {
        int g = i*256 + tid;
        int r = g / 12, rem = g % 12;
        int ks = rem >> 2, q = rem & 3;
        int kk0 = ks*32 + q*8;
        int ci = kk0 >> 4, k0 = kk0 & 15;
        half8 va;
        #pragma unroll
        for (int e = 0; e < 8; ++e) {
            int k = k0 + e;
            int l = lbase + r - 7 + k;
            float v = (ci < DIN && k < 15 && l >= 0 && l < L)
                        ? x[((size_t)(b*DIN + ci))*L + l] : 0.f;
            va[e] = (_Float16)v;
        }
        *(half8*)&a_lds[ks*4096 + r*32 + ((q ^ SWZ(r))*8)] = va;
        uint4 vb = *(const uint4*)&wenc[(size_t)(oh*128 + r)*96 + kk0];
        *(uint4*)&b_lds[ks*4096 + r*32 + ((q ^ SWZ(r))*8)] = vb;
    }
    __syncthreads();
    f32x4 acc[4][4];
    #pragma unroll
    for (int i = 0; i < 4; ++i)
        #pragma unroll
        for (int j = 0; j < 4; ++j)
            #pragma unroll
            for (int k = 0; k < 4; ++k) acc[i][j][k] = 0.f;
    #pragma unroll
    for (int ks = 0; ks < 3; ++ks) {
        half8 af[4], bfr[4];
        #pragma unroll
        for (int mf = 0; mf < 4; ++mf) {
            int ra = wm + mf*16 + fr;
            af[mf] = *(const half8*)&a_lds[ks*4096 + ra*32 + ((kg ^ SWZ(ra))*8)];
        }
        #pragma unroll
        for (int nf = 0; nf < 4; ++nf) {
            int rb = wn + nf*16 + fr;
            bfr[nf] = *(const half8*)&b_lds[ks*4096 + rb*32 + ((kg ^ SWZ(rb))*8)];
        }
        #pragma unroll
        for (int mf = 0; mf < 4; ++mf)
            #pragma unroll
            for (int nf = 0; nf < 4; ++nf)
                acc[mf][nf] = __builtin_amdgcn_mfma_f32_16x16x32_f16(af[mf], bfr[nf], acc[mf][nf], 0, 0, 0);
    }
    #pragma unroll
    for (int nf = 0; nf < 4; ++nf) {
        int o = oh*128 + wn + nf*16 + fr;
        float bo = bias[o];
        #pragma unroll
        for (int mf = 0; mf < 4; ++mf)
            #pragma unroll
            for (int rg = 0; rg < 4; ++rg) {
                size_t m = (size_t)mbase + wm + mf*16 + kg*4 + rg;
                out[m*256 + o] = (_Float16)(acc[mf][nf][rg] + bo);
            }
    }
}

// ---------------- res weight pack ----------------
__global__ void k_wpack(const float* __restrict__ w1, const float* __restrict__ w2,
                        _Float16* __restrict__ wpk) {
    int idx = blockIdx.x*256 + threadIdx.x;
    if (idx >= NRES*2*3*65536) return;
    int ci = idx & 255;
    int o  = (idx >> 8) & 255;
    int k  = (idx >> 16) % 3;
    int cv = idx / (3*65536);
    const float* src = (cv & 1) ? w2 : w1;
    wpk[idx] = (_Float16)src[(((cv>>1)*H + o)*H + ci)*3 + k];
}

// ---------------- transpose f32 chm -> fp16 chl (decoder prep) ----------------
__global__ __launch_bounds__(256) void k_t_cl(const float* __restrict__ in,
                                              _Float16* __restrict__ out) {
    __shared__ float t[64][65];
    int tid = threadIdx.x;
    int l0 = blockIdx.x*64, c0 = blockIdx.y*64, b = blockIdx.z;
    #pragma unroll
    for (int i = 0; i < 16; ++i) {
        int idx = i*256 + tid;
        int c = idx >> 6, l = idx & 63;
        t[c][l] = in[((size_t)(b*H + c0 + c))*L + l0 + l];
    }
    __syncthreads();
    #pragma unroll
    for (int i = 0; i < 16; ++i) {
        int idx = i*256 + tid;
        int l = idx >> 6, c = idx & 63;
        out[((size_t)b*L + l0 + l)*256 + c0 + c] = (_Float16)t[c][l];
    }
}

// ---------------- transpose fp16 chl -> f32 chm + fp16 chm mirror ----------------
__global__ __launch_bounds__(256) void k_t_cf(const _Float16* __restrict__ in,
        float* __restrict__ out, _Float16* __restrict__ out16) {
    __shared__ float t[64][65];
    int tid = threadIdx.x;
    int l0 = blockIdx.x*64, c0 = blockIdx.y*64, b = blockIdx.z;
    #pragma unroll
    for (int i = 0; i < 16; ++i) {
        int idx = i*256 + tid;
        int l = idx >> 6, c = idx & 63;
        t[c][l] = (float)in[((size_t)b*L + l0 + l)*256 + c0 + c];
    }
    __syncthreads();
    #pragma unroll
    for (int i = 0; i < 16; ++i) {
        int idx = i*256 + tid;
        int c = idx >> 6, l = idx & 63;
        float v = t[c][l];
        out[((size_t)(b*H + c0 + c))*L + l0 + l] = v;
        out16[((size_t)(b*H + c0 + c))*L + l0 + l] = (_Float16)v;
    }
}

// ---------------- transpose fp16 chm -> fp16 chl ----------------
__global__ __launch_bounds__(256) void k_t16(const _Float16* __restrict__ in,
                                             _Float16* __restrict__ out) {
    __shared__ float t[64][65];
    int tid = threadIdx.x;
    int l0 = blockIdx.x*64, c0 = blockIdx.y*64, b = blockIdx.z;
    #pragma unroll
    for (int i = 0; i < 16; ++i) {
        int idx = i*256 + tid;
        int c = idx >> 6, l = idx & 63;
        t[c][l] = (float)in[((size_t)(b*H + c0 + c))*L + l0 + l];
    }
    __syncthreads();
    #pragma unroll
    for (int i = 0; i < 16; ++i) {
        int idx = i*256 + tid;
        int l = idx >> 6, c = idx & 63;
        out[((size_t)b*L + l0 + l)*256 + c0 + c] = (_Float16)t[c][l];
    }
}

// ---------------- MFMA residual conv K=3 (fp16); grid (2, B*L/128) ----------------
template<bool RESID>
__global__ __launch_bounds__(256) void k_cv3(const _Float16* __restrict__ xin,
        const _Float16* __restrict__ wpk, const float* __restrict__ bias,
        const _Float16* __restrict__ resid, _Float16* __restrict__ out) {
    __shared__ _Float16 a_lds[128*32];
    __shared__ _Float16 b_lds[128*32];
    const int tid = threadIdx.x;
    const int mbase = blockIdx.y * 128;
    const int o0 = blockIdx.x * 128;
    const int lane = tid & 63;
    const int w = tid >> 6;
    const int wm = (w >> 1) * 64, wn = (w & 1) * 64;
    const int fr = lane & 15, kg = lane >> 4;

    const int r0s = tid >> 2, q0 = tid & 3;
    const int r1s = 64 + (tid >> 2);
    const int aw0 = r0s*32 + ((q0 ^ SWZ(r0s)) * 8);
    const int aw1 = r1s*32 + ((q0 ^ SWZ(r1s)) * 8);

    f32x4 acc[4][4];
    #pragma unroll
    for (int i = 0; i < 4; ++i)
        #pragma unroll
        for (int j = 0; j < 4; ++j)
            #pragma unroll
            for (int k = 0; k < 4; ++k) acc[i][j][k] = 0.f;

    uint4 pa0, pa1, pb0, pb1;
    auto loadstep = [&](int kk, uint4& a0, uint4& a1, uint4& b0, uint4& b1) {
        const int koff = kk >> 3, cic = kk & 7;
        const int cb = cic*32 + q0*8;
        {
            int m = mbase + r0s;
            int ll = (m & (L-1)) + koff - 1;
            a0 = (ll >= 0 && ll < L) ? *(const uint4*)&xin[((size_t)(m + koff - 1))*256 + cb]
                                     : make_uint4(0,0,0,0);
            int m1 = mbase + r1s;
            int l1 = (m1 & (L-1)) + koff - 1;
            a1 = (l1 >= 0 && l1 < L) ? *(const uint4*)&xin[((size_t)(m1 + koff - 1))*256 + cb]
                                     : make_uint4(0,0,0,0);
        }
        b0 = *(const uint4*)&wpk[((size_t)(koff*256 + o0 + r0s))*256 + cb];
        b1 = *(const uint4*)&wpk[((size_t)(koff*256 + o0 + r1s))*256 + cb];
    };
    loadstep(0, pa0, pa1, pb0, pb1);
    for (int kk = 0; kk < 24; ++kk) {
        __syncthreads();
        *(uint4*)&a_lds[aw0] = pa0;
        *(uint4*)&a_lds[aw1] = pa1;
        *(uint4*)&b_lds[aw0] = pb0;
        *(uint4*)&b_lds[aw1] = pb1;
        uint4 na0 = make_uint4(0,0,0,0), na1 = na0, nb0 = na0, nb1 = na0;
        if (kk < 23) loadstep(kk+1, na0, na1, nb0, nb1);
        __syncthreads();
        half8 af[4], bfr[4];
        #pragma unroll
        for (int mf = 0; mf < 4; ++mf) {
            int ra = wm + mf*16 + fr;
            af[mf] = *(const half8*)&a_lds[ra*32 + ((kg ^ SWZ(ra)) * 8)];
        }
        #pragma unroll
        for (int nf = 0; nf < 4; ++nf) {
            int rb = wn + nf*16 + fr;
            bfr[nf] = *(const half8*)&b_lds[rb*32 + ((kg ^ SWZ(rb)) * 8)];
        }
        #pragma unroll
        for (int mf = 0; mf < 4; ++mf)
            #pragma unroll
            for (int nf = 0; nf < 4; ++nf)
                acc[mf][nf] = __builtin_amdgcn_mfma_f32_16x16x32_f16(af[mf], bfr[nf], acc[mf][nf], 0, 0, 0);
        pa0 = na0; pa1 = na1; pb0 = nb0; pb1 = nb1;
    }
    const int orow = kg * 4;
    #pragma unroll
    for (int nf = 0; nf < 4; ++nf) {
        int o = o0 + wn + nf*16 + fr;
        float bo = bias[o];
        #pragma unroll
        for (int mf = 0; mf < 4; ++mf) {
            #pragma unroll
            for (int rg = 0; rg < 4; ++rg) {
                size_t m = (size_t)mbase + wm + mf*16 + orow + rg;
                float v = acc[mf][nf][rg] + bo;
                if (RESID) v += (float)resid[m*256 + o];
                v = fmaxf(v, 0.f);
                out[m*256 + o] = (_Float16)v;
            }
        }
    }
}

// ---------------- DSS: per-(h,n) pole z and z^CHUNK ----------------
__global__ void k_zw(const float* __restrict__ log_dt, const float* __restrict__ lam_re,
                     const float* __restrict__ lam_im, float4* __restrict__ zwbuf, int layer) {
    int idx = blockIdx.x*256 + threadIdx.x;
    if (idx >= H*NST) return;
    int hh = idx / NST, n = idx % NST;
    float dt = expf(log_dt[layer*H + hh]);
    float a  = dt * lam_re[layer*NST + n];
    float bi = dt * lam_im[layer*NST + n];
    float er = expf(a);
    float zre = er * cosf(bi), zim = er * sinf(bi);
    float eC = expf(a * (float)CHUNK);
    float bC = bi * (float)CHUNK;
    float zcre = eC * cosf(bC), zcim = eC * sinf(bC);
    zwbuf[idx] = make_float4(zre, zim, zcre, zcim);
}

// ---------------- Z-power matrix zp[h][t][j] fp16 (t = dn*2+c) ----------------
__global__ __launch_bounds__(128) void k_wzp(const float4* __restrict__ zw,
        _Float16* __restrict__ zp) {
    int hh = blockIdx.x;
    int t = threadIdx.x;
    int dn = t >> 1, c = t & 1, dir = dn >> 5, n = dn & 31;
    float4 z4 = zw[hh*NST + n];
    float zre = z4.x, zim = z4.y;
    _Float16* dst = &zp[(size_t)hh*16384 + t*128];
    float cr = 1.f, ci = 0.f;
    for (int p = 0; p < 128; ++p) {
        float val = c ? ci : cr;
        dst[dir ? p : (127 - p)] = (_Float16)val;
        float nr = cr*zre - ci*zim;
        float ni = cr*zim + ci*zre;
        cr = nr; ci = ni;
    }
}

// ---------------- W_big[h][t][256] fp16 ----------------
__global__ __launch_bounds__(128) void k_wkern(const float* __restrict__ log_dt,
        const float* __restrict__ lam_re, const float* __restrict__ lam_im,
        const float* __restrict__ W_re, const float* __restrict__ W_im,
        _Float16* __restrict__ wbig, int layer) {
    __shared__ float kf[128], kb[128];
    __shared__ float E[128*129];
    const int hh = blockIdx.x;
    const int t = threadIdx.x;
    float dt = expf(log_dt[layer*H + hh]);
    float skf = 0.f, skb = 0.f;
    for (int n = 0; n < 32; ++n) {
        float a  = dt * lam_re[layer*NST + n];
        float bi = dt * lam_im[layer*NST + n];
        float wfr = W_re[((layer*2+0)*H + hh)*NST + n];
        float wfi = W_im[((layer*2+0)*H + hh)*NST + n];
        float wbr = W_re[((layer*2+1)*H + hh)*NST + n];
        float wbi = W_im[((layer*2+1)*H + hh)*NST + n];
        float e0 = expf(a*t), s0, c0; sincosf(bi*t, &s0, &c0);
        float zr0 = e0*c0, zi0 = e0*s0;
        skf = fmaf(wfr, zr0, skf) - wfi*zi0;
        skb = fmaf(wbr, zr0, skb) - wbi*zi0;
        float e1 = expf(a*(t+1)), s1, c1; sincosf(bi*(t+1), &s1, &c1);
        float zr1 = e1*c1, zi1 = e1*s1;
        E[t*129 + n]      = wfr*zr1 - wfi*zi1;
        E[t*129 + 32 + n] = -(wfr*zi1 + wfi*zr1);
        float e2 = expf(a*(127-t)), s2, c2; sincosf(bi*(127-t), &s2, &c2);
        float zr2 = e2*c2, zi2 = e2*s2;
        E[t*129 + 64 + n] = wbr*zr2 - wbi*zi2;
        E[t*129 + 96 + n] = -(wbr*zi2 + wbi*zr2);
    }
    kf[t] = skf; kb[t] = skb;
    __syncthreads();
    _Float16* dst = &wbig[(size_t)hh*32768];
    for (int idx = t; idx < 128*256; idx += 128) {
        int tt = idx >> 8, k = idx & 255;
        float v;
        if (k < 128) v = (k <= tt) ? kf[tt - k] : kb[k - tt - 1];
        else         v = E[tt*129 + (k - 128)];
        dst[idx] = (_Float16)v;
    }
}

// ---------------- GLU weight pack ----------------
__global__ void k_wtg16(const float* __restrict__ gw, _Float16* __restrict__ wg, int layer) {
    int idx = blockIdx.x*256 + threadIdx.x;
    if (idx >= 512*256) return;
    wg[idx] = (_Float16)gw[layer*512*256 + idx];
}

// ---------------- decoder weight pack ----------------
__global__ void k_wdec(const float* __restrict__ dw, _Float16* __restrict__ wdk) {
    int idx = blockIdx.x*256 + threadIdx.x;
    if (idx >= 15*16*256) return;
    int cfull = idx & 255;
    int o = (idx >> 8) & 15;
    int k = idx >> 12;
    float v = (o < DOUT) ? dw[(o*H + cfull)*15 + k] : 0.f;
    int cc = cfull >> 5, cl = cfull & 31;
    int cq = cl >> 3, cb = cl & 7;
    wdk[cc*7680 + (k*16 + o)*32 + ((cq ^ SWZ(o))*8) + cb] = (_Float16)v;
}

// ---------------- FUSED DSS: S-GEMM -> in-LDS chunk scan -> [x|state] GEMM -> gelu ----------------
// grid (8, H): block = 4 b's x 16 chunks x one h. 64KB LDS, 2 blocks/CU.
__global__ __launch_bounds__(256) void k_dss(const _Float16* __restrict__ hm16,
        const _Float16* __restrict__ zp, const _Float16* __restrict__ wbig,
        const float4* __restrict__ zwb, const float* __restrict__ Dv,
        _Float16* __restrict__ y16, int layer) {
    __shared__ _Float16 xbuf[4*64*32];    // 16KB: x fp16, 4 K-panels
    __shared__ _Float16 bbuf[2*128*32];   // 16KB: zp dbuf -> stp (4 panels 64x32)
    __shared__ float    sbuf[64*128];     // 32KB: S f32 -> wbig dbuf (fp16)
    _Float16* sb16 = (_Float16*)sbuf;

    const int tid = threadIdx.x;
    const int b0 = blockIdx.x * 4;
    const int hh = blockIdx.y;
    const int lane = tid & 63;
    const int w = tid >> 6;
    const int wn = w * 32;
    const int fr = lane & 15, kg = lane >> 4;

    // stage x (64 rows x 128 j)
    #pragma unroll
    for (int i = 0; i < 4; ++i) {
        int g = i*256 + tid;
        int m = g >> 4, gi = g & 15;
        int kc = gi >> 2, q = gi & 3;
        uint4 v = *(const uint4*)&hm16[((size_t)((b0 + (m>>4))*H + hh))*L
                                       + (m&15)*128 + kc*32 + q*8];
        *(uint4*)&xbuf[kc*2048 + m*32 + ((q ^ SWZ(m))*8)] = v;
    }

    // ---- phase 1: S = x . zp^T  (M=64, N=128, K=128) ----
    f32x4 acc1[4][2];
    #pragma unroll
    for (int i = 0; i < 4; ++i)
        #pragma unroll
        for (int j = 0; j < 2; ++j)
            #pragma unroll
            for (int k = 0; k < 4; ++k) acc1[i][j][k] = 0.f;
    const _Float16* zb = &zp[(size_t)hh*16384];
    const int gr0 = tid >> 2, gq0 = tid & 3;        // granule 0: rows 0-63
    const int gr1 = 64 + gr0;                       // granule 1: rows 64-127
    uint4 pb0 = *(const uint4*)&zb[gr0*128 + gq0*8];
    uint4 pb1 = *(const uint4*)&zb[gr1*128 + gq0*8];
    for (int kc = 0; kc < 4; ++kc) {
        __syncthreads();
        *(uint4*)&bbuf[(kc&1)*4096 + gr0*32 + ((gq0 ^ SWZ(gr0))*8)] = pb0;
        *(uint4*)&bbuf[(kc&1)*4096 + gr1*32 + ((gq0 ^ SWZ(gr1))*8)] = pb1;
        if (kc < 3) {
            pb0 = *(const uint4*)&zb[gr0*128 + (kc+1)*32 + gq0*8];
            pb1 = *(const uint4*)&zb[gr1*128 + (kc+1)*32 + gq0*8];
        }
        __syncthreads();
        half8 af[4], bf2[2];
        #pragma unroll
        for (int mf = 0; mf < 4; ++mf) {
            int ra = mf*16 + fr;
            af[mf] = *(const half8*)&xbuf[kc*2048 + ra*32 + ((kg ^ SWZ(ra))*8)];
        }
        #pragma unroll
        for (int nf = 0; nf < 2; ++nf) {
            int rb = wn + nf*16 + fr;
            bf2[nf] = *(const half8*)&bbuf[(kc&1)*4096 + rb*32 + ((kg ^ SWZ(rb))*8)];
        }
        #pragma unroll
        for (int mf = 0; mf < 4; ++mf)
            #pragma unroll
            for (int nf = 0; nf < 2; ++nf)
                acc1[mf][nf] = __builtin_amdgcn_mfma_f32_16x16x32_f16(af[mf], bf2[nf], acc1[mf][nf], 0, 0, 0);
    }
    // dump S
    #pragma unroll
    for (int mf = 0; mf < 4; ++mf)
        #pragma unroll
        for (int nf = 0; nf < 2; ++nf)
            #pragma unroll
            for (int rg = 0; rg < 4; ++rg)
                sbuf[(mf*16 + kg*4 + rg)*128 + wn + nf*16 + fr] = acc1[mf][nf][rg];
    __syncthreads();

    // ---- phase 2: in-LDS cross-chunk scan (f32), pack stp fp16 into bbuf ----
    {
        int b_loc = tid >> 6, dn = tid & 63;
        int dir = dn >> 5, n = dn & 31;
        float4 z4 = zwb[hh*NST + n];
        float zcre = z4.z, zcim = z4.w;
        int q1 = n >> 3, e1 = n & 7;
        float pre = 0.f, pim = 0.f;
        for (int s = 0; s < NCH; ++s) {
            int ch = dir ? (NCH - 1 - s) : s;
            int m = b_loc*16 + ch;
            bbuf[(dir*2 + 0)*2048 + m*32 + ((q1 ^ SWZ(m))*8) + e1] = (_Float16)pre;
            bbuf[(dir*2 + 1)*2048 + m*32 + ((q1 ^ SWZ(m))*8) + e1] = (_Float16)pim;
            float cre = sbuf[m*128 + dn*2];
            float cim = sbuf[m*128 + dn*2 + 1];
            float nre = fmaf(zcre, pre, fmaf(-zcim, pim, cre));
            float nim = fmaf(zcre, pim, fmaf(zcim, pre, cim));
            pre = nre; pim = nim;
        }
    }
    __syncthreads();

    // ---- phase 3: y = [x | stp] . wbig^T  (M=64, N=128, K=256) ----
    f32x4 acc3[4][2];
    #pragma unroll
    for (int i = 0; i < 4; ++i)
        #pragma unroll
        for (int j = 0; j < 2; ++j)
            #pragma unroll
            for (int k = 0; k < 4; ++k) acc3[i][j][k] = 0.f;
    const _Float16* wb = &wbig[(size_t)hh*32768];
    pb0 = *(const uint4*)&wb[gr0*256 + gq0*8];
    pb1 = *(const uint4*)&wb[gr1*256 + gq0*8];
    for (int kc = 0; kc < 8; ++kc) {
        __syncthreads();
        *(uint4*)&sb16[(kc&1)*4096 + gr0*32 + ((gq0 ^ SWZ(gr0))*8)] = pb0;
        *(uint4*)&sb16[(kc&1)*4096 + gr1*32 + ((gq0 ^ SWZ(gr1))*8)] = pb1;
        if (kc < 7) {
            pb0 = *(const uint4*)&wb[gr0*256 + (kc+1)*32 + gq0*8];
            pb1 = *(const uint4*)&wb[gr1*256 + (kc+1)*32 + gq0*8];
        }
        __syncthreads();
        half8 af[4], bf2[2];
        #pragma unroll
        for (int mf = 0; mf < 4; ++mf) {
            int ra = mf*16 + fr;
            af[mf] = (kc < 4)
                ? *(const half8*)&xbuf[kc*2048 + ra*32 + ((kg ^ SWZ(ra))*8)]
                : *(const half8*)&bbuf[(kc-4)*2048 + ra*32 + ((kg ^ SWZ(ra))*8)];
        }
        #pragma unroll
        for (int nf = 0; nf < 2; ++nf) {
            int rb = wn + nf*16 + fr;
            bf2[nf] = *(const half8*)&sb16[(kc&1)*4096 + rb*32 + ((kg ^ SWZ(rb))*8)];
        }
        #pragma unroll
        for (int mf = 0; mf < 4; ++mf)
            #pragma unroll
            for (int nf = 0; nf < 2; ++nf)
                acc3[mf][nf] = __builtin_amdgcn_mfma_f32_16x16x32_f16(af[mf], bf2[nf], acc3[mf][nf], 0, 0, 0);
    }
    // epilogue: + D*x (x from LDS fp16), gelu, write fp16 chm
    float dv = Dv[layer*H + hh];
    #pragma unroll
    for (int mf = 0; mf < 4; ++mf) {
        #pragma unroll
        for (int rg = 0; rg < 4; ++rg) {
            int m = mf*16 + kg*4 + rg;
            size_t gb = ((size_t)((b0 + (m>>4))*H + hh))*L + (m&15)*128;
            #pragma unroll
            for (int nf = 0; nf < 2; ++nf) {
                int t = wn + nf*16 + fr;
                float xv = (float)xbuf[(t>>5)*2048 + m*32 + ((((t&31)>>3) ^ SWZ(m))*8) + (t&7)];
                float v = acc3[mf][nf][rg] + dv * xv;
                y16[gb + t] = (_Float16)gelu_exact(v);
            }
        }
    }
}

// ---------------- GLU MFMA fp16; grid (4, B*L/128) ----------------
__global__ __launch_bounds__(256) void k_glu16(const _Float16* __restrict__ yt,
        const _Float16* __restrict__ wg, const float* __restrict__ bias,
        float* __restrict__ zc) {
    __shared__ _Float16 a_lds[128*32];
    __shared__ _Float16 b_lds[128*32];
    const int tid = threadIdx.x;
    const int mbase = blockIdx.y * 128;
    const int o0 = blockIdx.x * 64;
    const int lane = tid & 63;
    const int w = tid >> 6;
    const int wm = (w >> 1) * 64, wn = (w & 1) * 32;
    const int fr = lane & 15, kg = lane >> 4;
    const int r0s = tid >> 2, q0 = tid & 3;
    const int r1s = 64 + r0s;
    const int aw0 = r0s*32 + ((q0 ^ SWZ(r0s)) * 8);
    const int aw1 = r1s*32 + ((q0 ^ SWZ(r1s)) * 8);
    const int og0 = o0 + r0s;
    const int og1 = 256 + o0 + r0s;

    f32x4 accg[4][2], accs[4][2];
    #pragma unroll
    for (int i = 0; i < 4; ++i)
        #pragma unroll
        for (int j = 0; j < 2; ++j)
            #pragma unroll
            for (int k = 0; k < 4; ++k) { accg[i][j][k] = 0.f; accs[i][j][k] = 0.f; }

    uint4 pa0, pa1, pb0, pb1;
    auto loadstep = [&](int kc, uint4& a0, uint4& a1, uint4& b0, uint4& b1) {
        const int cb = kc*32 + q0*8;
        a0 = *(const uint4*)&yt[((size_t)(mbase + r0s))*256 + cb];
        a1 = *(const uint4*)&yt[((size_t)(mbase + r1s))*256 + cb];
        b0 = *(const uint4*)&wg[((size_t)og0)*256 + cb];
        b1 = *(const uint4*)&wg[((size_t)og1)*256 + cb];
    };
    loadstep(0, pa0, pa1, pb0, pb1);
    for (int kc = 0; kc < 8; ++kc) {
        __syncthreads();
        *(uint4*)&a_lds[aw0] = pa0;
        *(uint4*)&a_lds[aw1] = pa1;
        *(uint4*)&b_lds[aw0] = pb0;
        *(uint4*)&b_lds[aw1] = pb1;
        uint4 na0 = make_uint4(0,0,0,0), na1 = na0, nb0 = na0, nb1 = na0;
        if (kc < 7) loadstep(kc+1, na0, na1, nb0, nb1);
        __syncthreads();
        half8 af[4], bg[2], bs[2];
        #pragma unroll
        for (int mf = 0; mf < 4; ++mf) {
            int ra = wm + mf*16 + fr;
            af[mf] = *(const half8*)&a_lds[ra*32 + ((kg ^ SWZ(ra)) * 8)];
        }
        #pragma unroll
        for (int nf = 0; nf < 2; ++nf) {
            int rb = wn + nf*16 + fr;
            bg[nf] = *(const half8*)&b_lds[rb*32 + ((kg ^ SWZ(rb)) * 8)];
            int rb2 = 64 + rb;
            bs[nf] = *(const half8*)&b_lds[rb2*32 + ((kg ^ SWZ(rb2)) * 8)];
        }
        #pragma unroll
        for (int mf = 0; mf < 4; ++mf)
            #pragma unroll
            for (int nf = 0; nf < 2; ++nf) {
                accg[mf][nf] = __builtin_amdgcn_mfma_f32_16x16x32_f16(af[mf], bg[nf], accg[mf][nf], 0, 0, 0);
                accs[mf][nf] = __builtin_amdgcn_mfma_f32_16x16x32_f16(af[mf], bs[nf], accs[mf][nf], 0, 0, 0);
            }
        pa0 = na0; pa1 = na1; pb0 = nb0; pb1 = nb1;
    }
    #pragma unroll
    for (int nf = 0; nf < 2; ++nf) {
        int o = o0 + wn + nf*16 + fr;
        float b0v = bias[o], b1v = bias[256 + o];
        #pragma unroll
        for (int mf = 0; mf < 4; ++mf) {
            #pragma unroll
            for (int rg = 0; rg < 4; ++rg) {
                size_t m = (size_t)mbase + wm + mf*16 + kg*4 + rg;
                float g = accg[mf][nf][rg] + b0v;
                float s = accs[mf][nf][rg] + b1v;
                zc[m*256 + o] = g / (1.f + expf(-s));
            }
        }
    }
}

// ---------------- LayerNorm; writes h f32 + hm16 fp16 (non-last), species/outseq (last) ----------------
template<bool SP>
__global__ __launch_bounds__(256) void k_ln2(const float* __restrict__ zc,
        float* __restrict__ h, const float* __restrict__ g, const float* __restrict__ bb,
        _Float16* __restrict__ hm16, const int* __restrict__ xs,
        const float* __restrict__ emb, float* __restrict__ outseq) {
    __shared__ float tl[8992];
    int tid = threadIdx.x;
    int b = blockIdx.y;
    int l0 = blockIdx.x * 32;
    for (int j = tid; j < 32*256; j += 256) {
        int c = j >> 5, l = j & 31;
        tl[LDIDX(l, c)] = h[((size_t)(b*H + c))*L + l0 + l];
    }
    __syncthreads();
    int r = tid >> 3, p = tid & 7;
    float v[32];
    float sum = 0.f, ss = 0.f;
    const float* zrow = &zc[((size_t)(b*L + l0 + r))*256 + p*32];
    #pragma unroll
    for (int q = 0; q < 8; ++q) {
        float4 z4 = *(const float4*)&zrow[q*4];
        float zz[4] = {z4.x, z4.y, z4.z, z4.w};
        #pragma unroll
        for (int i = 0; i < 4; ++i) {
            float hv = tl[LDIDX(r, p*32 + q*4 + i)];
            float vv = zz[i] + hv;
            v[q*4+i] = vv;
            sum += vv; ss = fmaf(vv, vv, ss);
        }
    }
    sum += __shfl_xor(sum, 1); ss += __shfl_xor(ss, 1);
    sum += __shfl_xor(sum, 2); ss += __shfl_xor(ss, 2);
    sum += __shfl_xor(sum, 4); ss += __shfl_xor(ss, 4);
    float mu = sum * (1.f/256.f);
    float var = ss * (1.f/256.f) - mu*mu;
    float rs = rsqrtf(var + 1e-5f);
    int sp = SP ? xs[b] : 0;
    #pragma unroll
    for (int q = 0; q < 32; ++q) {
        int c = p*32 + q;
        float val = (v[q] - mu) * rs * g[c] + bb[c];
        if (SP) val += emb[sp*H + c];
        tl[LDIDX(r, c)] = val;
    }
    __syncthreads();
    for (int j = tid; j < 32*256; j += 256) {
        int c = j >> 5, l = j & 31;
        float val = tl[LDIDX(l, c)];
        h[((size_t)(b*H + c))*L + l0 + l] = val;
        if (SP) outseq[((size_t)(b*H + c))*L + l0 + l] = val;
        else    hm16[((size_t)(b*H + c))*L + l0 + l] = (_Float16)val;
    }
}

// ---------------- MFMA decoder conv K=15 ----------------
__global__ __launch_bounds__(128) void k_dec(const _Float16* __restrict__ ht,
        const _Float16* __restrict__ wdk, const float* __restrict__ bias,
        float* __restrict__ outdec) {
    __shared__ _Float16 a_lds[160*32];
    __shared__ _Float16 b_lds[15*16*32];
    const int tid = threadIdx.x;
    const int mbase = blockIdx.x * 128;
    const int b = mbase >> 11;
    const int lbase = mbase & 2047;
    const int lane = tid & 63;
    const int w = tid >> 6;
    const int fr = lane & 15, kg = lane >> 4;
    const int rs = tid >> 2, q0 = tid & 3;
    f32x4 acc[4];
    #pragma unroll
    for (int i = 0; i < 4; ++i)
        #pragma unroll
        for (int k = 0; k < 4; ++k) acc[i][k] = 0.f;
    for (int cc = 0; cc < 8; ++cc) {
        __syncthreads();
        #pragma unroll
        for (int ps = 0; ps < 5; ++ps) {
            int r = ps*32 + rs;
            if (r < 142) {
                int l = lbase - 7 + r;
                uint4 v = (l >= 0 && l < L) ? *(const uint4*)&ht[((size_t)(b*L + l))*256 + cc*32 + q0*8]
                                            : make_uint4(0,0,0,0);
                *(uint4*)&a_lds[r*32 + ((q0 ^ SWZ(r))*8)] = v;
            }
        }
        for (int jj = tid; jj < 960; jj += 128)
            *(uint4*)&b_lds[jj*8] = *(const uint4*)&wdk[cc*7680 + jj*8];
        __syncthreads();
        #pragma unroll
        for (int k = 0; k < 15; ++k) {
            half8 bfr = *(const half8*)&b_lds[(k*16 + fr)*32 + ((kg ^ SWZ(fr))*8)];
            #pragma unroll
            for (int mf = 0; mf < 4; ++mf) {
                int ra = w*64 + mf*16 + fr + k;
                half8 af = *(const half8*)&a_lds[ra*32 + ((kg ^ SWZ(ra))*8)];
                acc[mf] = __builtin_amdgcn_mfma_f32_16x16x32_f16(af, bfr, acc[mf], 0, 0, 0);
            }
        }
    }
    if (fr < DOUT) {
        float bo = bias[fr];
        #pragma unroll
        for (int mf = 0; mf < 4; ++mf)
            #pragma unroll
            for (int rg = 0; rg < 4; ++rg) {
                int m = mbase + w*64 + mf*16 + kg*4 + rg;
                outdec[((size_t)(b*DOUT + fr))*L + (m & 2047)] = acc[mf][rg] + bo;
            }
    }
}

// ---------------- mean over L ----------------
__global__ __launch_bounds__(256) void k_agg(const float* __restrict__ h, float* __restrict__ agg) {
    __shared__ float red[256];
    int bc = blockIdx.x;
    int tid = threadIdx.x;
    float s = 0.f;
    for (int t = tid; t < L; t += 256) s += h[bc*L + t];
    red[tid] = s; __syncthreads();
    for (int k = 128; k > 0; k >>= 1) {
        if (tid < k) red[tid] += red[tid+k];
        __syncthreads();
    }
    if (tid == 0) agg[bc] = red[0] * (1.f/(float)L);
}

// ---------------- regression MLP ----------------
__global__ __launch_bounds__(128) void k_mlp(const float* __restrict__ agg,
        const float* __restrict__ w1, const float* __restrict__ b1,
        const float* __restrict__ w2, const float* __restrict__ b2,
        const float* __restrict__ w3, const float* __restrict__ b3,
        const float* __restrict__ w4, const float* __restrict__ b4,
        float* __restrict__ outreg) {
    __shared__ float a0[256], r1[128], r2[64], r3[32];
    int b = blockIdx.x, tid = threadIdx.x;
    a0[tid] = agg[b*256 + tid];
    a0[tid+128] = agg[b*256 + tid + 128];
    __syncthreads();
    {
        float s = b1[tid];
        for (int k = 0; k < 256; ++k) s = fmaf(w1[tid*256+k], a0[k], s);
        r1[tid] = s > 0.f ? s : expm1f(s);
    }
    __syncthreads();
    if (tid < 64) {
        float s = b2[tid];
        for (int k = 0; k < 128; ++k) s = fmaf(w2[tid*128+k], r1[k], s);
        r2[tid] = s > 0.f ? s : expm1f(s);
    }
    __syncthreads();
    if (tid < 32) {
        float s = b3[tid];
        for (int k = 0; k < 64; ++k) s = fmaf(w3[tid*64+k], r2[k], s);
        r3[tid] = s > 0.f ? s : expm1f(s);
    }
    __syncthreads();
    if (tid == 0) {
        float s = b4[0];
        for (int k = 0; k < 32; ++k) s = fmaf(w4[k], r3[k], s);
        outreg[b] = s;
    }
}

extern "C" void kernel_launch(void* const* d_in, const int* in_sizes, int n_in,
                              void* d_out, int out_size, void* d_ws, size_t ws_size,
                              hipStream_t stream) {
    const float* x      = (const float*)d_in[0];
    const int*   xs     = (const int*)d_in[1];
    const float* enc_w  = (const float*)d_in[2];
    const float* enc_b  = (const float*)d_in[3];
    const float* res_w1 = (const float*)d_in[4];
    const float* res_b1 = (const float*)d_in[5];
    const float* res_w2 = (const float*)d_in[6];
    const float* res_b2 = (const float*)d_in[7];
    const float* log_dt = (const float*)d_in[8];
    const float* lam_re = (const float*)d_in[9];
    const float* lam_im = (const float*)d_in[10];
    const float* W_re   = (const float*)d_in[11];
    const float* W_im   = (const float*)d_in[12];
    const float* Dv     = (const float*)d_in[13];
    const float* glu_w  = (const float*)d_in[14];
    const float* glu_b  = (const float*)d_in[15];
    const float* ln_g   = (const float*)d_in[16];
    const float* ln_b   = (const float*)d_in[17];
    const float* dec_w  = (const float*)d_in[18];
    const float* dec_b  = (const float*)d_in[19];
    const float* sp_emb = (const float*)d_in[20];
    const float* h1_w = (const float*)d_in[21]; const float* h1_b = (const float*)d_in[22];
    const float* h2_w = (const float*)d_in[23]; const float* h2_b = (const float*)d_in[24];
    const float* h3_w = (const float*)d_in[25]; const float* h3_b = (const float*)d_in[26];
    const float* h4_w = (const float*)d_in[27]; const float* h4_b = (const float*)d_in[28];

    float* ws   = (float*)d_ws;
    float* h    = ws;                                  // LSEQ f32 [b][c][l]
    float* t1   = ws + (size_t)LSEQ;                   // LSEQ f32
    float* t2   = ws + (size_t)2*LSEQ;                 // LSEQ f32
    // res-phase: xb lower / xa upper (so t_cf(xa -> hm16 lower) has no overlap)
    _Float16* xb  = (_Float16*)t1;                     // t1 lower 32MB
    _Float16* xa  = (_Float16*)t1 + (size_t)LSEQ;      // t1 upper 32MB
    _Float16* wpk = (_Float16*)t2;
    // DSS-phase:
    _Float16* hm16 = (_Float16*)t1;                    // fp16 chm h (t1 lower)
    _Float16* yt   = (_Float16*)t1;                    // fp16 chl y (overwrites hm16 after k_dss)
    _Float16* wbig = (_Float16*)t1 + (size_t)LSEQ;     // 16MB (t1 upper)
    _Float16* zp   = wbig + (size_t)H*32768;           // 8MB
    _Float16* y16  = (_Float16*)t2;                    // fp16 chm y (t2 lower)
    float* zcb     = t2;                               // glu out f32 chl (y16 dead)
    // tail:
    float* tail = ws + (size_t)3*LSEQ;
    _Float16* wg  = (_Float16*)tail;
    float4* zwb = (float4*)(tail + 65536);
    float* aggb = tail + 65536 + 32768;
    _Float16* wdk = (_Float16*)(aggb + 8192);
    _Float16* wenc = wdk + 61440;

    float* outdec = (float*)d_out;
    float* outseq = outdec + B*DOUT*L;
    float* outreg = outseq + (size_t)LSEQ;

    // encoder (MFMA, writes fp16 channel-last)
    k_wenc<<<96, 256, 0, stream>>>(enc_w, wenc);
    k_enc<<<dim3(B*L/128, 2), 256, 0, stream>>>(x, wenc, enc_b, xa);

    // residual stack
    k_wpack<<<(NRES*2*3*65536 + 255)/256, 256, 0, stream>>>(res_w1, res_w2, wpk);
    for (int r = 0; r < NRES; ++r) {
        k_cv3<false><<<dim3(2, B*L/128), 256, 0, stream>>>(
            xa, wpk + (size_t)(r*2+0)*3*65536, res_b1 + r*H, nullptr, xb);
        k_cv3<true><<<dim3(2, B*L/128), 256, 0, stream>>>(
            xb, wpk + (size_t)(r*2+1)*3*65536, res_b2 + r*H, xa, xa);
    }
    k_t_cf<<<dim3(L/64, H/64, B), 256, 0, stream>>>(xa, h, hm16);

    // DSS blocks
    for (int i = 0; i < NLAYERS; ++i) {
        k_zw<<<(H*NST + 255)/256, 256, 0, stream>>>(log_dt, lam_re, lam_im, zwb, i);
        k_wzp<<<H, 128, 0, stream>>>(zwb, zp);
        k_wkern<<<H, 128, 0, stream>>>(log_dt, lam_re, lam_im, W_re, W_im, wbig, i);
        k_wtg16<<<(512*256 + 255)/256, 256, 0, stream>>>(glu_w, wg, i);
        k_dss<<<dim3(8, H), 256, 0, stream>>>(hm16, zp, wbig, zwb, Dv, y16, i);
        k_t16<<<dim3(L/64, H/64, B), 256, 0, stream>>>(y16, yt);
        k_glu16<<<dim3(4, B*L/128), 256, 0, stream>>>(yt, wg, glu_b + i*512, zcb);
        if (i < NLAYERS - 1)
            k_ln2<false><<<dim3(L/32, B), 256, 0, stream>>>(zcb, h, ln_g + i*H, ln_b + i*H,
                                                            hm16, nullptr, nullptr, nullptr);
        else
            k_ln2<true><<<dim3(L/32, B), 256, 0, stream>>>(zcb, h, ln_g + i*H, ln_b + i*H,
                                                           hm16, xs, sp_emb, outseq);
    }

    // aggregate + regression head
    k_agg<<<B*H, 256, 0, stream>>>(h, aggb);
    k_mlp<<<B, 128, 0, stream>>>(aggb, h1_w, h1_b, h2_w, h2_b, h3_w, h3_b, h4_w, h4_b, outreg);
    // decoder
    k_t_cl<<<dim3(L/64, H/64, B), 256, 0, stream>>>(h, (_Float16*)t1);
    k_wdec<<<(15*16*256 + 255)/256, 256, 0, stream>>>(dec_w, wdk);
    k_dec<<<B*L/128, 128, 0, stream>>>((_Float16*)t1, wdk, dec_b, outdec);
}

// Round 8
// 1220.924 us; speedup vs baseline: 5.3674x; 1.0804x over previous
//
#include <hip/hip_runtime.h>
#include <math.h>

#define B 32
#define L 2048
#define DIN 5
#define DOUT 5
#define H 256
#define NST 32
#define NLAYERS 4
#define NRES 3
#define CHUNK 128
#define NCH 16            // L / CHUNK
#define LSEQ (B*H*L)      // 16777216

typedef __attribute__((ext_vector_type(8))) _Float16 half8;
typedef __attribute__((ext_vector_type(4))) float f32x4;

__device__ __forceinline__ float gelu_exact(float v) {
    return 0.5f * v * (1.0f + erff(v * 0.7071067811865475f));
}
#define SWZ(r) ((((r) ^ ((r) >> 2)) & 3))
#define LDIDX(l, c) ((l)*281 + ((c)>>5)*35 + ((c)&31))

// ---------------- encoder weight pack ----------------
__global__ void k_wenc(const float* __restrict__ ew, _Float16* __restrict__ wenc) {
    int idx = blockIdx.x*256 + threadIdx.x;
    if (idx >= 256*96) return;
    int o = idx / 96, kk = idx % 96;
    int ci = kk >> 4, k = kk & 15;
    float v = (ci < DIN && k < 15) ? ew[(o*DIN + ci)*15 + k] : 0.f;
    wenc[idx] = (_Float16)v;
}

// ---------------- MFMA encoder conv K=15 Cin=5 ----------------
__global__ __launch_bounds__(256) void k_enc(const float* __restrict__ x,
        const _Float16* __restrict__ wenc, const float* __restrict__ bias,
        _Float16* __restrict__ out) {
    __shared__ _Float16 a_lds[3*128*32];
    __shared__ _Float16 b_lds[3*128*32];
    const int tid = threadIdx.x;
    const int mbase = blockIdx.x * 128;
    const int oh = blockIdx.y;
    const int b = mbase >> 11;
    const int lbase = mbase & 2047;
    const int lane = tid & 63;
    const int w = tid >> 6;
    const int wm = (w >> 1) * 64, wn = (w & 1) * 64;
    const int fr = lane & 15, kg = lane >> 4;

    #pragma unroll
    for (int i = 0; i < 6; ++i) {
        int g = i*256 + tid;
        int r = g / 12, rem = g % 12;
        int ks = rem >> 2, q = rem & 3;
        int kk0 = ks*32 + q*8;
        int ci = kk0 >> 4, k0 = kk0 & 15;
        half8 va;
        #pragma unroll
        for (int e = 0; e < 8; ++e) {
            int k = k0 + e;
            int l = lbase + r - 7 + k;
            float v = (ci < DIN && k < 15 && l >= 0 && l < L)
                        ? x[((size_t)(b*DIN + ci))*L + l] : 0.f;
            va[e] = (_Float16)v;
        }
        *(half8*)&a_lds[ks*4096 + r*32 + ((q ^ SWZ(r))*8)] = va;
        uint4 vb = *(const uint4*)&wenc[(size_t)(oh*128 + r)*96 + kk0];
        *(uint4*)&b_lds[ks*4096 + r*32 + ((q ^ SWZ(r))*8)] = vb;
    }
    __syncthreads();
    f32x4 acc[4][4];
    #pragma unroll
    for (int i = 0; i < 4; ++i)
        #pragma unroll
        for (int j = 0; j < 4; ++j)
            #pragma unroll
            for (int k = 0; k < 4; ++k) acc[i][j][k] = 0.f;
    #pragma unroll
    for (int ks = 0; ks < 3; ++ks) {
        half8 af[4], bfr[4];
        #pragma unroll
        for (int mf = 0; mf < 4; ++mf) {
            int ra = wm + mf*16 + fr;
            af[mf] = *(const half8*)&a_lds[ks*4096 + ra*32 + ((kg ^ SWZ(ra))*8)];
        }
        #pragma unroll
        for (int nf = 0; nf < 4; ++nf) {
            int rb = wn + nf*16 + fr;
            bfr[nf] = *(const half8*)&b_lds[ks*4096 + rb*32 + ((kg ^ SWZ(rb))*8)];
        }
        #pragma unroll
        for (int mf = 0; mf < 4; ++mf)
            #pragma unroll
            for (int nf = 0; nf < 4; ++nf)
                acc[mf][nf] = __builtin_amdgcn_mfma_f32_16x16x32_f16(af[mf], bfr[nf], acc[mf][nf], 0, 0, 0);
    }
    #pragma unroll
    for (int nf = 0; nf < 4; ++nf) {
        int o = oh*128 + wn + nf*16 + fr;
        float bo = bias[o];
        #pragma unroll
        for (int mf = 0; mf < 4; ++mf)
            #pragma unroll
            for (int rg = 0; rg < 4; ++rg) {
                size_t m = (size_t)mbase + wm + mf*16 + kg*4 + rg;
                out[m*256 + o] = (_Float16)(acc[mf][nf][rg] + bo);
            }
    }
}

// ---------------- res weight pack ----------------
__global__ void k_wpack(const float* __restrict__ w1, const float* __restrict__ w2,
                        _Float16* __restrict__ wpk) {
    int idx = blockIdx.x*256 + threadIdx.x;
    if (idx >= NRES*2*3*65536) return;
    int ci = idx & 255;
    int o  = (idx >> 8) & 255;
    int k  = (idx >> 16) % 3;
    int cv = idx / (3*65536);
    const float* src = (cv & 1) ? w2 : w1;
    wpk[idx] = (_Float16)src[(((cv>>1)*H + o)*H + ci)*3 + k];
}

// ---------------- transpose f32 chm -> fp16 chl (decoder prep) ----------------
__global__ __launch_bounds__(256) void k_t_cl(const float* __restrict__ in,
                                              _Float16* __restrict__ out) {
    __shared__ float t[64][65];
    int tid = threadIdx.x;
    int l0 = blockIdx.x*64, c0 = blockIdx.y*64, b = blockIdx.z;
    #pragma unroll
    for (int i = 0; i < 16; ++i) {
        int idx = i*256 + tid;
        int c = idx >> 6, l = idx & 63;
        t[c][l] = in[((size_t)(b*H + c0 + c))*L + l0 + l];
    }
    __syncthreads();
    #pragma unroll
    for (int i = 0; i < 16; ++i) {
        int idx = i*256 + tid;
        int l = idx >> 6, c = idx & 63;
        out[((size_t)b*L + l0 + l)*256 + c0 + c] = (_Float16)t[c][l];
    }
}

// ---------------- transpose fp16 chl -> f32 chm + fp16 chm mirror ----------------
__global__ __launch_bounds__(256) void k_t_cf(const _Float16* __restrict__ in,
        float* __restrict__ out, _Float16* __restrict__ out16) {
    __shared__ float t[64][65];
    int tid = threadIdx.x;
    int l0 = blockIdx.x*64, c0 = blockIdx.y*64, b = blockIdx.z;
    #pragma unroll
    for (int i = 0; i < 16; ++i) {
        int idx = i*256 + tid;
        int l = idx >> 6, c = idx & 63;
        t[c][l] = (float)in[((size_t)b*L + l0 + l)*256 + c0 + c];
    }
    __syncthreads();
    #pragma unroll
    for (int i = 0; i < 16; ++i) {
        int idx = i*256 + tid;
        int c = idx >> 6, l = idx & 63;
        float v = t[c][l];
        out[((size_t)(b*H + c0 + c))*L + l0 + l] = v;
        out16[((size_t)(b*H + c0 + c))*L + l0 + l] = (_Float16)v;
    }
}

// ---------------- transpose fp16 chm -> fp16 chl ----------------
__global__ __launch_bounds__(256) void k_t16(const _Float16* __restrict__ in,
                                             _Float16* __restrict__ out) {
    __shared__ float t[64][65];
    int tid = threadIdx.x;
    int l0 = blockIdx.x*64, c0 = blockIdx.y*64, b = blockIdx.z;
    #pragma unroll
    for (int i = 0; i < 16; ++i) {
        int idx = i*256 + tid;
        int c = idx >> 6, l = idx & 63;
        t[c][l] = (float)in[((size_t)(b*H + c0 + c))*L + l0 + l];
    }
    __syncthreads();
    #pragma unroll
    for (int i = 0; i < 16; ++i) {
        int idx = i*256 + tid;
        int l = idx >> 6, c = idx & 63;
        out[((size_t)b*L + l0 + l)*256 + c0 + c] = (_Float16)t[c][l];
    }
}

// ---------------- MFMA residual conv K=3 v2: full-N tile 128m x 256o, coalesced epilogue ----------------
template<bool RESID>
__global__ __launch_bounds__(256, 2) void k_cv3(const _Float16* __restrict__ xin,
        const _Float16* __restrict__ wpk, const float* __restrict__ bias,
        const _Float16* __restrict__ resid, _Float16* __restrict__ out) {
    __shared__ _Float16 a_lds[128*32];   // 8KB
    __shared__ _Float16 b_lds[256*32];   // 16KB
    __shared__ float    ep[32*256];      // 32KB epilogue slab
    const int tid = threadIdx.x;
    const int mbase = blockIdx.x * 128;
    const int lane = tid & 63;
    const int w = tid >> 6;
    const int wm = (w >> 1) * 64, wo = (w & 1) * 128;
    const int fr = lane & 15, kg = lane >> 4;

    const int r0s = tid >> 2, q0 = tid & 3;
    const int sq = SWZ(r0s);   // SWZ(u*64 + r0s) == SWZ(r0s)
    const int awA0 = r0s*32 + ((q0 ^ sq) * 8);
    const int awA1 = (64 + r0s)*32 + ((q0 ^ SWZ(64 + r0s)) * 8);

    f32x4 acc[4][8];
    #pragma unroll
    for (int i = 0; i < 4; ++i)
        #pragma unroll
        for (int j = 0; j < 8; ++j)
            #pragma unroll
            for (int k = 0; k < 4; ++k) acc[i][j][k] = 0.f;

    uint4 pa0, pa1, pb[4];
    auto loadstep = [&](int kk, uint4& a0, uint4& a1, uint4 (&bb)[4]) {
        const int koff = kk >> 3, cic = kk & 7;
        const int cb = cic*32 + q0*8;
        {
            int m = mbase + r0s;
            int ll = (m & (L-1)) + koff - 1;
            a0 = (ll >= 0 && ll < L) ? *(const uint4*)&xin[((size_t)(m + koff - 1))*256 + cb]
                                     : make_uint4(0,0,0,0);
            int m1 = mbase + 64 + r0s;
            int l1 = (m1 & (L-1)) + koff - 1;
            a1 = (l1 >= 0 && l1 < L) ? *(const uint4*)&xin[((size_t)(m1 + koff - 1))*256 + cb]
                                     : make_uint4(0,0,0,0);
        }
        #pragma unroll
        for (int u = 0; u < 4; ++u)
            bb[u] = *(const uint4*)&wpk[((size_t)(koff*256 + u*64 + r0s))*256 + cb];
    };
    loadstep(0, pa0, pa1, pb);
    for (int kk = 0; kk < 24; ++kk) {
        __syncthreads();
        *(uint4*)&a_lds[awA0] = pa0;
        *(uint4*)&a_lds[awA1] = pa1;
        #pragma unroll
        for (int u = 0; u < 4; ++u)
            *(uint4*)&b_lds[(u*64 + r0s)*32 + ((q0 ^ sq)*8)] = pb[u];
        uint4 na0 = make_uint4(0,0,0,0), na1 = na0, nb[4] = {na0, na0, na0, na0};
        if (kk < 23) loadstep(kk+1, na0, na1, nb);
        __syncthreads();
        half8 af[4];
        #pragma unroll
        for (int mf = 0; mf < 4; ++mf) {
            int ra = wm + mf*16 + fr;
            af[mf] = *(const half8*)&a_lds[ra*32 + ((kg ^ SWZ(ra)) * 8)];
        }
        #pragma unroll
        for (int nf = 0; nf < 8; ++nf) {
            int rb = wo + nf*16 + fr;
            half8 bfr = *(const half8*)&b_lds[rb*32 + ((kg ^ SWZ(rb)) * 8)];
            #pragma unroll
            for (int mf = 0; mf < 4; ++mf)
                acc[mf][nf] = __builtin_amdgcn_mfma_f32_16x16x32_f16(af[mf], bfr, acc[mf][nf], 0, 0, 0);
        }
        pa0 = na0; pa1 = na1;
        #pragma unroll
        for (int u = 0; u < 4; ++u) pb[u] = nb[u];
    }
    // epilogue: per-mf slab through LDS, coalesced fp16 stores with resid+relu
    float bo8[8];
    #pragma unroll
    for (int nf = 0; nf < 8; ++nf) bo8[nf] = bias[wo + nf*16 + fr];
    const int er = tid >> 3, eoc = (tid & 7) * 32;
    #pragma unroll
    for (int mf = 0; mf < 4; ++mf) {
        __syncthreads();
        #pragma unroll
        for (int nf = 0; nf < 8; ++nf) {
            int o = wo + nf*16 + fr;
            int srb = (w >> 1)*16 + kg*4;
            #pragma unroll
            for (int rg = 0; rg < 4; ++rg)
                ep[(srb + rg)*256 + o] = acc[mf][nf][rg] + bo8[nf];
        }
        __syncthreads();
        size_t m = (size_t)mbase + mf*16 + (er < 16 ? er : 48 + er);
        #pragma unroll
        for (int u = 0; u < 4; ++u) {
            float4 v0 = *(float4*)&ep[er*256 + eoc + u*8];
            float4 v1 = *(float4*)&ep[er*256 + eoc + u*8 + 4];
            float vv[8] = {v0.x, v0.y, v0.z, v0.w, v1.x, v1.y, v1.z, v1.w};
            if (RESID) {
                half8 rv = *(const half8*)&resid[m*256 + eoc + u*8];
                #pragma unroll
                for (int e = 0; e < 8; ++e) vv[e] += (float)rv[e];
            }
            half8 hv;
            #pragma unroll
            for (int e = 0; e < 8; ++e) hv[e] = (_Float16)fmaxf(vv[e], 0.f);
            *(half8*)&out[m*256 + eoc + u*8] = hv;
        }
    }
}

// ---------------- DSS: per-(h,n) pole z and z^CHUNK ----------------
__global__ void k_zw(const float* __restrict__ log_dt, const float* __restrict__ lam_re,
                     const float* __restrict__ lam_im, float4* __restrict__ zwbuf, int layer) {
    int idx = blockIdx.x*256 + threadIdx.x;
    if (idx >= H*NST) return;
    int hh = idx / NST, n = idx % NST;
    float dt = expf(log_dt[layer*H + hh]);
    float a  = dt * lam_re[layer*NST + n];
    float bi = dt * lam_im[layer*NST + n];
    float er = expf(a);
    float zre = er * cosf(bi), zim = er * sinf(bi);
    float eC = expf(a * (float)CHUNK);
    float bC = bi * (float)CHUNK;
    float zcre = eC * cosf(bC), zcim = eC * sinf(bC);
    zwbuf[idx] = make_float4(zre, zim, zcre, zcim);
}

// ---------------- Z-power matrix zp[h][t][j] fp16 (t = dn*2+c) ----------------
__global__ __launch_bounds__(128) void k_wzp(const float4* __restrict__ zw,
        _Float16* __restrict__ zp) {
    int hh = blockIdx.x;
    int t = threadIdx.x;
    int dn = t >> 1, c = t & 1, dir = dn >> 5, n = dn & 31;
    float4 z4 = zw[hh*NST + n];
    float zre = z4.x, zim = z4.y;
    _Float16* dst = &zp[(size_t)hh*16384 + t*128];
    float cr = 1.f, ci = 0.f;
    for (int p = 0; p < 128; ++p) {
        float val = c ? ci : cr;
        dst[dir ? p : (127 - p)] = (_Float16)val;
        float nr = cr*zre - ci*zim;
        float ni = cr*zim + ci*zre;
        cr = nr; ci = ni;
    }
}

// ---------------- W_big[h][t][256] fp16 ----------------
__global__ __launch_bounds__(128) void k_wkern(const float* __restrict__ log_dt,
        const float* __restrict__ lam_re, const float* __restrict__ lam_im,
        const float* __restrict__ W_re, const float* __restrict__ W_im,
        _Float16* __restrict__ wbig, int layer) {
    __shared__ float kf[128], kb[128];
    __shared__ float E[128*129];
    const int hh = blockIdx.x;
    const int t = threadIdx.x;
    float dt = expf(log_dt[layer*H + hh]);
    float skf = 0.f, skb = 0.f;
    for (int n = 0; n < 32; ++n) {
        float a  = dt * lam_re[layer*NST + n];
        float bi = dt * lam_im[layer*NST + n];
        float wfr = W_re[((layer*2+0)*H + hh)*NST + n];
        float wfi = W_im[((layer*2+0)*H + hh)*NST + n];
        float wbr = W_re[((layer*2+1)*H + hh)*NST + n];
        float wbi = W_im[((layer*2+1)*H + hh)*NST + n];
        float e0 = expf(a*t), s0, c0; sincosf(bi*t, &s0, &c0);
        float zr0 = e0*c0, zi0 = e0*s0;
        skf = fmaf(wfr, zr0, skf) - wfi*zi0;
        skb = fmaf(wbr, zr0, skb) - wbi*zi0;
        float e1 = expf(a*(t+1)), s1, c1; sincosf(bi*(t+1), &s1, &c1);
        float zr1 = e1*c1, zi1 = e1*s1;
        E[t*129 + n]      = wfr*zr1 - wfi*zi1;
        E[t*129 + 32 + n] = -(wfr*zi1 + wfi*zr1);
        float e2 = expf(a*(127-t)), s2, c2; sincosf(bi*(127-t), &s2, &c2);
        float zr2 = e2*c2, zi2 = e2*s2;
        E[t*129 + 64 + n] = wbr*zr2 - wbi*zi2;
        E[t*129 + 96 + n] = -(wbr*zi2 + wbi*zr2);
    }
    kf[t] = skf; kb[t] = skb;
    __syncthreads();
    _Float16* dst = &wbig[(size_t)hh*32768];
    for (int idx = t; idx < 128*256; idx += 128) {
        int tt = idx >> 8, k = idx & 255;
        float v;
        if (k < 128) v = (k <= tt) ? kf[tt - k] : kb[k - tt - 1];
        else         v = E[tt*129 + (k - 128)];
        dst[idx] = (_Float16)v;
    }
}

// ---------------- GLU weight pack ----------------
__global__ void k_wtg16(const float* __restrict__ gw, _Float16* __restrict__ wg, int layer) {
    int idx = blockIdx.x*256 + threadIdx.x;
    if (idx >= 512*256) return;
    wg[idx] = (_Float16)gw[layer*512*256 + idx];
}

// ---------------- decoder weight pack ----------------
__global__ void k_wdec(const float* __restrict__ dw, _Float16* __restrict__ wdk) {
    int idx = blockIdx.x*256 + threadIdx.x;
    if (idx >= 15*16*256) return;
    int cfull = idx & 255;
    int o = (idx >> 8) & 15;
    int k = idx >> 12;
    float v = (o < DOUT) ? dw[(o*H + cfull)*15 + k] : 0.f;
    int cc = cfull >> 5, cl = cfull & 31;
    int cq = cl >> 3, cb = cl & 7;
    wdk[cc*7680 + (k*16 + o)*32 + ((cq ^ SWZ(o))*8) + cb] = (_Float16)v;
}

// ---------------- FUSED DSS with coalesced y16 epilogue ----------------
__global__ __launch_bounds__(256) void k_dss(const _Float16* __restrict__ hm16,
        const _Float16* __restrict__ zp, const _Float16* __restrict__ wbig,
        const float4* __restrict__ zwb, const float* __restrict__ Dv,
        _Float16* __restrict__ y16, int layer) {
    __shared__ _Float16 xbuf[4*64*32];    // 16KB
    __shared__ _Float16 bbuf[2*128*32];   // 16KB: zp dbuf -> stp -> y16 stage
    __shared__ float    sbuf[64*128];     // 32KB
    _Float16* sb16 = (_Float16*)sbuf;

    const int tid = threadIdx.x;
    const int b0 = blockIdx.x * 4;
    const int hh = blockIdx.y;
    const int lane = tid & 63;
    const int w = tid >> 6;
    const int wn = w * 32;
    const int fr = lane & 15, kg = lane >> 4;

    #pragma unroll
    for (int i = 0; i < 4; ++i) {
        int g = i*256 + tid;
        int m = g >> 4, gi = g & 15;
        int kc = gi >> 2, q = gi & 3;
        uint4 v = *(const uint4*)&hm16[((size_t)((b0 + (m>>4))*H + hh))*L
                                       + (m&15)*128 + kc*32 + q*8];
        *(uint4*)&xbuf[kc*2048 + m*32 + ((q ^ SWZ(m))*8)] = v;
    }

    // ---- phase 1: S = x . zp^T ----
    f32x4 acc1[4][2];
    #pragma unroll
    for (int i = 0; i < 4; ++i)
        #pragma unroll
        for (int j = 0; j < 2; ++j)
            #pragma unroll
            for (int k = 0; k < 4; ++k) acc1[i][j][k] = 0.f;
    const _Float16* zb = &zp[(size_t)hh*16384];
    const int gr0 = tid >> 2, gq0 = tid & 3;
    const int gr1 = 64 + gr0;
    uint4 pb0 = *(const uint4*)&zb[gr0*128 + gq0*8];
    uint4 pb1 = *(const uint4*)&zb[gr1*128 + gq0*8];
    for (int kc = 0; kc < 4; ++kc) {
        __syncthreads();
        *(uint4*)&bbuf[(kc&1)*4096 + gr0*32 + ((gq0 ^ SWZ(gr0))*8)] = pb0;
        *(uint4*)&bbuf[(kc&1)*4096 + gr1*32 + ((gq0 ^ SWZ(gr1))*8)] = pb1;
        if (kc < 3) {
            pb0 = *(const uint4*)&zb[gr0*128 + (kc+1)*32 + gq0*8];
            pb1 = *(const uint4*)&zb[gr1*128 + (kc+1)*32 + gq0*8];
        }
        __syncthreads();
        half8 af[4], bf2[2];
        #pragma unroll
        for (int mf = 0; mf < 4; ++mf) {
            int ra = mf*16 + fr;
            af[mf] = *(const half8*)&xbuf[kc*2048 + ra*32 + ((kg ^ SWZ(ra))*8)];
        }
        #pragma unroll
        for (int nf = 0; nf < 2; ++nf) {
            int rb = wn + nf*16 + fr;
            bf2[nf] = *(const half8*)&bbuf[(kc&1)*4096 + rb*32 + ((kg ^ SWZ(rb))*8)];
        }
        #pragma unroll
        for (int mf = 0; mf < 4; ++mf)
            #pragma unroll
            for (int nf = 0; nf < 2; ++nf)
                acc1[mf][nf] = __builtin_amdgcn_mfma_f32_16x16x32_f16(af[mf], bf2[nf], acc1[mf][nf], 0, 0, 0);
    }
    #pragma unroll
    for (int mf = 0; mf < 4; ++mf)
        #pragma unroll
        for (int nf = 0; nf < 2; ++nf)
            #pragma unroll
            for (int rg = 0; rg < 4; ++rg)
                sbuf[(mf*16 + kg*4 + rg)*128 + wn + nf*16 + fr] = acc1[mf][nf][rg];
    __syncthreads();

    // ---- phase 2: in-LDS cross-chunk scan (f32) -> stp fp16 in bbuf ----
    {
        int b_loc = tid >> 6, dn = tid & 63;
        int dir = dn >> 5, n = dn & 31;
        float4 z4 = zwb[hh*NST + n];
        float zcre = z4.z, zcim = z4.w;
        int q1 = n >> 3, e1 = n & 7;
        float pre = 0.f, pim = 0.f;
        for (int s = 0; s < NCH; ++s) {
            int ch = dir ? (NCH - 1 - s) : s;
            int m = b_loc*16 + ch;
            bbuf[(dir*2 + 0)*2048 + m*32 + ((q1 ^ SWZ(m))*8) + e1] = (_Float16)pre;
            bbuf[(dir*2 + 1)*2048 + m*32 + ((q1 ^ SWZ(m))*8) + e1] = (_Float16)pim;
            float cre = sbuf[m*128 + dn*2];
            float cim = sbuf[m*128 + dn*2 + 1];
            float nre = fmaf(zcre, pre, fmaf(-zcim, pim, cre));
            float nim = fmaf(zcre, pim, fmaf(zcim, pre, cim));
            pre = nre; pim = nim;
        }
    }
    __syncthreads();

    // ---- phase 3: y = [x | stp] . wbig^T ----
    f32x4 acc3[4][2];
    #pragma unroll
    for (int i = 0; i < 4; ++i)
        #pragma unroll
        for (int j = 0; j < 2; ++j)
            #pragma unroll
            for (int k = 0; k < 4; ++k) acc3[i][j][k] = 0.f;
    const _Float16* wb = &wbig[(size_t)hh*32768];
    pb0 = *(const uint4*)&wb[gr0*256 + gq0*8];
    pb1 = *(const uint4*)&wb[gr1*256 + gq0*8];
    for (int kc = 0; kc < 8; ++kc) {
        __syncthreads();
        *(uint4*)&sb16[(kc&1)*4096 + gr0*32 + ((gq0 ^ SWZ(gr0))*8)] = pb0;
        *(uint4*)&sb16[(kc&1)*4096 + gr1*32 + ((gq0 ^ SWZ(gr1))*8)] = pb1;
        if (kc < 7) {
            pb0 = *(const uint4*)&wb[gr0*256 + (kc+1)*32 + gq0*8];
            pb1 = *(const uint4*)&wb[gr1*256 + (kc+1)*32 + gq0*8];
        }
        __syncthreads();
        half8 af[4], bf2[2];
        #pragma unroll
        for (int mf = 0; mf < 4; ++mf) {
            int ra = mf*16 + fr;
            af[mf] = (kc < 4)
                ? *(const half8*)&xbuf[kc*2048 + ra*32 + ((kg ^ SWZ(ra))*8)]
                : *(const half8*)&bbuf[(kc-4)*2048 + ra*32 + ((kg ^ SWZ(ra))*8)];
        }
        #pragma unroll
        for (int nf = 0; nf < 2; ++nf) {
            int rb = wn + nf*16 + fr;
            bf2[nf] = *(const half8*)&sb16[(kc&1)*4096 + rb*32 + ((kg ^ SWZ(rb))*8)];
        }
        #pragma unroll
        for (int mf = 0; mf < 4; ++mf)
            #pragma unroll
            for (int nf = 0; nf < 2; ++nf)
                acc3[mf][nf] = __builtin_amdgcn_mfma_f32_16x16x32_f16(af[mf], bf2[nf], acc3[mf][nf], 0, 0, 0);
    }
    // epilogue: D*x + gelu, stage fp16 tile in bbuf, coalesced stores
    __syncthreads();                       // all waves done reading bbuf (stp)
    float dv = Dv[layer*H + hh];
    _Float16* yst = bbuf;                  // 64 x 128 fp16 = 16KB
    #pragma unroll
    for (int mf = 0; mf < 4; ++mf) {
        #pragma unroll
        for (int rg = 0; rg < 4; ++rg) {
            int m = mf*16 + kg*4 + rg;
            #pragma unroll
            for (int nf = 0; nf < 2; ++nf) {
                int t = wn + nf*16 + fr;
                float xv = (float)xbuf[(t>>5)*2048 + m*32 + ((((t&31)>>3) ^ SWZ(m))*8) + (t&7)];
                float v = acc3[mf][nf][rg] + dv * xv;
                yst[m*128 + t] = (_Float16)gelu_exact(v);
            }
        }
    }
    __syncthreads();
    {
        int r = tid >> 2, tc = (tid & 3) * 32;
        size_t gb = ((size_t)((b0 + (r>>4))*H + hh))*L + (r&15)*128;
        #pragma unroll
        for (int u = 0; u < 4; ++u)
            *(half8*)&y16[gb + tc + u*8] = *(half8*)&yst[r*128 + tc + u*8];
    }
}

// ---------------- GLU MFMA fp16 -> fp16 zc, coalesced epilogue; grid (4, B*L/128) ----------------
__global__ __launch_bounds__(256) void k_glu16(const _Float16* __restrict__ yt,
        const _Float16* __restrict__ wg, const float* __restrict__ bias,
        _Float16* __restrict__ zc) {
    __shared__ _Float16 a_lds[128*32];
    __shared__ _Float16 b_lds[128*32];
    __shared__ float    ep[32*64];       // 8KB epilogue slab
    const int tid = threadIdx.x;
    const int mbase = blockIdx.y * 128;
    const int o0 = blockIdx.x * 64;
    const int lane = tid & 63;
    const int w = tid >> 6;
    const int wm = (w >> 1) * 64, wn = (w & 1) * 32;
    const int fr = lane & 15, kg = lane >> 4;
    const int r0s = tid >> 2, q0 = tid & 3;
    const int r1s = 64 + r0s;
    const int aw0 = r0s*32 + ((q0 ^ SWZ(r0s)) * 8);
    const int aw1 = r1s*32 + ((q0 ^ SWZ(r1s)) * 8);
    const int og0 = o0 + r0s;
    const int og1 = 256 + o0 + r0s;

    f32x4 accg[4][2], accs[4][2];
    #pragma unroll
    for (int i = 0; i < 4; ++i)
        #pragma unroll
        for (int j = 0; j < 2; ++j)
            #pragma unroll
            for (int k = 0; k < 4; ++k) { accg[i][j][k] = 0.f; accs[i][j][k] = 0.f; }

    uint4 pa0, pa1, pb0, pb1;
    auto loadstep = [&](int kc, uint4& a0, uint4& a1, uint4& b0, uint4& b1) {
        const int cb = kc*32 + q0*8;
        a0 = *(const uint4*)&yt[((size_t)(mbase + r0s))*256 + cb];
        a1 = *(const uint4*)&yt[((size_t)(mbase + r1s))*256 + cb];
        b0 = *(const uint4*)&wg[((size_t)og0)*256 + cb];
        b1 = *(const uint4*)&wg[((size_t)og1)*256 + cb];
    };
    loadstep(0, pa0, pa1, pb0, pb1);
    for (int kc = 0; kc < 8; ++kc) {
        __syncthreads();
        *(uint4*)&a_lds[aw0] = pa0;
        *(uint4*)&a_lds[aw1] = pa1;
        *(uint4*)&b_lds[aw0] = pb0;
        *(uint4*)&b_lds[aw1] = pb1;
        uint4 na0 = make_uint4(0,0,0,0), na1 = na0, nb0 = na0, nb1 = na0;
        if (kc < 7) loadstep(kc+1, na0, na1, nb0, nb1);
        __syncthreads();
        half8 af[4], bg[2], bs[2];
        #pragma unroll
        for (int mf = 0; mf < 4; ++mf) {
            int ra = wm + mf*16 + fr;
            af[mf] = *(const half8*)&a_lds[ra*32 + ((kg ^ SWZ(ra)) * 8)];
        }
        #pragma unroll
        for (int nf = 0; nf < 2; ++nf) {
            int rb = wn + nf*16 + fr;
            bg[nf] = *(const half8*)&b_lds[rb*32 + ((kg ^ SWZ(rb)) * 8)];
            int rb2 = 64 + rb;
            bs[nf] = *(const half8*)&b_lds[rb2*32 + ((kg ^ SWZ(rb2)) * 8)];
        }
        #pragma unroll
        for (int mf = 0; mf < 4; ++mf)
            #pragma unroll
            for (int nf = 0; nf < 2; ++nf) {
                accg[mf][nf] = __builtin_amdgcn_mfma_f32_16x16x32_f16(af[mf], bg[nf], accg[mf][nf], 0, 0, 0);
                accs[mf][nf] = __builtin_amdgcn_mfma_f32_16x16x32_f16(af[mf], bs[nf], accs[mf][nf], 0, 0, 0);
            }
        pa0 = na0; pa1 = na1; pb0 = nb0; pb1 = nb1;
    }
    // epilogue: sigmoid-gate in-reg, LDS slab, coalesced fp16 stores
    float b0v[2], b1v[2];
    #pragma unroll
    for (int nf = 0; nf < 2; ++nf) {
        int o = o0 + wn + nf*16 + fr;
        b0v[nf] = bias[o]; b1v[nf] = bias[256 + o];
    }
    const int er = tid >> 3, eoc = (tid & 7) * 8;
    #pragma unroll
    for (int mf = 0; mf < 4; ++mf) {
        __syncthreads();
        #pragma unroll
        for (int nf = 0; nf < 2; ++nf) {
            int ol = wn + nf*16 + fr;
            int srb = (w >> 1)*16 + kg*4;
            #pragma unroll
            for (int rg = 0; rg < 4; ++rg) {
                float g = accg[mf][nf][rg] + b0v[nf];
                float s = accs[mf][nf][rg] + b1v[nf];
                ep[(srb + rg)*64 + ol] = g / (1.f + expf(-s));
            }
        }
        __syncthreads();
        size_t m = (size_t)mbase + mf*16 + (er < 16 ? er : 48 + er);
        float4 v0 = *(float4*)&ep[er*64 + eoc];
        float4 v1 = *(float4*)&ep[er*64 + eoc + 4];
        half8 hv;
        hv[0]=(_Float16)v0.x; hv[1]=(_Float16)v0.y; hv[2]=(_Float16)v0.z; hv[3]=(_Float16)v0.w;
        hv[4]=(_Float16)v1.x; hv[5]=(_Float16)v1.y; hv[6]=(_Float16)v1.z; hv[7]=(_Float16)v1.w;
        *(half8*)&zc[m*256 + o0 + eoc] = hv;
    }
}

// ---------------- LayerNorm (zc fp16); writes h f32 + hm16 (non-last) / species+outseq (last) ----------------
template<bool SP>
__global__ __launch_bounds__(256) void k_ln2(const _Float16* __restrict__ zc,
        float* __restrict__ h, const float* __restrict__ g, const float* __restrict__ bb,
        _Float16* __restrict__ hm16, const int* __restrict__ xs,
        const float* __restrict__ emb, float* __restrict__ outseq) {
    __shared__ float tl[8992];
    int tid = threadIdx.x;
    int b = blockIdx.y;
    int l0 = blockIdx.x * 32;
    for (int j = tid; j < 32*256; j += 256) {
        int c = j >> 5, l = j & 31;
        tl[LDIDX(l, c)] = h[((size_t)(b*H + c))*L + l0 + l];
    }
    __syncthreads();
    int r = tid >> 3, p = tid & 7;
    float v[32];
    float sum = 0.f, ss = 0.f;
    const _Float16* zrow = &zc[((size_t)(b*L + l0 + r))*256 + p*32];
    #pragma unroll
    for (int q = 0; q < 4; ++q) {
        half8 z8 = *(const half8*)&zrow[q*8];
        #pragma unroll
        for (int i = 0; i < 8; ++i) {
            float hv = tl[LDIDX(r, p*32 + q*8 + i)];
            float vv = (float)z8[i] + hv;
            v[q*8+i] = vv;
            sum += vv; ss = fmaf(vv, vv, ss);
        }
    }
    sum += __shfl_xor(sum, 1); ss += __shfl_xor(ss, 1);
    sum += __shfl_xor(sum, 2); ss += __shfl_xor(ss, 2);
    sum += __shfl_xor(sum, 4); ss += __shfl_xor(ss, 4);
    float mu = sum * (1.f/256.f);
    float var = ss * (1.f/256.f) - mu*mu;
    float rs = rsqrtf(var + 1e-5f);
    int sp = SP ? xs[b] : 0;
    #pragma unroll
    for (int q = 0; q < 32; ++q) {
        int c = p*32 + q;
        float val = (v[q] - mu) * rs * g[c] + bb[c];
        if (SP) val += emb[sp*H + c];
        tl[LDIDX(r, c)] = val;
    }
    __syncthreads();
    for (int j = tid; j < 32*256; j += 256) {
        int c = j >> 5, l = j & 31;
        float val = tl[LDIDX(l, c)];
        h[((size_t)(b*H + c))*L + l0 + l] = val;
        if (SP) outseq[((size_t)(b*H + c))*L + l0 + l] = val;
        else    hm16[((size_t)(b*H + c))*L + l0 + l] = (_Float16)val;
    }
}

// ---------------- MFMA decoder conv K=15 ----------------
__global__ __launch_bounds__(128) void k_dec(const _Float16* __restrict__ ht,
        const _Float16* __restrict__ wdk, const float* __restrict__ bias,
        float* __restrict__ outdec) {
    __shared__ _Float16 a_lds[160*32];
    __shared__ _Float16 b_lds[15*16*32];
    const int tid = threadIdx.x;
    const int mbase = blockIdx.x * 128;
    const int b = mbase >> 11;
    const int lbase = mbase & 2047;
    const int lane = tid & 63;
    const int w = tid >> 6;
    const int fr = lane & 15, kg = lane >> 4;
    const int rs = tid >> 2, q0 = tid & 3;
    f32x4 acc[4];
    #pragma unroll
    for (int i = 0; i < 4; ++i)
        #pragma unroll
        for (int k = 0; k < 4; ++k) acc[i][k] = 0.f;
    for (int cc = 0; cc < 8; ++cc) {
        __syncthreads();
        #pragma unroll
        for (int ps = 0; ps < 5; ++ps) {
            int r = ps*32 + rs;
            if (r < 142) {
                int l = lbase - 7 + r;
                uint4 v = (l >= 0 && l < L) ? *(const uint4*)&ht[((size_t)(b*L + l))*256 + cc*32 + q0*8]
                                            : make_uint4(0,0,0,0);
                *(uint4*)&a_lds[r*32 + ((q0 ^ SWZ(r))*8)] = v;
            }
        }
        for (int jj = tid; jj < 960; jj += 128)
            *(uint4*)&b_lds[jj*8] = *(const uint4*)&wdk[cc*7680 + jj*8];
        __syncthreads();
        #pragma unroll
        for (int k = 0; k < 15; ++k) {
            half8 bfr = *(const half8*)&b_lds[(k*16 + fr)*32 + ((kg ^ SWZ(fr))*8)];
            #pragma unroll
            for (int mf = 0; mf < 4; ++mf) {
                int ra = w*64 + mf*16 + fr + k;
                half8 af = *(const half8*)&a_lds[ra*32 + ((kg ^ SWZ(ra))*8)];
                acc[mf] = __builtin_amdgcn_mfma_f32_16x16x32_f16(af, bfr, acc[mf], 0, 0, 0);
            }
        }
    }
    if (fr < DOUT) {
        float bo = bias[fr];
        #pragma unroll
        for (int mf = 0; mf < 4; ++mf)
            #pragma unroll
            for (int rg = 0; rg < 4; ++rg) {
                int m = mbase + w*64 + mf*16 + kg*4 + rg;
                outdec[((size_t)(b*DOUT + fr))*L + (m & 2047)] = acc[mf][rg] + bo;
            }
    }
}

// ---------------- mean over L ----------------
__global__ __launch_bounds__(256) void k_agg(const float* __restrict__ h, float* __restrict__ agg) {
    __shared__ float red[256];
    int bc = blockIdx.x;
    int tid = threadIdx.x;
    float s = 0.f;
    for (int t = tid; t < L; t += 256) s += h[bc*L + t];
    red[tid] = s; __syncthreads();
    for (int k = 128; k > 0; k >>= 1) {
        if (tid < k) red[tid] += red[tid+k];
        __syncthreads();
    }
    if (tid == 0) agg[bc] = red[0] * (1.f/(float)L);
}

// ---------------- regression MLP ----------------
__global__ __launch_bounds__(128) void k_mlp(const float* __restrict__ agg,
        const float* __restrict__ w1, const float* __restrict__ b1,
        const float* __restrict__ w2, const float* __restrict__ b2,
        const float* __restrict__ w3, const float* __restrict__ b3,
        const float* __restrict__ w4, const float* __restrict__ b4,
        float* __restrict__ outreg) {
    __shared__ float a0[256], r1[128], r2[64], r3[32];
    int b = blockIdx.x, tid = threadIdx.x;
    a0[tid] = agg[b*256 + tid];
    a0[tid+128] = agg[b*256 + tid + 128];
    __syncthreads();
    {
        float s = b1[tid];
        for (int k = 0; k < 256; ++k) s = fmaf(w1[tid*256+k], a0[k], s);
        r1[tid] = s > 0.f ? s : expm1f(s);
    }
    __syncthreads();
    if (tid < 64) {
        float s = b2[tid];
        for (int k = 0; k < 128; ++k) s = fmaf(w2[tid*128+k], r1[k], s);
        r2[tid] = s > 0.f ? s : expm1f(s);
    }
    __syncthreads();
    if (tid < 32) {
        float s = b3[tid];
        for (int k = 0; k < 64; ++k) s = fmaf(w3[tid*64+k], r2[k], s);
        r3[tid] = s > 0.f ? s : expm1f(s);
    }
    __syncthreads();
    if (tid == 0) {
        float s = b4[0];
        for (int k = 0; k < 32; ++k) s = fmaf(w4[k], r3[k], s);
        outreg[b] = s;
    }
}

extern "C" void kernel_launch(void* const* d_in, const int* in_sizes, int n_in,
                              void* d_out, int out_size, void* d_ws, size_t ws_size,
                              hipStream_t stream) {
    const float* x      = (const float*)d_in[0];
    const int*   xs     = (const int*)d_in[1];
    const float* enc_w  = (const float*)d_in[2];
    const float* enc_b  = (const float*)d_in[3];
    const float* res_w1 = (const float*)d_in[4];
    const float* res_b1 = (const float*)d_in[5];
    const float* res_w2 = (const float*)d_in[6];
    const float* res_b2 = (const float*)d_in[7];
    const float* log_dt = (const float*)d_in[8];
    const float* lam_re = (const float*)d_in[9];
    const float* lam_im = (const float*)d_in[10];
    const float* W_re   = (const float*)d_in[11];
    const float* W_im   = (const float*)d_in[12];
    const float* Dv     = (const float*)d_in[13];
    const float* glu_w  = (const float*)d_in[14];
    const float* glu_b  = (const float*)d_in[15];
    const float* ln_g   = (const float*)d_in[16];
    const float* ln_b   = (const float*)d_in[17];
    const float* dec_w  = (const float*)d_in[18];
    const float* dec_b  = (const float*)d_in[19];
    const float* sp_emb = (const float*)d_in[20];
    const float* h1_w = (const float*)d_in[21]; const float* h1_b = (const float*)d_in[22];
    const float* h2_w = (const float*)d_in[23]; const float* h2_b = (const float*)d_in[24];
    const float* h3_w = (const float*)d_in[25]; const float* h3_b = (const float*)d_in[26];
    const float* h4_w = (const float*)d_in[27]; const float* h4_b = (const float*)d_in[28];

    float* ws   = (float*)d_ws;
    float* h    = ws;                                  // LSEQ f32 [b][c][l]
    float* t1   = ws + (size_t)LSEQ;                   // LSEQ f32
    float* t2   = ws + (size_t)2*LSEQ;                 // LSEQ f32
    // res-phase: xb lower / xa upper
    _Float16* xb  = (_Float16*)t1;
    _Float16* xa  = (_Float16*)t1 + (size_t)LSEQ;
    _Float16* wpk = (_Float16*)t2;
    // DSS-phase:
    _Float16* hm16 = (_Float16*)t1;                    // fp16 chm h (t1 lower)
    _Float16* yt   = (_Float16*)t1;                    // fp16 chl y (overwrites hm16 after k_dss)
    _Float16* wbig = (_Float16*)t1 + (size_t)LSEQ;     // 16MB (t1 upper)
    _Float16* zp   = wbig + (size_t)H*32768;           // 8MB
    _Float16* y16  = (_Float16*)t2;                    // fp16 chm y (t2 lower)
    _Float16* zc16 = (_Float16*)t2;                    // glu out fp16 chl (y16 dead)
    // tail:
    float* tail = ws + (size_t)3*LSEQ;
    _Float16* wg  = (_Float16*)tail;
    float4* zwb = (float4*)(tail + 65536);
    float* aggb = tail + 65536 + 32768;
    _Float16* wdk = (_Float16*)(aggb + 8192);
    _Float16* wenc = wdk + 61440;

    float* outdec = (float*)d_out;
    float* outseq = outdec + B*DOUT*L;
    float* outreg = outseq + (size_t)LSEQ;

    // encoder
    k_wenc<<<96, 256, 0, stream>>>(enc_w, wenc);
    k_enc<<<dim3(B*L/128, 2), 256, 0, stream>>>(x, wenc, enc_b, xa);

    // residual stack (full-N MFMA conv, coalesced epilogue)
    k_wpack<<<(NRES*2*3*65536 + 255)/256, 256, 0, stream>>>(res_w1, res_w2, wpk);
    for (int r = 0; r < NRES; ++r) {
        k_cv3<false><<<B*L/128, 256, 0, stream>>>(
            xa, wpk + (size_t)(r*2+0)*3*65536, res_b1 + r*H, nullptr, xb);
        k_cv3<true><<<B*L/128, 256, 0, stream>>>(
            xb, wpk + (size_t)(r*2+1)*3*65536, res_b2 + r*H, xa, xa);
    }
    k_t_cf<<<dim3(L/64, H/64, B), 256, 0, stream>>>(xa, h, hm16);

    // DSS blocks
    for (int i = 0; i < NLAYERS; ++i) {
        k_zw<<<(H*NST + 255)/256, 256, 0, stream>>>(log_dt, lam_re, lam_im, zwb, i);
        k_wzp<<<H, 128, 0, stream>>>(zwb, zp);
        k_wkern<<<H, 128, 0, stream>>>(log_dt, lam_re, lam_im, W_re, W_im, wbig, i);
        k_wtg16<<<(512*256 + 255)/256, 256, 0, stream>>>(glu_w, wg, i);
        k_dss<<<dim3(8, H), 256, 0, stream>>>(hm16, zp, wbig, zwb, Dv, y16, i);
        k_t16<<<dim3(L/64, H/64, B), 256, 0, stream>>>(y16, yt);
        k_glu16<<<dim3(4, B*L/128), 256, 0, stream>>>(yt, wg, glu_b + i*512, zc16);
        if (i < NLAYERS - 1)
            k_ln2<false><<<dim3(L/32, B), 256, 0, stream>>>(zc16, h, ln_g + i*H, ln_b + i*H,
                                                            hm16, nullptr, nullptr, nullptr);
        else
            k_ln2<true><<<dim3(L/32, B), 256, 0, stream>>>(zc16, h, ln_g + i*H, ln_b + i*H,
                                                           hm16, xs, sp_emb, outseq);
    }

    // aggregate + regression head
    k_agg<<<B*H, 256, 0, stream>>>(h, aggb);
    k_mlp<<<B, 128, 0, stream>>>(aggb, h1_w, h1_b, h2_w, h2_b, h3_w, h3_b, h4_w, h4_b, outreg);
    // decoder
    k_t_cl<<<dim3(L/64, H/64, B), 256, 0, stream>>>(h, (_Float16*)t1);
    k_wdec<<<(15*16*256 + 255)/256, 256, 0, stream>>>(dec_w, wdk);
    k_dec<<<B*L/128, 128, 0, stream>>>((_Float16*)t1, wdk, dec_b, outdec);
}

// Round 9
// 1147.171 us; speedup vs baseline: 5.7125x; 1.0643x over previous
//
#include <hip/hip_runtime.h>
#include <math.h>

#define B 32
#define L 2048
#define DIN 5
#define DOUT 5
#define H 256
#define NST 32
#define NLAYERS 4
#define NRES 3
#define CHUNK 128
#define NCH 16            // L / CHUNK
#define LSEQ (B*H*L)      // 16777216

typedef __attribute__((ext_vector_type(8))) _Float16 half8;
typedef __attribute__((ext_vector_type(4))) float f32x4;

__device__ __forceinline__ float gelu_exact(float v) {
    return 0.5f * v * (1.0f + erff(v * 0.7071067811865475f));
}
#define SWZ(r) ((((r) ^ ((r) >> 2)) & 3))
#define LDIDX(l, c) ((l)*281 + ((c)>>5)*35 + ((c)&31))

// ---------------- encoder weight pack ----------------
__global__ void k_wenc(const float* __restrict__ ew, _Float16* __restrict__ wenc) {
    int idx = blockIdx.x*256 + threadIdx.x;
    if (idx >= 256*96) return;
    int o = idx / 96, kk = idx % 96;
    int ci = kk >> 4, k = kk & 15;
    float v = (ci < DIN && k < 15) ? ew[(o*DIN + ci)*15 + k] : 0.f;
    wenc[idx] = (_Float16)v;
}

// ---------------- MFMA encoder conv K=15 Cin=5 ----------------
__global__ __launch_bounds__(256) void k_enc(const float* __restrict__ x,
        const _Float16* __restrict__ wenc, const float* __restrict__ bias,
        _Float16* __restrict__ out) {
    __shared__ _Float16 a_lds[3*128*32];
    __shared__ _Float16 b_lds[3*128*32];
    const int tid = threadIdx.x;
    const int mbase = blockIdx.x * 128;
    const int oh = blockIdx.y;
    const int b = mbase >> 11;
    const int lbase = mbase & 2047;
    const int lane = tid & 63;
    const int w = tid >> 6;
    const int wm = (w >> 1) * 64, wn = (w & 1) * 64;
    const int fr = lane & 15, kg = lane >> 4;

    #pragma unroll
    for (int i = 0; i < 6; ++i) {
        int g = i*256 + tid;
        int r = g / 12, rem = g % 12;
        int ks = rem >> 2, q = rem & 3;
        int kk0 = ks*32 + q*8;
        int ci = kk0 >> 4, k0 = kk0 & 15;
        half8 va;
        #pragma unroll
        for (int e = 0; e < 8; ++e) {
            int k = k0 + e;
            int l = lbase + r - 7 + k;
            float v = (ci < DIN && k < 15 && l >= 0 && l < L)
                        ? x[((size_t)(b*DIN + ci))*L + l] : 0.f;
            va[e] = (_Float16)v;
        }
        *(half8*)&a_lds[ks*4096 + r*32 + ((q ^ SWZ(r))*8)] = va;
        uint4 vb = *(const uint4*)&wenc[(size_t)(oh*128 + r)*96 + kk0];
        *(uint4*)&b_lds[ks*4096 + r*32 + ((q ^ SWZ(r))*8)] = vb;
    }
    __syncthreads();
    f32x4 acc[4][4];
    #pragma unroll
    for (int i = 0; i < 4; ++i)
        #pragma unroll
        for (int j = 0; j < 4; ++j)
            #pragma unroll
            for (int k = 0; k < 4; ++k) acc[i][j][k] = 0.f;
    #pragma unroll
    for (int ks = 0; ks < 3; ++ks) {
        half8 af[4], bfr[4];
        #pragma unroll
        for (int mf = 0; mf < 4; ++mf) {
            int ra = wm + mf*16 + fr;
            af[mf] = *(const half8*)&a_lds[ks*4096 + ra*32 + ((kg ^ SWZ(ra))*8)];
        }
        #pragma unroll
        for (int nf = 0; nf < 4; ++nf) {
            int rb = wn + nf*16 + fr;
            bfr[nf] = *(const half8*)&b_lds[ks*4096 + rb*32 + ((kg ^ SWZ(rb))*8)];
        }
        #pragma unroll
        for (int mf = 0; mf < 4; ++mf)
            #pragma unroll
            for (int nf = 0; nf < 4; ++nf)
                acc[mf][nf] = __builtin_amdgcn_mfma_f32_16x16x32_f16(af[mf], bfr[nf], acc[mf][nf], 0, 0, 0);
    }
    #pragma unroll
    for (int nf = 0; nf < 4; ++nf) {
        int o = oh*128 + wn + nf*16 + fr;
        float bo = bias[o];
        #pragma unroll
        for (int mf = 0; mf < 4; ++mf)
            #pragma unroll
            for (int rg = 0; rg < 4; ++rg) {
                size_t m = (size_t)mbase + wm + mf*16 + kg*4 + rg;
                out[m*256 + o] = (_Float16)(acc[mf][nf][rg] + bo);
            }
    }
}

// ---------------- res weight pack ----------------
__global__ void k_wpack(const float* __restrict__ w1, const float* __restrict__ w2,
                        _Float16* __restrict__ wpk) {
    int idx = blockIdx.x*256 + threadIdx.x;
    if (idx >= NRES*2*3*65536) return;
    int ci = idx & 255;
    int o  = (idx >> 8) & 255;
    int k  = (idx >> 16) % 3;
    int cv = idx / (3*65536);
    const float* src = (cv & 1) ? w2 : w1;
    wpk[idx] = (_Float16)src[(((cv>>1)*H + o)*H + ci)*3 + k];
}

// ---------------- transpose fp16 chl -> fp16 chm ----------------
__global__ __launch_bounds__(256) void k_t_cf16(const _Float16* __restrict__ in,
        _Float16* __restrict__ out) {
    __shared__ float t[64][65];
    int tid = threadIdx.x;
    int l0 = blockIdx.x*64, c0 = blockIdx.y*64, b = blockIdx.z;
    #pragma unroll
    for (int i = 0; i < 16; ++i) {
        int idx = i*256 + tid;
        int l = idx >> 6, c = idx & 63;
        t[c][l] = (float)in[((size_t)b*L + l0 + l)*256 + c0 + c];
    }
    __syncthreads();
    #pragma unroll
    for (int i = 0; i < 16; ++i) {
        int idx = i*256 + tid;
        int c = idx >> 6, l = idx & 63;
        out[((size_t)(b*H + c0 + c))*L + l0 + l] = (_Float16)t[c][l];
    }
}

// ---------------- transpose fp16 chm -> fp16 chl ----------------
__global__ __launch_bounds__(256) void k_t16(const _Float16* __restrict__ in,
                                             _Float16* __restrict__ out) {
    __shared__ float t[64][65];
    int tid = threadIdx.x;
    int l0 = blockIdx.x*64, c0 = blockIdx.y*64, b = blockIdx.z;
    #pragma unroll
    for (int i = 0; i < 16; ++i) {
        int idx = i*256 + tid;
        int c = idx >> 6, l = idx & 63;
        t[c][l] = (float)in[((size_t)(b*H + c0 + c))*L + l0 + l];
    }
    __syncthreads();
    #pragma unroll
    for (int i = 0; i < 16; ++i) {
        int idx = i*256 + tid;
        int l = idx >> 6, c = idx & 63;
        out[((size_t)b*L + l0 + l)*256 + c0 + c] = (_Float16)t[c][l];
    }
}

// ---------------- MFMA residual conv K=3: full-N tile 128m x 256o, coalesced epilogue ----------------
template<bool RESID>
__global__ __launch_bounds__(256, 2) void k_cv3(const _Float16* __restrict__ xin,
        const _Float16* __restrict__ wpk, const float* __restrict__ bias,
        const _Float16* __restrict__ resid, _Float16* __restrict__ out) {
    __shared__ _Float16 a_lds[128*32];   // 8KB
    __shared__ _Float16 b_lds[256*32];   // 16KB
    __shared__ float    ep[32*256];      // 32KB epilogue slab
    const int tid = threadIdx.x;
    const int mbase = blockIdx.x * 128;
    const int lane = tid & 63;
    const int w = tid >> 6;
    const int wm = (w >> 1) * 64, wo = (w & 1) * 128;
    const int fr = lane & 15, kg = lane >> 4;

    const int r0s = tid >> 2, q0 = tid & 3;
    const int sq = SWZ(r0s);
    const int awA0 = r0s*32 + ((q0 ^ sq) * 8);
    const int awA1 = (64 + r0s)*32 + ((q0 ^ SWZ(64 + r0s)) * 8);

    f32x4 acc[4][8];
    #pragma unroll
    for (int i = 0; i < 4; ++i)
        #pragma unroll
        for (int j = 0; j < 8; ++j)
            #pragma unroll
            for (int k = 0; k < 4; ++k) acc[i][j][k] = 0.f;

    uint4 pa0, pa1, pb[4];
    auto loadstep = [&](int kk, uint4& a0, uint4& a1, uint4 (&bb)[4]) {
        const int koff = kk >> 3, cic = kk & 7;
        const int cb = cic*32 + q0*8;
        {
            int m = mbase + r0s;
            int ll = (m & (L-1)) + koff - 1;
            a0 = (ll >= 0 && ll < L) ? *(const uint4*)&xin[((size_t)(m + koff - 1))*256 + cb]
                                     : make_uint4(0,0,0,0);
            int m1 = mbase + 64 + r0s;
            int l1 = (m1 & (L-1)) + koff - 1;
            a1 = (l1 >= 0 && l1 < L) ? *(const uint4*)&xin[((size_t)(m1 + koff - 1))*256 + cb]
                                     : make_uint4(0,0,0,0);
        }
        #pragma unroll
        for (int u = 0; u < 4; ++u)
            bb[u] = *(const uint4*)&wpk[((size_t)(koff*256 + u*64 + r0s))*256 + cb];
    };
    loadstep(0, pa0, pa1, pb);
    for (int kk = 0; kk < 24; ++kk) {
        __syncthreads();
        *(uint4*)&a_lds[awA0] = pa0;
        *(uint4*)&a_lds[awA1] = pa1;
        #pragma unroll
        for (int u = 0; u < 4; ++u)
            *(uint4*)&b_lds[(u*64 + r0s)*32 + ((q0 ^ sq)*8)] = pb[u];
        uint4 na0 = make_uint4(0,0,0,0), na1 = na0, nb[4] = {na0, na0, na0, na0};
        if (kk < 23) loadstep(kk+1, na0, na1, nb);
        __syncthreads();
        half8 af[4];
        #pragma unroll
        for (int mf = 0; mf < 4; ++mf) {
            int ra = wm + mf*16 + fr;
            af[mf] = *(const half8*)&a_lds[ra*32 + ((kg ^ SWZ(ra)) * 8)];
        }
        #pragma unroll
        for (int nf = 0; nf < 8; ++nf) {
            int rb = wo + nf*16 + fr;
            half8 bfr = *(const half8*)&b_lds[rb*32 + ((kg ^ SWZ(rb)) * 8)];
            #pragma unroll
            for (int mf = 0; mf < 4; ++mf)
                acc[mf][nf] = __builtin_amdgcn_mfma_f32_16x16x32_f16(af[mf], bfr, acc[mf][nf], 0, 0, 0);
        }
        pa0 = na0; pa1 = na1;
        #pragma unroll
        for (int u = 0; u < 4; ++u) pb[u] = nb[u];
    }
    float bo8[8];
    #pragma unroll
    for (int nf = 0; nf < 8; ++nf) bo8[nf] = bias[wo + nf*16 + fr];
    const int er = tid >> 3, eoc = (tid & 7) * 32;
    #pragma unroll
    for (int mf = 0; mf < 4; ++mf) {
        __syncthreads();
        #pragma unroll
        for (int nf = 0; nf < 8; ++nf) {
            int o = wo + nf*16 + fr;
            int srb = (w >> 1)*16 + kg*4;
            #pragma unroll
            for (int rg = 0; rg < 4; ++rg)
                ep[(srb + rg)*256 + o] = acc[mf][nf][rg] + bo8[nf];
        }
        __syncthreads();
        size_t m = (size_t)mbase + mf*16 + (er < 16 ? er : 48 + er);
        #pragma unroll
        for (int u = 0; u < 4; ++u) {
            float4 v0 = *(float4*)&ep[er*256 + eoc + u*8];
            float4 v1 = *(float4*)&ep[er*256 + eoc + u*8 + 4];
            float vv[8] = {v0.x, v0.y, v0.z, v0.w, v1.x, v1.y, v1.z, v1.w};
            if (RESID) {
                half8 rv = *(const half8*)&resid[m*256 + eoc + u*8];
                #pragma unroll
                for (int e = 0; e < 8; ++e) vv[e] += (float)rv[e];
            }
            half8 hv;
            #pragma unroll
            for (int e = 0; e < 8; ++e) hv[e] = (_Float16)fmaxf(vv[e], 0.f);
            *(half8*)&out[m*256 + eoc + u*8] = hv;
        }
    }
}

// ---------------- DSS: per-(h,n) pole z and z^CHUNK ----------------
__global__ void k_zw(const float* __restrict__ log_dt, const float* __restrict__ lam_re,
                     const float* __restrict__ lam_im, float4* __restrict__ zwbuf, int layer) {
    int idx = blockIdx.x*256 + threadIdx.x;
    if (idx >= H*NST) return;
    int hh = idx / NST, n = idx % NST;
    float dt = expf(log_dt[layer*H + hh]);
    float a  = dt * lam_re[layer*NST + n];
    float bi = dt * lam_im[layer*NST + n];
    float er = expf(a);
    float zre = er * cosf(bi), zim = er * sinf(bi);
    float eC = expf(a * (float)CHUNK);
    float bC = bi * (float)CHUNK;
    float zcre = eC * cosf(bC), zcim = eC * sinf(bC);
    zwbuf[idx] = make_float4(zre, zim, zcre, zcim);
}

// ---------------- Z-power matrix zp[h][t][j] fp16 (t = dn*2+c) ----------------
__global__ __launch_bounds__(128) void k_wzp(const float4* __restrict__ zw,
        _Float16* __restrict__ zp) {
    int hh = blockIdx.x;
    int t = threadIdx.x;
    int dn = t >> 1, c = t & 1, dir = dn >> 5, n = dn & 31;
    float4 z4 = zw[hh*NST + n];
    float zre = z4.x, zim = z4.y;
    _Float16* dst = &zp[(size_t)hh*16384 + t*128];
    float cr = 1.f, ci = 0.f;
    for (int p = 0; p < 128; ++p) {
        float val = c ? ci : cr;
        dst[dir ? p : (127 - p)] = (_Float16)val;
        float nr = cr*zre - ci*zim;
        float ni = cr*zim + ci*zre;
        cr = nr; ci = ni;
    }
}

// ---------------- W_big[h][t][256] fp16 ----------------
__global__ __launch_bounds__(128) void k_wkern(const float* __restrict__ log_dt,
        const float* __restrict__ lam_re, const float* __restrict__ lam_im,
        const float* __restrict__ W_re, const float* __restrict__ W_im,
        _Float16* __restrict__ wbig, int layer) {
    __shared__ float kf[128], kb[128];
    __shared__ float E[128*129];
    const int hh = blockIdx.x;
    const int t = threadIdx.x;
    float dt = expf(log_dt[layer*H + hh]);
    float skf = 0.f, skb = 0.f;
    for (int n = 0; n < 32; ++n) {
        float a  = dt * lam_re[layer*NST + n];
        float bi = dt * lam_im[layer*NST + n];
        float wfr = W_re[((layer*2+0)*H + hh)*NST + n];
        float wfi = W_im[((layer*2+0)*H + hh)*NST + n];
        float wbr = W_re[((layer*2+1)*H + hh)*NST + n];
        float wbi = W_im[((layer*2+1)*H + hh)*NST + n];
        float e0 = expf(a*t), s0, c0; sincosf(bi*t, &s0, &c0);
        float zr0 = e0*c0, zi0 = e0*s0;
        skf = fmaf(wfr, zr0, skf) - wfi*zi0;
        skb = fmaf(wbr, zr0, skb) - wbi*zi0;
        float e1 = expf(a*(t+1)), s1, c1; sincosf(bi*(t+1), &s1, &c1);
        float zr1 = e1*c1, zi1 = e1*s1;
        E[t*129 + n]      = wfr*zr1 - wfi*zi1;
        E[t*129 + 32 + n] = -(wfr*zi1 + wfi*zr1);
        float e2 = expf(a*(127-t)), s2, c2; sincosf(bi*(127-t), &s2, &c2);
        float zr2 = e2*c2, zi2 = e2*s2;
        E[t*129 + 64 + n] = wbr*zr2 - wbi*zi2;
        E[t*129 + 96 + n] = -(wbr*zi2 + wbi*zr2);
    }
    kf[t] = skf; kb[t] = skb;
    __syncthreads();
    _Float16* dst = &wbig[(size_t)hh*32768];
    for (int idx = t; idx < 128*256; idx += 128) {
        int tt = idx >> 8, k = idx & 255;
        float v;
        if (k < 128) v = (k <= tt) ? kf[tt - k] : kb[k - tt - 1];
        else         v = E[tt*129 + (k - 128)];
        dst[idx] = (_Float16)v;
    }
}

// ---------------- GLU weight pack ----------------
__global__ void k_wtg16(const float* __restrict__ gw, _Float16* __restrict__ wg, int layer) {
    int idx = blockIdx.x*256 + threadIdx.x;
    if (idx >= 512*256) return;
    wg[idx] = (_Float16)gw[layer*512*256 + idx];
}

// ---------------- decoder weight pack ----------------
__global__ void k_wdec(const float* __restrict__ dw, _Float16* __restrict__ wdk) {
    int idx = blockIdx.x*256 + threadIdx.x;
    if (idx >= 15*16*256) return;
    int cfull = idx & 255;
    int o = (idx >> 8) & 15;
    int k = idx >> 12;
    float v = (o < DOUT) ? dw[(o*H + cfull)*15 + k] : 0.f;
    int cc = cfull >> 5, cl = cfull & 31;
    int cq = cl >> 3, cb = cl & 7;
    wdk[cc*7680 + (k*16 + o)*32 + ((cq ^ SWZ(o))*8) + cb] = (_Float16)v;
}

// ---------------- FUSED DSS; grid (H, 8): all m-tiles of an hh land on XCD hh%8 ----------------
__global__ __launch_bounds__(256) void k_dss(const _Float16* __restrict__ hm16,
        const _Float16* __restrict__ zp, const _Float16* __restrict__ wbig,
        const float4* __restrict__ zwb, const float* __restrict__ Dv,
        _Float16* __restrict__ y16, int layer) {
    __shared__ _Float16 xbuf[4*64*32];    // 16KB
    __shared__ _Float16 bbuf[2*128*32];   // 16KB: zp dbuf -> stp -> y16 stage
    __shared__ float    sbuf[64*128];     // 32KB
    _Float16* sb16 = (_Float16*)sbuf;

    const int tid = threadIdx.x;
    const int hh = blockIdx.x;
    const int b0 = blockIdx.y * 4;
    const int lane = tid & 63;
    const int w = tid >> 6;
    const int wn = w * 32;
    const int fr = lane & 15, kg = lane >> 4;

    #pragma unroll
    for (int i = 0; i < 4; ++i) {
        int g = i*256 + tid;
        int m = g >> 4, gi = g & 15;
        int kc = gi >> 2, q = gi & 3;
        uint4 v = *(const uint4*)&hm16[((size_t)((b0 + (m>>4))*H + hh))*L
                                       + (m&15)*128 + kc*32 + q*8];
        *(uint4*)&xbuf[kc*2048 + m*32 + ((q ^ SWZ(m))*8)] = v;
    }

    // ---- phase 1: S = x . zp^T ----
    f32x4 acc1[4][2];
    #pragma unroll
    for (int i = 0; i < 4; ++i)
        #pragma unroll
        for (int j = 0; j < 2; ++j)
            #pragma unroll
            for (int k = 0; k < 4; ++k) acc1[i][j][k] = 0.f;
    const _Float16* zb = &zp[(size_t)hh*16384];
    const int gr0 = tid >> 2, gq0 = tid & 3;
    const int gr1 = 64 + gr0;
    uint4 pb0 = *(const uint4*)&zb[gr0*128 + gq0*8];
    uint4 pb1 = *(const uint4*)&zb[gr1*128 + gq0*8];
    for (int kc = 0; kc < 4; ++kc) {
        __syncthreads();
        *(uint4*)&bbuf[(kc&1)*4096 + gr0*32 + ((gq0 ^ SWZ(gr0))*8)] = pb0;
        *(uint4*)&bbuf[(kc&1)*4096 + gr1*32 + ((gq0 ^ SWZ(gr1))*8)] = pb1;
        if (kc < 3) {
            pb0 = *(const uint4*)&zb[gr0*128 + (kc+1)*32 + gq0*8];
            pb1 = *(const uint4*)&zb[gr1*128 + (kc+1)*32 + gq0*8];
        }
        __syncthreads();
        half8 af[4], bf2[2];
        #pragma unroll
        for (int mf = 0; mf < 4; ++mf) {
            int ra = mf*16 + fr;
            af[mf] = *(const half8*)&xbuf[kc*2048 + ra*32 + ((kg ^ SWZ(ra))*8)];
        }
        #pragma unroll
        for (int nf = 0; nf < 2; ++nf) {
            int rb = wn + nf*16 + fr;
            bf2[nf] = *(const half8*)&bbuf[(kc&1)*4096 + rb*32 + ((kg ^ SWZ(rb))*8)];
        }
        #pragma unroll
        for (int mf = 0; mf < 4; ++mf)
            #pragma unroll
            for (int nf = 0; nf < 2; ++nf)
                acc1[mf][nf] = __builtin_amdgcn_mfma_f32_16x16x32_f16(af[mf], bf2[nf], acc1[mf][nf], 0, 0, 0);
    }
    #pragma unroll
    for (int mf = 0; mf < 4; ++mf)
        #pragma unroll
        for (int nf = 0; nf < 2; ++nf)
            #pragma unroll
            for (int rg = 0; rg < 4; ++rg)
                sbuf[(mf*16 + kg*4 + rg)*128 + wn + nf*16 + fr] = acc1[mf][nf][rg];
    __syncthreads();

    // ---- phase 2: in-LDS cross-chunk scan (f32) -> stp fp16 in bbuf ----
    {
        int b_loc = tid >> 6, dn = tid & 63;
        int dir = dn >> 5, n = dn & 31;
        float4 z4 = zwb[hh*NST + n];
        float zcre = z4.z, zcim = z4.w;
        int q1 = n >> 3, e1 = n & 7;
        float pre = 0.f, pim = 0.f;
        for (int s = 0; s < NCH; ++s) {
            int ch = dir ? (NCH - 1 - s) : s;
            int m = b_loc*16 + ch;
            bbuf[(dir*2 + 0)*2048 + m*32 + ((q1 ^ SWZ(m))*8) + e1] = (_Float16)pre;
            bbuf[(dir*2 + 1)*2048 + m*32 + ((q1 ^ SWZ(m))*8) + e1] = (_Float16)pim;
            float cre = sbuf[m*128 + dn*2];
            float cim = sbuf[m*128 + dn*2 + 1];
            float nre = fmaf(zcre, pre, fmaf(-zcim, pim, cre));
            float nim = fmaf(zcre, pim, fmaf(zcim, pre, cim));
            pre = nre; pim = nim;
        }
    }
    __syncthreads();

    // ---- phase 3: y = [x | stp] . wbig^T ----
    f32x4 acc3[4][2];
    #pragma unroll
    for (int i = 0; i < 4; ++i)
        #pragma unroll
        for (int j = 0; j < 2; ++j)
            #pragma unroll
            for (int k = 0; k < 4; ++k) acc3[i][j][k] = 0.f;
    const _Float16* wb = &wbig[(size_t)hh*32768];
    pb0 = *(const uint4*)&wb[gr0*256 + gq0*8];
    pb1 = *(const uint4*)&wb[gr1*256 + gq0*8];
    for (int kc = 0; kc < 8; ++kc) {
        __syncthreads();
        *(uint4*)&sb16[(kc&1)*4096 + gr0*32 + ((gq0 ^ SWZ(gr0))*8)] = pb0;
        *(uint4*)&sb16[(kc&1)*4096 + gr1*32 + ((gq0 ^ SWZ(gr1))*8)] = pb1;
        if (kc < 7) {
            pb0 = *(const uint4*)&wb[gr0*256 + (kc+1)*32 + gq0*8];
            pb1 = *(const uint4*)&wb[gr1*256 + (kc+1)*32 + gq0*8];
        }
        __syncthreads();
        half8 af[4], bf2[2];
        #pragma unroll
        for (int mf = 0; mf < 4; ++mf) {
            int ra = mf*16 + fr;
            af[mf] = (kc < 4)
                ? *(const half8*)&xbuf[kc*2048 + ra*32 + ((kg ^ SWZ(ra))*8)]
                : *(const half8*)&bbuf[(kc-4)*2048 + ra*32 + ((kg ^ SWZ(ra))*8)];
        }
        #pragma unroll
        for (int nf = 0; nf < 2; ++nf) {
            int rb = wn + nf*16 + fr;
            bf2[nf] = *(const half8*)&sb16[(kc&1)*4096 + rb*32 + ((kg ^ SWZ(rb))*8)];
        }
        #pragma unroll
        for (int mf = 0; mf < 4; ++mf)
            #pragma unroll
            for (int nf = 0; nf < 2; ++nf)
                acc3[mf][nf] = __builtin_amdgcn_mfma_f32_16x16x32_f16(af[mf], bf2[nf], acc3[mf][nf], 0, 0, 0);
    }
    __syncthreads();
    float dv = Dv[layer*H + hh];
    _Float16* yst = bbuf;
    #pragma unroll
    for (int mf = 0; mf < 4; ++mf) {
        #pragma unroll
        for (int rg = 0; rg < 4; ++rg) {
            int m = mf*16 + kg*4 + rg;
            #pragma unroll
            for (int nf = 0; nf < 2; ++nf) {
                int t = wn + nf*16 + fr;
                float xv = (float)xbuf[(t>>5)*2048 + m*32 + ((((t&31)>>3) ^ SWZ(m))*8) + (t&7)];
                float v = acc3[mf][nf][rg] + dv * xv;
                yst[m*128 + t] = (_Float16)gelu_exact(v);
            }
        }
    }
    __syncthreads();
    {
        int r = tid >> 2, tc = (tid & 3) * 32;
        size_t gb = ((size_t)((b0 + (r>>4))*H + hh))*L + (r&15)*128;
        #pragma unroll
        for (int u = 0; u < 4; ++u)
            *(half8*)&y16[gb + tc + u*8] = *(half8*)&yst[r*128 + tc + u*8];
    }
}

// ---------------- GLU MFMA fp16; grid (B*L/128, 4): 4 o-blocks of m-tile share XCD ----------------
__global__ __launch_bounds__(256) void k_glu16(const _Float16* __restrict__ yt,
        const _Float16* __restrict__ wg, const float* __restrict__ bias,
        _Float16* __restrict__ zc) {
    __shared__ _Float16 a_lds[128*32];
    __shared__ _Float16 b_lds[128*32];
    __shared__ float    ep[32*64];
    const int tid = threadIdx.x;
    const int mbase = blockIdx.x * 128;
    const int o0 = blockIdx.y * 64;
    const int lane = tid & 63;
    const int w = tid >> 6;
    const int wm = (w >> 1) * 64, wn = (w & 1) * 32;
    const int fr = lane & 15, kg = lane >> 4;
    const int r0s = tid >> 2, q0 = tid & 3;
    const int r1s = 64 + r0s;
    const int aw0 = r0s*32 + ((q0 ^ SWZ(r0s)) * 8);
    const int aw1 = r1s*32 + ((q0 ^ SWZ(r1s)) * 8);
    const int og0 = o0 + r0s;
    const int og1 = 256 + o0 + r0s;

    f32x4 accg[4][2], accs[4][2];
    #pragma unroll
    for (int i = 0; i < 4; ++i)
        #pragma unroll
        for (int j = 0; j < 2; ++j)
            #pragma unroll
            for (int k = 0; k < 4; ++k) { accg[i][j][k] = 0.f; accs[i][j][k] = 0.f; }

    uint4 pa0, pa1, pb0, pb1;
    auto loadstep = [&](int kc, uint4& a0, uint4& a1, uint4& b0, uint4& b1) {
        const int cb = kc*32 + q0*8;
        a0 = *(const uint4*)&yt[((size_t)(mbase + r0s))*256 + cb];
        a1 = *(const uint4*)&yt[((size_t)(mbase + r1s))*256 + cb];
        b0 = *(const uint4*)&wg[((size_t)og0)*256 + cb];
        b1 = *(const uint4*)&wg[((size_t)og1)*256 + cb];
    };
    loadstep(0, pa0, pa1, pb0, pb1);
    for (int kc = 0; kc < 8; ++kc) {
        __syncthreads();
        *(uint4*)&a_lds[aw0] = pa0;
        *(uint4*)&a_lds[aw1] = pa1;
        *(uint4*)&b_lds[aw0] = pb0;
        *(uint4*)&b_lds[aw1] = pb1;
        uint4 na0 = make_uint4(0,0,0,0), na1 = na0, nb0 = na0, nb1 = na0;
        if (kc < 7) loadstep(kc+1, na0, na1, nb0, nb1);
        __syncthreads();
        half8 af[4], bg[2], bs[2];
        #pragma unroll
        for (int mf = 0; mf < 4; ++mf) {
            int ra = wm + mf*16 + fr;
            af[mf] = *(const half8*)&a_lds[ra*32 + ((kg ^ SWZ(ra)) * 8)];
        }
        #pragma unroll
        for (int nf = 0; nf < 2; ++nf) {
            int rb = wn + nf*16 + fr;
            bg[nf] = *(const half8*)&b_lds[rb*32 + ((kg ^ SWZ(rb)) * 8)];
            int rb2 = 64 + rb;
            bs[nf] = *(const half8*)&b_lds[rb2*32 + ((kg ^ SWZ(rb2)) * 8)];
        }
        #pragma unroll
        for (int mf = 0; mf < 4; ++mf)
            #pragma unroll
            for (int nf = 0; nf < 2; ++nf) {
                accg[mf][nf] = __builtin_amdgcn_mfma_f32_16x16x32_f16(af[mf], bg[nf], accg[mf][nf], 0, 0, 0);
                accs[mf][nf] = __builtin_amdgcn_mfma_f32_16x16x32_f16(af[mf], bs[nf], accs[mf][nf], 0, 0, 0);
            }
        pa0 = na0; pa1 = na1; pb0 = nb0; pb1 = nb1;
    }
    float b0v[2], b1v[2];
    #pragma unroll
    for (int nf = 0; nf < 2; ++nf) {
        int o = o0 + wn + nf*16 + fr;
        b0v[nf] = bias[o]; b1v[nf] = bias[256 + o];
    }
    const int er = tid >> 3, eoc = (tid & 7) * 8;
    #pragma unroll
    for (int mf = 0; mf < 4; ++mf) {
        __syncthreads();
        #pragma unroll
        for (int nf = 0; nf < 2; ++nf) {
            int ol = wn + nf*16 + fr;
            int srb = (w >> 1)*16 + kg*4;
            #pragma unroll
            for (int rg = 0; rg < 4; ++rg) {
                float g = accg[mf][nf][rg] + b0v[nf];
                float s = accs[mf][nf][rg] + b1v[nf];
                ep[(srb + rg)*64 + ol] = g / (1.f + expf(-s));
            }
        }
        __syncthreads();
        size_t m = (size_t)mbase + mf*16 + (er < 16 ? er : 48 + er);
        float4 v0 = *(float4*)&ep[er*64 + eoc];
        float4 v1 = *(float4*)&ep[er*64 + eoc + 4];
        half8 hv;
        hv[0]=(_Float16)v0.x; hv[1]=(_Float16)v0.y; hv[2]=(_Float16)v0.z; hv[3]=(_Float16)v0.w;
        hv[4]=(_Float16)v1.x; hv[5]=(_Float16)v1.y; hv[6]=(_Float16)v1.z; hv[7]=(_Float16)v1.w;
        *(half8*)&zc[m*256 + o0 + eoc] = hv;
    }
}

// ---------------- LayerNorm: fp16 residual stream; last layer adds species + outseq f32 ----------------
template<bool SP>
__global__ __launch_bounds__(256) void k_ln2(const _Float16* __restrict__ zc,
        _Float16* __restrict__ hm, const float* __restrict__ g, const float* __restrict__ bb,
        const int* __restrict__ xs, const float* __restrict__ emb,
        float* __restrict__ outseq) {
    __shared__ float tl[8992];
    int tid = threadIdx.x;
    int b = blockIdx.y;
    int l0 = blockIdx.x * 32;
    for (int j = tid; j < 1024; j += 256) {
        int c = j >> 2, l8 = (j & 3) * 8;
        half8 v = *(const half8*)&hm[((size_t)(b*H + c))*L + l0 + l8];
        #pragma unroll
        for (int e = 0; e < 8; ++e) tl[LDIDX(l8 + e, c)] = (float)v[e];
    }
    __syncthreads();
    int r = tid >> 3, p = tid & 7;
    float v[32];
    float sum = 0.f, ss = 0.f;
    const _Float16* zrow = &zc[((size_t)(b*L + l0 + r))*256 + p*32];
    #pragma unroll
    for (int q = 0; q < 4; ++q) {
        half8 z8 = *(const half8*)&zrow[q*8];
        #pragma unroll
        for (int i = 0; i < 8; ++i) {
            float hv = tl[LDIDX(r, p*32 + q*8 + i)];
            float vv = (float)z8[i] + hv;
            v[q*8+i] = vv;
            sum += vv; ss = fmaf(vv, vv, ss);
        }
    }
    sum += __shfl_xor(sum, 1); ss += __shfl_xor(ss, 1);
    sum += __shfl_xor(sum, 2); ss += __shfl_xor(ss, 2);
    sum += __shfl_xor(sum, 4); ss += __shfl_xor(ss, 4);
    float mu = sum * (1.f/256.f);
    float var = ss * (1.f/256.f) - mu*mu;
    float rs = rsqrtf(var + 1e-5f);
    int sp = SP ? xs[b] : 0;
    #pragma unroll
    for (int q = 0; q < 32; ++q) {
        int c = p*32 + q;
        float val = (v[q] - mu) * rs * g[c] + bb[c];
        if (SP) val += emb[sp*H + c];
        tl[LDIDX(r, c)] = val;
    }
    __syncthreads();
    for (int j = tid; j < 1024; j += 256) {
        int c = j >> 2, l8 = (j & 3) * 8;
        float fv[8];
        half8 hv;
        #pragma unroll
        for (int e = 0; e < 8; ++e) {
            fv[e] = tl[LDIDX(l8 + e, c)];
            hv[e] = (_Float16)fv[e];
        }
        *(half8*)&hm[((size_t)(b*H + c))*L + l0 + l8] = hv;
        if (SP) {
            *(float4*)&outseq[((size_t)(b*H + c))*L + l0 + l8] = make_float4(fv[0],fv[1],fv[2],fv[3]);
            *(float4*)&outseq[((size_t)(b*H + c))*L + l0 + l8 + 4] = make_float4(fv[4],fv[5],fv[6],fv[7]);
        }
    }
}

// ---------------- MFMA decoder conv K=15 ----------------
__global__ __launch_bounds__(128) void k_dec(const _Float16* __restrict__ ht,
        const _Float16* __restrict__ wdk, const float* __restrict__ bias,
        float* __restrict__ outdec) {
    __shared__ _Float16 a_lds[160*32];
    __shared__ _Float16 b_lds[15*16*32];
    const int tid = threadIdx.x;
    const int mbase = blockIdx.x * 128;
    const int b = mbase >> 11;
    const int lbase = mbase & 2047;
    const int lane = tid & 63;
    const int w = tid >> 6;
    const int fr = lane & 15, kg = lane >> 4;
    const int rs = tid >> 2, q0 = tid & 3;
    f32x4 acc[4];
    #pragma unroll
    for (int i = 0; i < 4; ++i)
        #pragma unroll
        for (int k = 0; k < 4; ++k) acc[i][k] = 0.f;
    for (int cc = 0; cc < 8; ++cc) {
        __syncthreads();
        #pragma unroll
        for (int ps = 0; ps < 5; ++ps) {
            int r = ps*32 + rs;
            if (r < 142) {
                int l = lbase - 7 + r;
                uint4 v = (l >= 0 && l < L) ? *(const uint4*)&ht[((size_t)(b*L + l))*256 + cc*32 + q0*8]
                                            : make_uint4(0,0,0,0);
                *(uint4*)&a_lds[r*32 + ((q0 ^ SWZ(r))*8)] = v;
            }
        }
        for (int jj = tid; jj < 960; jj += 128)
            *(uint4*)&b_lds[jj*8] = *(const uint4*)&wdk[cc*7680 + jj*8];
        __syncthreads();
        #pragma unroll
        for (int k = 0; k < 15; ++k) {
            half8 bfr = *(const half8*)&b_lds[(k*16 + fr)*32 + ((kg ^ SWZ(fr))*8)];
            #pragma unroll
            for (int mf = 0; mf < 4; ++mf) {
                int ra = w*64 + mf*16 + fr + k;
                half8 af = *(const half8*)&a_lds[ra*32 + ((kg ^ SWZ(ra))*8)];
                acc[mf] = __builtin_amdgcn_mfma_f32_16x16x32_f16(af, bfr, acc[mf], 0, 0, 0);
            }
        }
    }
    if (fr < DOUT) {
        float bo = bias[fr];
        #pragma unroll
        for (int mf = 0; mf < 4; ++mf)
            #pragma unroll
            for (int rg = 0; rg < 4; ++rg) {
                int m = mbase + w*64 + mf*16 + kg*4 + rg;
                outdec[((size_t)(b*DOUT + fr))*L + (m & 2047)] = acc[mf][rg] + bo;
            }
    }
}

// ---------------- mean over L (fp16 input) ----------------
__global__ __launch_bounds__(256) void k_agg(const _Float16* __restrict__ h, float* __restrict__ agg) {
    __shared__ float red[256];
    int bc = blockIdx.x;
    int tid = threadIdx.x;
    half8 v = *(const half8*)&h[(size_t)bc*L + tid*8];
    float s = 0.f;
    #pragma unroll
    for (int e = 0; e < 8; ++e) s += (float)v[e];
    red[tid] = s; __syncthreads();
    for (int k = 128; k > 0; k >>= 1) {
        if (tid < k) red[tid] += red[tid+k];
        __syncthreads();
    }
    if (tid == 0) agg[bc] = red[0] * (1.f/(float)L);
}

// ---------------- regression MLP ----------------
__global__ __launch_bounds__(128) void k_mlp(const float* __restrict__ agg,
        const float* __restrict__ w1, const float* __restrict__ b1,
        const float* __restrict__ w2, const float* __restrict__ b2,
        const float* __restrict__ w3, const float* __restrict__ b3,
        const float* __restrict__ w4, const float* __restrict__ b4,
        float* __restrict__ outreg) {
    __shared__ float a0[256], r1[128], r2[64], r3[32];
    int b = blockIdx.x, tid = threadIdx.x;
    a0[tid] = agg[b*256 + tid];
    a0[tid+128] = agg[b*256 + tid + 128];
    __syncthreads();
    {
        float s = b1[tid];
        for (int k = 0; k < 256; ++k) s = fmaf(w1[tid*256+k], a0[k], s);
        r1[tid] = s > 0.f ? s : expm1f(s);
    }
    __syncthreads();
    if (tid < 64) {
        float s = b2[tid];
        for (int k = 0; k < 128; ++k) s = fmaf(w2[tid*128+k], r1[k], s);
        r2[tid] = s > 0.f ? s : expm1f(s);
    }
    __syncthreads();
    if (tid < 32) {
        float s = b3[tid];
        for (int k = 0; k < 64; ++k) s = fmaf(w3[tid*64+k], r2[k], s);
        r3[tid] = s > 0.f ? s : expm1f(s);
    }
    __syncthreads();
    if (tid == 0) {
        float s = b4[0];
        for (int k = 0; k < 32; ++k) s = fmaf(w4[k], r3[k], s);
        outreg[b] = s;
    }
}

extern "C" void kernel_launch(void* const* d_in, const int* in_sizes, int n_in,
                              void* d_out, int out_size, void* d_ws, size_t ws_size,
                              hipStream_t stream) {
    const float* x      = (const float*)d_in[0];
    const int*   xs     = (const int*)d_in[1];
    const float* enc_w  = (const float*)d_in[2];
    const float* enc_b  = (const float*)d_in[3];
    const float* res_w1 = (const float*)d_in[4];
    const float* res_b1 = (const float*)d_in[5];
    const float* res_w2 = (const float*)d_in[6];
    const float* res_b2 = (const float*)d_in[7];
    const float* log_dt = (const float*)d_in[8];
    const float* lam_re = (const float*)d_in[9];
    const float* lam_im = (const float*)d_in[10];
    const float* W_re   = (const float*)d_in[11];
    const float* W_im   = (const float*)d_in[12];
    const float* Dv     = (const float*)d_in[13];
    const float* glu_w  = (const float*)d_in[14];
    const float* glu_b  = (const float*)d_in[15];
    const float* ln_g   = (const float*)d_in[16];
    const float* ln_b   = (const float*)d_in[17];
    const float* dec_w  = (const float*)d_in[18];
    const float* dec_b  = (const float*)d_in[19];
    const float* sp_emb = (const float*)d_in[20];
    const float* h1_w = (const float*)d_in[21]; const float* h1_b = (const float*)d_in[22];
    const float* h2_w = (const float*)d_in[23]; const float* h2_b = (const float*)d_in[24];
    const float* h3_w = (const float*)d_in[25]; const float* h3_b = (const float*)d_in[26];
    const float* h4_w = (const float*)d_in[27]; const float* h4_b = (const float*)d_in[28];

    float* ws   = (float*)d_ws;
    _Float16* hm16 = (_Float16*)ws;                    // fp16 chm residual (persistent, 32MB)
    float* t1   = ws + (size_t)LSEQ;
    float* t2   = ws + (size_t)2*LSEQ;
    // res-phase:
    _Float16* xb  = (_Float16*)t1;                     // t1 lower
    _Float16* xa  = (_Float16*)t1 + (size_t)LSEQ;      // t1 upper
    _Float16* wpk = (_Float16*)t2;
    // DSS-phase:
    _Float16* yt   = (_Float16*)t1;                    // fp16 chl y (t1 lower)
    _Float16* wbig = (_Float16*)t1 + (size_t)LSEQ;     // 16MB (t1 upper)
    _Float16* zp   = wbig + (size_t)H*32768;           // 8MB
    _Float16* y16  = (_Float16*)t2;                    // fp16 chm y
    _Float16* zc16 = (_Float16*)t2;                    // glu out fp16 chl (y16 dead)
    _Float16* dect = (_Float16*)t1;                    // decoder chl input (yt dead)
    // tail:
    float* tail = ws + (size_t)3*LSEQ;
    _Float16* wg  = (_Float16*)tail;
    float4* zwb = (float4*)(tail + 65536);
    float* aggb = tail + 65536 + 32768;
    _Float16* wdk = (_Float16*)(aggb + 8192);
    _Float16* wenc = wdk + 61440;

    float* outdec = (float*)d_out;
    float* outseq = outdec + B*DOUT*L;
    float* outreg = outseq + (size_t)LSEQ;

    // encoder
    k_wenc<<<96, 256, 0, stream>>>(enc_w, wenc);
    k_enc<<<dim3(B*L/128, 2), 256, 0, stream>>>(x, wenc, enc_b, xa);

    // residual stack
    k_wpack<<<(NRES*2*3*65536 + 255)/256, 256, 0, stream>>>(res_w1, res_w2, wpk);
    for (int r = 0; r < NRES; ++r) {
        k_cv3<false><<<B*L/128, 256, 0, stream>>>(
            xa, wpk + (size_t)(r*2+0)*3*65536, res_b1 + r*H, nullptr, xb);
        k_cv3<true><<<B*L/128, 256, 0, stream>>>(
            xb, wpk + (size_t)(r*2+1)*3*65536, res_b2 + r*H, xa, xa);
    }
    k_t_cf16<<<dim3(L/64, H/64, B), 256, 0, stream>>>(xa, hm16);

    // DSS blocks
    for (int i = 0; i < NLAYERS; ++i) {
        k_zw<<<(H*NST + 255)/256, 256, 0, stream>>>(log_dt, lam_re, lam_im, zwb, i);
        k_wzp<<<H, 128, 0, stream>>>(zwb, zp);
        k_wkern<<<H, 128, 0, stream>>>(log_dt, lam_re, lam_im, W_re, W_im, wbig, i);
        k_wtg16<<<(512*256 + 255)/256, 256, 0, stream>>>(glu_w, wg, i);
        k_dss<<<dim3(H, 8), 256, 0, stream>>>(hm16, zp, wbig, zwb, Dv, y16, i);
        k_t16<<<dim3(L/64, H/64, B), 256, 0, stream>>>(y16, yt);
        k_glu16<<<dim3(B*L/128, 4), 256, 0, stream>>>(yt, wg, glu_b + i*512, zc16);
        if (i < NLAYERS - 1)
            k_ln2<false><<<dim3(L/32, B), 256, 0, stream>>>(zc16, hm16, ln_g + i*H, ln_b + i*H,
                                                            nullptr, nullptr, nullptr);
        else
            k_ln2<true><<<dim3(L/32, B), 256, 0, stream>>>(zc16, hm16, ln_g + i*H, ln_b + i*H,
                                                           xs, sp_emb, outseq);
    }

    // aggregate + regression head
    k_agg<<<B*H, 256, 0, stream>>>(hm16, aggb);
    k_mlp<<<B, 128, 0, stream>>>(aggb, h1_w, h1_b, h2_w, h2_b, h3_w, h3_b, h4_w, h4_b, outreg);
    // decoder
    k_t16<<<dim3(L/64, H/64, B), 256, 0, stream>>>(hm16, dect);
    k_wdec<<<(15*16*256 + 255)/256, 256, 0, stream>>>(dec_w, wdk);
    k_dec<<<B*L/128, 128, 0, stream>>>(dect, wdk, dec_b, outdec);
}